// Round 8
// baseline (694.618 us; speedup 1.0000x reference)
//
#include <hip/hip_runtime.h>
#include <stdint.h>

typedef unsigned short u16;
typedef unsigned int u32;
typedef __attribute__((ext_vector_type(4))) float f32x4;
typedef __attribute__((ext_vector_type(8))) short bf16x8;

#define NB 128      // graphs
#define LL 256      // nodes per graph
#define DD 128      // hidden
#define EDGES 524288
#define EPG 4096    // edges per graph
#define NN (NB*LL)

__device__ __forceinline__ float bf2f(u16 u) {
    union { u32 i; float f; } v; v.i = ((u32)u) << 16; return v.f;
}
__device__ __forceinline__ u16 f2bf(float f) {
    union { float f; u32 i; } v; v.f = f;
    u32 i = v.i;
    u32 r = (i + 0x7fffu + ((i >> 16) & 1u)) >> 16;   // RNE
    return (u16)r;
}
__device__ __forceinline__ float matfn(float a, float dv) {
    if (a != 0.f) return (a == 1.2f) ? 1.1f : a;
    return (dv == 0.f) ? 0.f : exp2f((1.f - dv) * 0.5849625007211562f); // 1.5^(1-dis)
}
__device__ __forceinline__ float red16(float v) {
#pragma unroll
    for (int off = 1; off < 16; off <<= 1) v += __shfl_xor(v, off, 64);
    return v;
}
__device__ __forceinline__ u32 cvtpk(float lo, float hi) {
    u32 r;
    asm("v_cvt_pk_bf16_f32 %0, %1, %2" : "=v"(r) : "v"(lo), "v"(hi));
    return r;
}
__device__ __forceinline__ u32 bperm(int srcLane, u32 v) {
    return (u32)__builtin_amdgcn_ds_bpermute(srcLane << 2, (int)v);
}

// ---------------- prep kernels ----------------

__global__ __launch_bounds__(256) void build_matrix_k(const float* __restrict__ adj,
                                                      const float* __restrict__ dis,
                                                      float* __restrict__ mat, int n) {
    int i = blockIdx.x * 256 + threadIdx.x;
    if (i >= n) return;
    mat[i] = matfn(adj[i], dis[i]);
}

__global__ __launch_bounds__(256) void zero_f32(float* __restrict__ p, int n) {
    int i = blockIdx.x * 256 + threadIdx.x;
    if (i < n) p[i] = 0.f;
}

__global__ __launch_bounds__(256) void scatter_w_k(const int* __restrict__ srcI,
                                                   const int* __restrict__ dstI,
                                                   const float* __restrict__ ew,
                                                   float* __restrict__ Wf) {
    int e = blockIdx.x * 256 + threadIdx.x;
    if (e >= EDGES) return;
    int b = e >> 12;
    atomicAdd(&Wf[(size_t)b * 65536 + (size_t)(dstI[e] & 255) * 256 + (srcI[e] & 255)], ew[e]);
}

__global__ __launch_bounds__(256) void cast_w_k(const float* __restrict__ Wf, u16* __restrict__ Wb) {
    int i = blockIdx.x * 256 + threadIdx.x;
    float4 v = ((const float4*)Wf)[i];
    ushort4 o;
    o.x = f2bf(v.x); o.y = f2bf(v.y); o.z = f2bf(v.z); o.w = f2bf(v.w);
    ((ushort4*)Wb)[i] = o;
}

__global__ __launch_bounds__(256) void build_wconvT0_k(const float* __restrict__ rel,
                                                       const float* __restrict__ root,
                                                       u16* __restrict__ dst) {
    int i = blockIdx.x * 256 + threadIdx.x;   // 128*128
    int m = i >> 7, k = i & 127;
    float v = 0.f;
    if (k < 40) v = rel[k * 128 + m];
    else if (k >= 64 && k < 104) v = root[(k - 64) * 128 + m];
    dst[m * 128 + k] = f2bf(v);
}

__global__ __launch_bounds__(256) void build_wconvT_k(const float* __restrict__ rel,
                                                      const float* __restrict__ root,
                                                      u16* __restrict__ dst) {
    int i = blockIdx.x * 256 + threadIdx.x;   // 128*256
    int m = i >> 8, k = i & 255;
    float v = (k < 128) ? rel[k * 128 + m] : root[(k - 128) * 128 + m];
    dst[m * 256 + k] = f2bf(v);
}

__global__ __launch_bounds__(256) void build_wqkvT_k(const float* __restrict__ wq,
                                                     const float* __restrict__ wk,
                                                     const float* __restrict__ wv,
                                                     u16* __restrict__ dst) {
    int i = blockIdx.x * 256 + threadIdx.x;   // 768*128
    int m = i >> 7, k = i & 127;
    const float* s = (m < 256) ? wq : (m < 512) ? wk : wv;
    int mm = m & 255;
    dst[m * 128 + k] = f2bf(s[k * 256 + mm]);
}

__global__ __launch_bounds__(256) void transpose_cast_k(const float* __restrict__ src,
                                                        u16* __restrict__ dst, int K, int M) {
    int i = blockIdx.x * 256 + threadIdx.x;
    if (i >= K * M) return;
    int m = i / K, k = i - m * K;
    dst[i] = f2bf(src[k * M + m]);   // dst [M][K]
}

// per-graph transpose: h [N,128] bf16 (or x [N,40] f32, zero-padded) -> hT [b][128][256]
template<bool IS0>
__global__ __launch_bounds__(256) void transpose_h_k(const u16* __restrict__ h,
                                                     const float* __restrict__ x,
                                                     u16* __restrict__ hT) {
    int gw = blockIdx.x * 4 + (threadIdx.x >> 6);
    int lane = threadIdx.x & 63;
    int b = gw >> 6, rem = gw & 63, db = rem >> 5, jb = rem & 31;
    int d = (db << 6) + lane;
    u16 vals[8];
#pragma unroll
    for (int jj = 0; jj < 8; ++jj) {
        int node = (b << 8) + (jb << 3) + jj;
        if (IS0) vals[jj] = (d < 40) ? f2bf(x[(size_t)node * 40 + d]) : (u16)0;
        else     vals[jj] = h[(size_t)node * 128 + d];
    }
    *(uint4*)(hT + (size_t)b * 32768 + (size_t)d * 256 + (jb << 3)) = *(uint4*)vals;
}

// ---------------- per-graph aggregation GEMM: Acat = [W@h | h]  (K=256) ----------------

template<bool IS0>
__global__ __launch_bounds__(256) void gemm_agg(const u16* __restrict__ Wb,
                                                const u16* __restrict__ BT0,
                                                const u16* __restrict__ h,
                                                const float* __restrict__ x,
                                                u16* __restrict__ Acat) {
    __shared__ __align__(16) u16 lds[8192];
    char* ldsc = (char*)lds;
    int t = threadIdx.x, lane = t & 63, wid = t >> 6;
    int b = blockIdx.x >> 1, rt = blockIdx.x & 1;
    int row0 = rt << 7, nbase = b << 8;
    const u16* A = Wb + (size_t)b * 65536 + (size_t)row0 * 256;
    const u16* BT = BT0 + (size_t)b * 32768;

    f32x4 zero = {0.f, 0.f, 0.f, 0.f};
    f32x4 acc[4][4];
#pragma unroll
    for (int mt = 0; mt < 4; ++mt)
#pragma unroll
        for (int nt = 0; nt < 4; ++nt) acc[mt][nt] = zero;

    int wr = wid >> 1, wc = wid & 1;
    int rA = wr * 64 + (lane & 15);
    int rB = wc * 64 + (lane & 15);
    int kch = (lane >> 4) << 4;

    for (int kt = 0; kt < 8; ++kt) {
        int kc = kt << 5;
#pragma unroll
        for (int i = 0; i < 2; ++i) {
            int off = wid * 2048 + i * 1024 + lane * 16;
            int r = off >> 6, cb = off & 63;
            __builtin_amdgcn_global_load_lds((const u32*)((const char*)A + ((size_t)r * 256 + kc) * 2 + cb),
                                             (u32*)(ldsc + wid * 2048 + i * 1024), 16, 0, 0);
            __builtin_amdgcn_global_load_lds((const u32*)((const char*)BT + ((size_t)r * 256 + kc) * 2 + cb),
                                             (u32*)(ldsc + 8192 + wid * 2048 + i * 1024), 16, 0, 0);
        }
        __syncthreads();
        bf16x8 af[4], bfr[4];
#pragma unroll
        for (int mt = 0; mt < 4; ++mt)
            af[mt] = *(const bf16x8*)(ldsc + (rA + mt * 16) * 64 + kch);
#pragma unroll
        for (int nt = 0; nt < 4; ++nt)
            bfr[nt] = *(const bf16x8*)(ldsc + 8192 + (rB + nt * 16) * 64 + kch);
#pragma unroll
        for (int mt = 0; mt < 4; ++mt)
#pragma unroll
            for (int nt = 0; nt < 4; ++nt)
                acc[mt][nt] = __builtin_amdgcn_mfma_f32_16x16x32_bf16(af[mt], bfr[nt], acc[mt][nt], 0, 0, 0);
        __syncthreads();
    }

    int colb = wc * 64 + (lane & 15);
    int rowb = wr * 64 + ((lane >> 4) << 2);
#pragma unroll
    for (int mt = 0; mt < 4; ++mt)
#pragma unroll
        for (int nt = 0; nt < 4; ++nt)
#pragma unroll
            for (int r = 0; r < 4; ++r) {
                int i = rowb + mt * 16 + r;
                int c = colb + nt * 16;
                float v = acc[mt][nt][r];
                if (IS0) Acat[(size_t)(nbase + row0 + i) * 128 + c] = f2bf(v);
                else     Acat[(size_t)(nbase + row0 + i) * 256 + c] = f2bf(v);
            }
    if (IS0) {
        for (int idx = t; idx < 128 * 40; idx += 256) {
            int i = idx / 40, c = idx - i * 40;
            int node = nbase + row0 + i;
            Acat[(size_t)node * 128 + 64 + c] = f2bf(x[(size_t)node * 40 + c]);
        }
    } else {
        for (int idx = t; idx < 2048; idx += 256) {
            int i = idx >> 4, q = idx & 15;
            int node = nbase + row0 + i;
            *(uint4*)(Acat + (size_t)node * 256 + 128 + (q << 3)) =
                *(const uint4*)(h + (size_t)node * 128 + (q << 3));
        }
    }
}

// ---------------- qkv GEMM (K=128, Mtot=768) with fused V->vT transpose epilogue ----------------

__global__ __launch_bounds__(256) void gemm_qkv(const u16* __restrict__ A,
                                                const u16* __restrict__ BT,
                                                u16* __restrict__ qkv,
                                                u16* __restrict__ vT) {
    __shared__ __align__(16) u16 lds[8192];
    char* ldsc = (char*)lds;
    int t = threadIdx.x, lane = t & 63, wid = t >> 6;
    int row0 = blockIdx.x * 128, col0 = blockIdx.y * 128;

    f32x4 zero = {0.f, 0.f, 0.f, 0.f};
    f32x4 acc[4][4];
#pragma unroll
    for (int mt = 0; mt < 4; ++mt)
#pragma unroll
        for (int nt = 0; nt < 4; ++nt) acc[mt][nt] = zero;

    int wr = wid >> 1, wc = wid & 1;
    int rA = wr * 64 + (lane & 15);
    int rB = wc * 64 + (lane & 15);
    int kch = (lane >> 4) << 4;

    for (int kt = 0; kt < 4; ++kt) {
        int kc = kt << 5;
#pragma unroll
        for (int i = 0; i < 2; ++i) {
            int off = wid * 2048 + i * 1024 + lane * 16;
            int r = off >> 6, cb = off & 63;
            __builtin_amdgcn_global_load_lds((const u32*)((const char*)A + ((size_t)(row0 + r) * 128 + kc) * 2 + cb),
                                             (u32*)(ldsc + wid * 2048 + i * 1024), 16, 0, 0);
            __builtin_amdgcn_global_load_lds((const u32*)((const char*)BT + ((size_t)(col0 + r) * 128 + kc) * 2 + cb),
                                             (u32*)(ldsc + 8192 + wid * 2048 + i * 1024), 16, 0, 0);
        }
        __syncthreads();
        bf16x8 af[4], bfr[4];
#pragma unroll
        for (int mt = 0; mt < 4; ++mt)
            af[mt] = *(const bf16x8*)(ldsc + (rA + mt * 16) * 64 + kch);
#pragma unroll
        for (int nt = 0; nt < 4; ++nt)
            bfr[nt] = *(const bf16x8*)(ldsc + 8192 + (rB + nt * 16) * 64 + kch);
#pragma unroll
        for (int mt = 0; mt < 4; ++mt)
#pragma unroll
            for (int nt = 0; nt < 4; ++nt)
                acc[mt][nt] = __builtin_amdgcn_mfma_f32_16x16x32_bf16(af[mt], bfr[nt], acc[mt][nt], 0, 0, 0);
        __syncthreads();
    }

    int colb = col0 + wc * 64 + (lane & 15);
    int rowb = row0 + wr * 64 + ((lane >> 4) << 2);
    if (col0 < 512) {
#pragma unroll
        for (int mt = 0; mt < 4; ++mt)
#pragma unroll
            for (int nt = 0; nt < 4; ++nt)
#pragma unroll
                for (int r = 0; r < 4; ++r)
                    qkv[(size_t)(rowb + mt * 16 + r) * 768 + colb + nt * 16] = f2bf(acc[mt][nt][r]);
    } else {
        int bb = row0 >> 8;
#pragma unroll
        for (int mt = 0; mt < 4; ++mt) {
            int node0 = (rowb + mt * 16) & 255;
#pragma unroll
            for (int nt = 0; nt < 4; ++nt) {
                int c = colb + nt * 16 - 512;
                int hh = c >> 6, d = c & 63;
                u16 tmp[4];
#pragma unroll
                for (int r = 0; r < 4; ++r) tmp[r] = f2bf(acc[mt][nt][r]);
                *(ushort4*)(vT + (size_t)(bb * 4 + hh) * 16384 + d * 256 + node0) = *(ushort4*)tmp;
            }
        }
    }
}

// ---------------- final projection GEMM (K=128, f32 out + bias) ----------------

__global__ __launch_bounds__(256) void gemm_proj(const u16* __restrict__ A,
                                                 const u16* __restrict__ BT,
                                                 float* __restrict__ Out,
                                                 const float* __restrict__ bias) {
    __shared__ __align__(16) u16 lds[8192];
    char* ldsc = (char*)lds;
    int t = threadIdx.x, lane = t & 63, wid = t >> 6;
    int row0 = blockIdx.x * 128;

    f32x4 zero = {0.f, 0.f, 0.f, 0.f};
    f32x4 acc[4][4];
#pragma unroll
    for (int mt = 0; mt < 4; ++mt)
#pragma unroll
        for (int nt = 0; nt < 4; ++nt) acc[mt][nt] = zero;

    int wr = wid >> 1, wc = wid & 1;
    int rA = wr * 64 + (lane & 15);
    int rB = wc * 64 + (lane & 15);
    int kch = (lane >> 4) << 4;

    for (int kt = 0; kt < 4; ++kt) {
        int kc = kt << 5;
#pragma unroll
        for (int i = 0; i < 2; ++i) {
            int off = wid * 2048 + i * 1024 + lane * 16;
            int r = off >> 6, cb = off & 63;
            __builtin_amdgcn_global_load_lds((const u32*)((const char*)A + ((size_t)(row0 + r) * 128 + kc) * 2 + cb),
                                             (u32*)(ldsc + wid * 2048 + i * 1024), 16, 0, 0);
            __builtin_amdgcn_global_load_lds((const u32*)((const char*)BT + ((size_t)r * 128 + kc) * 2 + cb),
                                             (u32*)(ldsc + 8192 + wid * 2048 + i * 1024), 16, 0, 0);
        }
        __syncthreads();
        bf16x8 af[4], bfr[4];
#pragma unroll
        for (int mt = 0; mt < 4; ++mt)
            af[mt] = *(const bf16x8*)(ldsc + (rA + mt * 16) * 64 + kch);
#pragma unroll
        for (int nt = 0; nt < 4; ++nt)
            bfr[nt] = *(const bf16x8*)(ldsc + 8192 + (rB + nt * 16) * 64 + kch);
#pragma unroll
        for (int mt = 0; mt < 4; ++mt)
#pragma unroll
            for (int nt = 0; nt < 4; ++nt)
                acc[mt][nt] = __builtin_amdgcn_mfma_f32_16x16x32_bf16(af[mt], bfr[nt], acc[mt][nt], 0, 0, 0);
        __syncthreads();
    }

    int colb = wc * 64 + (lane & 15);
    int rowb = row0 + wr * 64 + ((lane >> 4) << 2);
#pragma unroll
    for (int mt = 0; mt < 4; ++mt)
#pragma unroll
        for (int nt = 0; nt < 4; ++nt)
#pragma unroll
            for (int r = 0; r < 4; ++r)
                Out[(size_t)(rowb + mt * 16 + r) * 128 + colb + nt * 16] =
                    acc[mt][nt][r] + bias[colb + nt * 16];
}

// ---------------- conv GEMM with fused bias + LN + relu ----------------

template<int KK>
__global__ __launch_bounds__(256) void gemm_conv_ln(const u16* __restrict__ A,
                                                    const u16* __restrict__ BT,
                                                    const float* __restrict__ rb,
                                                    const float* __restrict__ g,
                                                    const float* __restrict__ be,
                                                    u16* __restrict__ hout) {
    __shared__ __align__(16) u16 lds[8192];
    char* ldsc = (char*)lds;
    int t = threadIdx.x, lane = t & 63, wid = t >> 6;
    int row0 = blockIdx.x * 128;

    f32x4 zero = {0.f, 0.f, 0.f, 0.f};
    f32x4 acc[4][4];
#pragma unroll
    for (int mt = 0; mt < 4; ++mt)
#pragma unroll
        for (int nt = 0; nt < 4; ++nt) acc[mt][nt] = zero;

    int wr = wid >> 1, wc = wid & 1;
    int rA = wr * 64 + (lane & 15);
    int rB = wc * 64 + (lane & 15);
    int kch = (lane >> 4) << 4;

    for (int kt = 0; kt < (KK >> 5); ++kt) {
        int kc = kt << 5;
#pragma unroll
        for (int i = 0; i < 2; ++i) {
            int off = wid * 2048 + i * 1024 + lane * 16;
            int r = off >> 6, cb = off & 63;
            __builtin_amdgcn_global_load_lds((const u32*)((const char*)A + ((size_t)(row0 + r) * KK + kc) * 2 + cb),
                                             (u32*)(ldsc + wid * 2048 + i * 1024), 16, 0, 0);
            __builtin_amdgcn_global_load_lds((const u32*)((const char*)BT + ((size_t)r * KK + kc) * 2 + cb),
                                             (u32*)(ldsc + 8192 + wid * 2048 + i * 1024), 16, 0, 0);
        }
        __syncthreads();
        bf16x8 af[4], bfr[4];
#pragma unroll
        for (int mt = 0; mt < 4; ++mt)
            af[mt] = *(const bf16x8*)(ldsc + (rA + mt * 16) * 64 + kch);
#pragma unroll
        for (int nt = 0; nt < 4; ++nt)
            bfr[nt] = *(const bf16x8*)(ldsc + 8192 + (rB + nt * 16) * 64 + kch);
#pragma unroll
        for (int mt = 0; mt < 4; ++mt)
#pragma unroll
            for (int nt = 0; nt < 4; ++nt)
                acc[mt][nt] = __builtin_amdgcn_mfma_f32_16x16x32_bf16(af[mt], bfr[nt], acc[mt][nt], 0, 0, 0);
        __syncthreads();
    }

    float* redS = (float*)ldsc;            // [128][2]
    float* redQ = (float*)(ldsc + 2048);   // [128][2]
    int colbase = wc * 64 + (lane & 15);
    int qrow = (lane >> 4) << 2;
    float rbv[4], gv[4], bev[4];
#pragma unroll
    for (int nt = 0; nt < 4; ++nt) {
        int c = colbase + nt * 16;
        rbv[nt] = rb[c]; gv[nt] = g[c]; bev[nt] = be[c];
    }
#pragma unroll
    for (int mt = 0; mt < 4; ++mt)
#pragma unroll
        for (int r = 0; r < 4; ++r) {
            float s = 0.f, q = 0.f;
#pragma unroll
            for (int nt = 0; nt < 4; ++nt) {
                float v = acc[mt][nt][r] + rbv[nt];
                s += v; q += v * v;
            }
            s = red16(s); q = red16(q);
            if ((lane & 15) == 0) {
                int lr = wr * 64 + qrow + mt * 16 + r;
                redS[lr * 2 + wc] = s; redQ[lr * 2 + wc] = q;
            }
        }
    __syncthreads();
#pragma unroll
    for (int mt = 0; mt < 4; ++mt)
#pragma unroll
        for (int r = 0; r < 4; ++r) {
            int lr = wr * 64 + qrow + mt * 16 + r;
            float mu = (redS[lr * 2] + redS[lr * 2 + 1]) * (1.f / 128.f);
            float var = (redQ[lr * 2] + redQ[lr * 2 + 1]) * (1.f / 128.f) - mu * mu;
            float rs = rsqrtf(var + 1e-5f);
            size_t rbase = (size_t)(row0 + lr) * 128;
#pragma unroll
            for (int nt = 0; nt < 4; ++nt) {
                float v = acc[mt][nt][r] + rbv[nt];
                float o = (v - mu) * rs * gv[nt] + bev[nt];
                o = o < 0.f ? 0.f : o;
                hout[rbase + colbase + nt * 16] = f2bf(o);
            }
        }
}

// ---------------- fc GEMM with fused LN -> +residual -> LN (K=256, Mtot=128) ----------------

__global__ __launch_bounds__(256) void gemm_fc_ln2(const u16* __restrict__ A,
                                                   const u16* __restrict__ BT,
                                                   const float* __restrict__ mg,
                                                   const float* __restrict__ mb,
                                                   const float* __restrict__ eg,
                                                   const float* __restrict__ eb,
                                                   u16* __restrict__ h) {
    __shared__ __align__(16) u16 lds[8192];
    char* ldsc = (char*)lds;
    int t = threadIdx.x, lane = t & 63, wid = t >> 6;
    int row0 = blockIdx.x * 128;

    f32x4 zero = {0.f, 0.f, 0.f, 0.f};
    f32x4 acc[4][4];
#pragma unroll
    for (int mt = 0; mt < 4; ++mt)
#pragma unroll
        for (int nt = 0; nt < 4; ++nt) acc[mt][nt] = zero;

    int wr = wid >> 1, wc = wid & 1;
    int rA = wr * 64 + (lane & 15);
    int rB = wc * 64 + (lane & 15);
    int kch = (lane >> 4) << 4;

    for (int kt = 0; kt < 8; ++kt) {
        int kc = kt << 5;
#pragma unroll
        for (int i = 0; i < 2; ++i) {
            int off = wid * 2048 + i * 1024 + lane * 16;
            int r = off >> 6, cb = off & 63;
            __builtin_amdgcn_global_load_lds((const u32*)((const char*)A + ((size_t)(row0 + r) * 256 + kc) * 2 + cb),
                                             (u32*)(ldsc + wid * 2048 + i * 1024), 16, 0, 0);
            __builtin_amdgcn_global_load_lds((const u32*)((const char*)BT + ((size_t)r * 256 + kc) * 2 + cb),
                                             (u32*)(ldsc + 8192 + wid * 2048 + i * 1024), 16, 0, 0);
        }
        __syncthreads();
        bf16x8 af[4], bfr[4];
#pragma unroll
        for (int mt = 0; mt < 4; ++mt)
            af[mt] = *(const bf16x8*)(ldsc + (rA + mt * 16) * 64 + kch);
#pragma unroll
        for (int nt = 0; nt < 4; ++nt)
            bfr[nt] = *(const bf16x8*)(ldsc + 8192 + (rB + nt * 16) * 64 + kch);
#pragma unroll
        for (int mt = 0; mt < 4; ++mt)
#pragma unroll
            for (int nt = 0; nt < 4; ++nt)
                acc[mt][nt] = __builtin_amdgcn_mfma_f32_16x16x32_bf16(af[mt], bfr[nt], acc[mt][nt], 0, 0, 0);
        __syncthreads();
    }

    float* redS  = (float*)ldsc;
    float* redQ  = (float*)(ldsc + 2048);
    float* redS2 = (float*)(ldsc + 4096);
    float* redQ2 = (float*)(ldsc + 6144);
    int colbase = wc * 64 + (lane & 15);
    int qrow = (lane >> 4) << 2;
    float mgv[4], mbv[4], egv[4], ebv[4];
#pragma unroll
    for (int nt = 0; nt < 4; ++nt) {
        int c = colbase + nt * 16;
        mgv[nt] = mg[c]; mbv[nt] = mb[c]; egv[nt] = eg[c]; ebv[nt] = eb[c];
    }
#pragma unroll
    for (int mt = 0; mt < 4; ++mt)
#pragma unroll
        for (int r = 0; r < 4; ++r) {
            float s = 0.f, q = 0.f;
#pragma unroll
            for (int nt = 0; nt < 4; ++nt) {
                float v = acc[mt][nt][r];
                s += v; q += v * v;
            }
            s = red16(s); q = red16(q);
            if ((lane & 15) == 0) {
                int lr = wr * 64 + qrow + mt * 16 + r;
                redS[lr * 2 + wc] = s; redQ[lr * 2 + wc] = q;
            }
        }
    __syncthreads();
#pragma unroll
    for (int mt = 0; mt < 4; ++mt)
#pragma unroll
        for (int r = 0; r < 4; ++r) {
            int lr = wr * 64 + qrow + mt * 16 + r;
            float mu = (redS[lr * 2] + redS[lr * 2 + 1]) * (1.f / 128.f);
            float var = (redQ[lr * 2] + redQ[lr * 2 + 1]) * (1.f / 128.f) - mu * mu;
            float rs = rsqrtf(var + 1e-5f);
            size_t rbase = (size_t)(row0 + lr) * 128;
            float s2 = 0.f, q2 = 0.f;
#pragma unroll
            for (int nt = 0; nt < 4; ++nt) {
                float o = (acc[mt][nt][r] - mu) * rs * mgv[nt] + mbv[nt];
                float z = o + bf2f(h[rbase + colbase + nt * 16]);
                acc[mt][nt][r] = z;
                s2 += z; q2 += z * z;
            }
            s2 = red16(s2); q2 = red16(q2);
            if ((lane & 15) == 0) {
                redS2[lr * 2 + wc] = s2; redQ2[lr * 2 + wc] = q2;
            }
        }
    __syncthreads();
#pragma unroll
    for (int mt = 0; mt < 4; ++mt)
#pragma unroll
        for (int r = 0; r < 4; ++r) {
            int lr = wr * 64 + qrow + mt * 16 + r;
            float mu = (redS2[lr * 2] + redS2[lr * 2 + 1]) * (1.f / 128.f);
            float var = (redQ2[lr * 2] + redQ2[lr * 2 + 1]) * (1.f / 128.f) - mu * mu;
            float rs = rsqrtf(var + 1e-5f);
            size_t rbase = (size_t)(row0 + lr) * 128;
#pragma unroll
            for (int nt = 0; nt < 4; ++nt) {
                float z = acc[mt][nt][r];
                h[rbase + colbase + nt * 16] = f2bf((z - mu) * rs * egv[nt] + ebv[nt]);
            }
        }
}

// ---------------- fused attention: swapped QK^T, in-register P, zero LDS ----------------
// grid (b, qt=8), 512 thd = 8 waves: wave = (hh = w&3, qsub = w>>2); wave owns 16 q-rows of one head.
// After S^T = mfma(K,Q): lane holds q = lane&15, k = nt*16 + lg*4 + r (lg = lane>>4).

__global__ __launch_bounds__(512) void attn_k(const u16* __restrict__ qkv,
                                              const u16* __restrict__ vT,
                                              const float* __restrict__ mat,
                                              u16* __restrict__ ctx) {
    int t = threadIdx.x, lane = t & 63, w = t >> 6;
    int b = blockIdx.x, qt = blockIdx.y;
    int hh = w & 3, qsub = w >> 2;
    int nbase = b * LL;
    int qrow_l = qt * 32 + qsub * 16;
    int lg = lane >> 4, q16 = lane & 15;

    // Q as B-fragment: lane holds col=q16, dims lg*8..+7 (aq0: d 0..31, aq1: d 32..63)
    const u16* qsrc = qkv + (size_t)(nbase + qrow_l + q16) * 768 + hh * 64 + (lg << 3);
    bf16x8 aq0 = *(const bf16x8*)(qsrc);
    bf16x8 aq1 = *(const bf16x8*)(qsrc + 32);

    // K as A-fragment: lane holds row=k=nt*16+q16, dims lg*8..+7
    const u16* kbase = qkv + (size_t)nbase * 768 + 256 + hh * 64 + (lg << 3);
    f32x4 zero = {0.f, 0.f, 0.f, 0.f};
    f32x4 sc[16];
#pragma unroll
    for (int nt = 0; nt < 16; ++nt) {
        const u16* ks = kbase + (size_t)(nt * 16 + q16) * 768;
        bf16x8 k0 = *(const bf16x8*)(ks);
        bf16x8 k1 = *(const bf16x8*)(ks + 32);
        f32x4 a = __builtin_amdgcn_mfma_f32_16x16x32_bf16(k0, aq0, zero, 0, 0, 0);
        a = __builtin_amdgcn_mfma_f32_16x16x32_bf16(k1, aq1, a, 0, 0, 0);
        sc[nt] = a;   // sc[nt][r] = S[q16][nt*16 + lg*4 + r]
    }

    // mat: vector f32x4 load per nt (k = nt*16+lg*4 .. +3)
    const float* mrow = mat + ((size_t)b * LL + qrow_l + q16) * LL + (lg << 2);
#pragma unroll
    for (int nt = 0; nt < 16; ++nt) {
        f32x4 mv = *(const f32x4*)(mrow + nt * 16);
#pragma unroll
        for (int r = 0; r < 4; ++r)
            sc[nt][r] *= 0.125f * mv[r];
    }

    // softmax over k: lane-local 64 values + reduce across lg (xor 16, 32)
    float mx = -1e30f;
#pragma unroll
    for (int nt = 0; nt < 16; ++nt)
#pragma unroll
        for (int r = 0; r < 4; ++r) mx = fmaxf(mx, sc[nt][r]);
    mx = fmaxf(mx, __shfl_xor(mx, 16, 64));
    mx = fmaxf(mx, __shfl_xor(mx, 32, 64));
    float sm = 0.f;
#pragma unroll
    for (int nt = 0; nt < 16; ++nt)
#pragma unroll
        for (int r = 0; r < 4; ++r) {
            float e = __expf(sc[nt][r] - mx);
            sc[nt][r] = e;
            sm += e;
        }
    sm += __shfl_xor(sm, 16, 64);
    sm += __shfl_xor(sm, 32, 64);
    float inv = 1.f / sm;
#pragma unroll
    for (int nt = 0; nt < 16; ++nt)
#pragma unroll
        for (int r = 0; r < 4; ++r) sc[nt][r] *= inv;

    // PV: build P A-fragment in registers per kt via cvt_pk + UNCONDITIONAL bpermutes + cndmask
    const u16* vbase = vT + (size_t)(b * 4 + hh) * 16384 + (lg << 3);
    f32x4 oa[4];
#pragma unroll
    for (int dt = 0; dt < 4; ++dt) oa[dt] = zero;
    bool loA = (lg < 2);
    int s01 = q16 + ((lg & 1) << 5);   // q16 + 32*(lg&1)
    int s23 = s01 + 16;
#pragma unroll
    for (int kt = 0; kt < 8; ++kt) {
        u32 A0 = cvtpk(sc[2 * kt][0], sc[2 * kt][1]);
        u32 A1 = cvtpk(sc[2 * kt][2], sc[2 * kt][3]);
        u32 B0 = cvtpk(sc[2 * kt + 1][0], sc[2 * kt + 1][1]);
        u32 B1 = cvtpk(sc[2 * kt + 1][2], sc[2 * kt + 1][3]);
        // all 8 bpermutes straight-line (full exec mask), select afterwards
        u32 a0s = bperm(s01, A0), b0s = bperm(s01, B0);
        u32 a1s = bperm(s01, A1), b1s = bperm(s01, B1);
        u32 a0t = bperm(s23, A0), b0t = bperm(s23, B0);
        u32 a1t = bperm(s23, A1), b1t = bperm(s23, B1);
        union { u32 u[4]; bf16x8 v; } pa;
        pa.u[0] = loA ? a0s : b0s;
        pa.u[1] = loA ? a1s : b1s;
        pa.u[2] = loA ? a0t : b0t;
        pa.u[3] = loA ? a1t : b1t;
#pragma unroll
        for (int dt = 0; dt < 4; ++dt) {
            bf16x8 bv = *(const bf16x8*)(vbase + (size_t)(dt * 16 + q16) * 256 + kt * 32);
            oa[dt] = __builtin_amdgcn_mfma_f32_16x16x32_bf16(pa.v, bv, oa[dt], 0, 0, 0);
        }
    }
    // oa[dt]: col=lane&15 = d, row = q = lg*4 + r
#pragma unroll
    for (int dt = 0; dt < 4; ++dt)
#pragma unroll
        for (int r = 0; r < 4; ++r)
            ctx[(size_t)(nbase + qrow_l + (lg << 2) + r) * 256 + hh * 64 + dt * 16 + q16] = f2bf(oa[dt][r]);
}

// ---------------- host launch ----------------

extern "C" void kernel_launch(void* const* d_in, const int* in_sizes, int n_in,
                              void* d_out, int out_size, void* d_ws, size_t ws_size,
                              hipStream_t stream) {
    (void)out_size; (void)ws_size; (void)n_in;
    const float* x        = (const float*)d_in[0];
    const int*   ei       = (const int*)d_in[1];
    const float* ea       = (const float*)d_in[2];
    const float* adj      = (const float*)d_in[3];
    const float* dis      = (const float*)d_in[4];
    int pb = (in_sizes[5] == 5120) ? 5 : 6;
    const float* g0_rel_w = (const float*)d_in[pb + 0];
    const float* g0_rel_b = (const float*)d_in[pb + 1];
    const float* g0_root_w= (const float*)d_in[pb + 2];
    const float* g_rel_w  = (const float*)d_in[pb + 3];
    const float* g_rel_b  = (const float*)d_in[pb + 4];
    const float* g_root_w = (const float*)d_in[pb + 5];
    const float* nm_g     = (const float*)d_in[pb + 6];
    const float* nm_b     = (const float*)d_in[pb + 7];
    const float* wq       = (const float*)d_in[pb + 8];
    const float* wk       = (const float*)d_in[pb + 9];
    const float* wv       = (const float*)d_in[pb + 10];
    const float* fc       = (const float*)d_in[pb + 11];
    const float* mha_g    = (const float*)d_in[pb + 12];
    const float* mha_b    = (const float*)d_in[pb + 13];
    const float* enc_g    = (const float*)d_in[pb + 14];
    const float* enc_b    = (const float*)d_in[pb + 15];
    const float* proj_w   = (const float*)d_in[pb + 16];
    const float* proj_b   = (const float*)d_in[pb + 17];
    const int* srcI = ei;
    const int* dstI = ei + EDGES;

    char* w = (char*)d_ws;
    float* Wf     = (float*)w; w += (size_t)33554432;   // W f32 scatter, then reused as `mat`
    u16*   Acat   = (u16*)w;   w += (size_t)16777216;   // ctx aliases this
    u16*   h      = (u16*)w;   w += (size_t)8388608;
    u16*   qkv    = (u16*)w;   w += (size_t)50331648;
    u16*   Wb     = (u16*)w;   w += (size_t)16777216;   // W bf16 [128][256][256]
    u16*   bigT   = (u16*)w;   w += (size_t)16777216;   // hT (8.4MB) / vT (16.7MB), temporally disjoint
    u16* wconvT0  = (u16*)w;   w += (size_t)32768;
    u16* wconvT   = (u16*)w;   w += (size_t)196608;
    u16* wqkvT    = (u16*)w;   w += (size_t)786432;
    u16* fcT      = (u16*)w;   w += (size_t)262144;
    u16* projT    = (u16*)w;   w += (size_t)32768;
    float* mat = Wf;
    u16*   ctx = Acat;
    u16*   hT  = bigT;
    u16*   vT  = bigT;

    // --- prep ---
    zero_f32<<<32768, 256, 0, stream>>>(Wf, 8388608);
    scatter_w_k<<<2048, 256, 0, stream>>>(srcI, dstI, ea, Wf);
    cast_w_k<<<8192, 256, 0, stream>>>(Wf, Wb);
    build_matrix_k<<<32768, 256, 0, stream>>>(adj, dis, mat, NB * LL * LL);

    build_wconvT0_k<<<64, 256, 0, stream>>>(g0_rel_w, g0_root_w, wconvT0);
    for (int i = 0; i < 3; ++i)
        build_wconvT_k<<<128, 256, 0, stream>>>(g_rel_w + i * 16384, g_root_w + i * 16384,
                                                wconvT + i * 32768);
    for (int i = 0; i < 4; ++i)
        build_wqkvT_k<<<384, 256, 0, stream>>>(wq + i * 32768, wk + i * 32768, wv + i * 32768,
                                               wqkvT + i * 98304);
    for (int i = 0; i < 4; ++i)
        transpose_cast_k<<<128, 256, 0, stream>>>(fc + i * 32768, fcT + i * 32768, 256, 128);
    transpose_cast_k<<<64, 256, 0, stream>>>(proj_w, projT, 128, 128);

    for (int L = 0; L < 4; ++L) {
        if (L == 0) {
            transpose_h_k<true><<<2048, 256, 0, stream>>>(h, x, hT);
            gemm_agg<true><<<256, 256, 0, stream>>>(Wb, hT, h, x, Acat);
            gemm_conv_ln<128><<<256, 256, 0, stream>>>(Acat, wconvT0, g0_rel_b,
                                                       nm_g, nm_b, h);
        } else {
            transpose_h_k<false><<<2048, 256, 0, stream>>>(h, x, hT);
            gemm_agg<false><<<256, 256, 0, stream>>>(Wb, hT, h, x, Acat);
            gemm_conv_ln<256><<<256, 256, 0, stream>>>(Acat, wconvT + (L - 1) * 32768,
                                                       g_rel_b + (L - 1) * 128,
                                                       nm_g + L * 128, nm_b + L * 128, h);
        }
        gemm_qkv<<<dim3(256, 6), 256, 0, stream>>>(h, wqkvT + L * 98304, qkv, vT);
        attn_k<<<dim3(NB, 8), 512, 0, stream>>>(qkv, vT, mat, ctx);
        gemm_fc_ln2<<<256, 256, 0, stream>>>(ctx, fcT + L * 32768,
                                             mha_g + L * 128, mha_b + L * 128,
                                             enc_g + L * 128, enc_b + L * 128, h);
    }
    gemm_proj<<<256, 256, 0, stream>>>(h, projT, (float*)d_out, proj_b);
}

// Round 9
// 580.750 us; speedup vs baseline: 1.1961x; 1.1961x over previous
//
#include <hip/hip_runtime.h>
#include <stdint.h>

typedef unsigned short u16;
typedef unsigned int u32;
typedef __attribute__((ext_vector_type(4))) float f32x4;
typedef __attribute__((ext_vector_type(8))) short bf16x8;

#define NB 128      // graphs
#define LL 256      // nodes per graph
#define DD 128      // hidden
#define EDGES 524288
#define EPG 4096    // edges per graph
#define NN (NB*LL)

__device__ __forceinline__ float bf2f(u16 u) {
    union { u32 i; float f; } v; v.i = ((u32)u) << 16; return v.f;
}
__device__ __forceinline__ u16 f2bf(float f) {
    union { float f; u32 i; } v; v.f = f;
    u32 i = v.i;
    u32 r = (i + 0x7fffu + ((i >> 16) & 1u)) >> 16;   // RNE
    return (u16)r;
}
__device__ __forceinline__ float matfn(float a, float dv) {
    if (a != 0.f) return (a == 1.2f) ? 1.1f : a;
    return (dv == 0.f) ? 0.f : exp2f((1.f - dv) * 0.5849625007211562f); // 1.5^(1-dis)
}
__device__ __forceinline__ float red16(float v) {
#pragma unroll
    for (int off = 1; off < 16; off <<= 1) v += __shfl_xor(v, off, 64);
    return v;
}
__device__ __forceinline__ u32 cvtpk(float lo, float hi) {
    u32 r;
    asm("v_cvt_pk_bf16_f32 %0, %1, %2" : "=v"(r) : "v"(lo), "v"(hi));
    return r;
}
__device__ __forceinline__ u32 bperm(int srcLane, u32 v) {
    return (u32)__builtin_amdgcn_ds_bpermute(srcLane << 2, (int)v);
}

// ---------------- prep kernels ----------------

__global__ __launch_bounds__(256) void build_matrix_k(const float* __restrict__ adj,
                                                      const float* __restrict__ dis,
                                                      float* __restrict__ mat, int n) {
    int i = blockIdx.x * 256 + threadIdx.x;
    if (i >= n) return;
    mat[i] = matfn(adj[i], dis[i]);
}

__global__ __launch_bounds__(256) void zero_f32(float* __restrict__ p, int n) {
    int i = blockIdx.x * 256 + threadIdx.x;
    if (i < n) p[i] = 0.f;
}

__global__ __launch_bounds__(256) void scatter_w_k(const int* __restrict__ srcI,
                                                   const int* __restrict__ dstI,
                                                   const float* __restrict__ ew,
                                                   float* __restrict__ Wf) {
    int e = blockIdx.x * 256 + threadIdx.x;
    if (e >= EDGES) return;
    int b = e >> 12;
    atomicAdd(&Wf[(size_t)b * 65536 + (size_t)(dstI[e] & 255) * 256 + (srcI[e] & 255)], ew[e]);
}

__global__ __launch_bounds__(256) void cast_w_k(const float* __restrict__ Wf, u16* __restrict__ Wb) {
    int i = blockIdx.x * 256 + threadIdx.x;
    float4 v = ((const float4*)Wf)[i];
    ushort4 o;
    o.x = f2bf(v.x); o.y = f2bf(v.y); o.z = f2bf(v.z); o.w = f2bf(v.w);
    ((ushort4*)Wb)[i] = o;
}

__global__ __launch_bounds__(256) void build_wconvT0_k(const float* __restrict__ rel,
                                                       const float* __restrict__ root,
                                                       u16* __restrict__ dst) {
    int i = blockIdx.x * 256 + threadIdx.x;   // 128*128
    int m = i >> 7, k = i & 127;
    float v = 0.f;
    if (k < 40) v = rel[k * 128 + m];
    else if (k >= 64 && k < 104) v = root[(k - 64) * 128 + m];
    dst[m * 128 + k] = f2bf(v);
}

__global__ __launch_bounds__(256) void build_wconvT_k(const float* __restrict__ rel,
                                                      const float* __restrict__ root,
                                                      u16* __restrict__ dst) {
    int i = blockIdx.x * 256 + threadIdx.x;   // 128*256
    int m = i >> 8, k = i & 255;
    float v = (k < 128) ? rel[k * 128 + m] : root[(k - 128) * 128 + m];
    dst[m * 256 + k] = f2bf(v);
}

__global__ __launch_bounds__(256) void build_wqkvT_k(const float* __restrict__ wq,
                                                     const float* __restrict__ wk,
                                                     const float* __restrict__ wv,
                                                     u16* __restrict__ dst) {
    int i = blockIdx.x * 256 + threadIdx.x;   // 768*128
    int m = i >> 7, k = i & 127;
    const float* s = (m < 256) ? wq : (m < 512) ? wk : wv;
    int mm = m & 255;
    dst[m * 128 + k] = f2bf(s[k * 256 + mm]);
}

__global__ __launch_bounds__(256) void transpose_cast_k(const float* __restrict__ src,
                                                        u16* __restrict__ dst, int K, int M) {
    int i = blockIdx.x * 256 + threadIdx.x;
    if (i >= K * M) return;
    int m = i / K, k = i - m * K;
    dst[i] = f2bf(src[k * M + m]);   // dst [M][K]
}

// per-graph transpose: h [N,128] bf16 (or x [N,40] f32, zero-padded) -> hT [b][128][256]
template<bool IS0>
__global__ __launch_bounds__(256) void transpose_h_k(const u16* __restrict__ h,
                                                     const float* __restrict__ x,
                                                     u16* __restrict__ hT) {
    int gw = blockIdx.x * 4 + (threadIdx.x >> 6);
    int lane = threadIdx.x & 63;
    int b = gw >> 6, rem = gw & 63, db = rem >> 5, jb = rem & 31;
    int d = (db << 6) + lane;
    u16 vals[8];
#pragma unroll
    for (int jj = 0; jj < 8; ++jj) {
        int node = (b << 8) + (jb << 3) + jj;
        if (IS0) vals[jj] = (d < 40) ? f2bf(x[(size_t)node * 40 + d]) : (u16)0;
        else     vals[jj] = h[(size_t)node * 128 + d];
    }
    *(uint4*)(hT + (size_t)b * 32768 + (size_t)d * 256 + (jb << 3)) = *(uint4*)vals;
}

// ---------------- per-graph aggregation GEMM: Acat = [W@h | h]  (K=256) ----------------

template<bool IS0>
__global__ __launch_bounds__(256) void gemm_agg(const u16* __restrict__ Wb,
                                                const u16* __restrict__ BT0,
                                                const u16* __restrict__ h,
                                                const float* __restrict__ x,
                                                u16* __restrict__ Acat) {
    __shared__ __align__(16) u16 lds[8192];
    char* ldsc = (char*)lds;
    int t = threadIdx.x, lane = t & 63, wid = t >> 6;
    int b = blockIdx.x >> 1, rt = blockIdx.x & 1;
    int row0 = rt << 7, nbase = b << 8;
    const u16* A = Wb + (size_t)b * 65536 + (size_t)row0 * 256;
    const u16* BT = BT0 + (size_t)b * 32768;

    f32x4 zero = {0.f, 0.f, 0.f, 0.f};
    f32x4 acc[4][4];
#pragma unroll
    for (int mt = 0; mt < 4; ++mt)
#pragma unroll
        for (int nt = 0; nt < 4; ++nt) acc[mt][nt] = zero;

    int wr = wid >> 1, wc = wid & 1;
    int rA = wr * 64 + (lane & 15);
    int rB = wc * 64 + (lane & 15);
    int kch = (lane >> 4) << 4;

    for (int kt = 0; kt < 8; ++kt) {
        int kc = kt << 5;
#pragma unroll
        for (int i = 0; i < 2; ++i) {
            int off = wid * 2048 + i * 1024 + lane * 16;
            int r = off >> 6, cb = off & 63;
            __builtin_amdgcn_global_load_lds((const u32*)((const char*)A + ((size_t)r * 256 + kc) * 2 + cb),
                                             (u32*)(ldsc + wid * 2048 + i * 1024), 16, 0, 0);
            __builtin_amdgcn_global_load_lds((const u32*)((const char*)BT + ((size_t)r * 256 + kc) * 2 + cb),
                                             (u32*)(ldsc + 8192 + wid * 2048 + i * 1024), 16, 0, 0);
        }
        __syncthreads();
        bf16x8 af[4], bfr[4];
#pragma unroll
        for (int mt = 0; mt < 4; ++mt)
            af[mt] = *(const bf16x8*)(ldsc + (rA + mt * 16) * 64 + kch);
#pragma unroll
        for (int nt = 0; nt < 4; ++nt)
            bfr[nt] = *(const bf16x8*)(ldsc + 8192 + (rB + nt * 16) * 64 + kch);
#pragma unroll
        for (int mt = 0; mt < 4; ++mt)
#pragma unroll
            for (int nt = 0; nt < 4; ++nt)
                acc[mt][nt] = __builtin_amdgcn_mfma_f32_16x16x32_bf16(af[mt], bfr[nt], acc[mt][nt], 0, 0, 0);
        __syncthreads();
    }

    int colb = wc * 64 + (lane & 15);
    int rowb = wr * 64 + ((lane >> 4) << 2);
#pragma unroll
    for (int mt = 0; mt < 4; ++mt)
#pragma unroll
        for (int nt = 0; nt < 4; ++nt)
#pragma unroll
            for (int r = 0; r < 4; ++r) {
                int i = rowb + mt * 16 + r;
                int c = colb + nt * 16;
                float v = acc[mt][nt][r];
                if (IS0) Acat[(size_t)(nbase + row0 + i) * 128 + c] = f2bf(v);
                else     Acat[(size_t)(nbase + row0 + i) * 256 + c] = f2bf(v);
            }
    if (IS0) {
        for (int idx = t; idx < 128 * 40; idx += 256) {
            int i = idx / 40, c = idx - i * 40;
            int node = nbase + row0 + i;
            Acat[(size_t)node * 128 + 64 + c] = f2bf(x[(size_t)node * 40 + c]);
        }
    } else {
        for (int idx = t; idx < 2048; idx += 256) {
            int i = idx >> 4, q = idx & 15;
            int node = nbase + row0 + i;
            *(uint4*)(Acat + (size_t)node * 256 + 128 + (q << 3)) =
                *(const uint4*)(h + (size_t)node * 128 + (q << 3));
        }
    }
}

// ---------------- qkv GEMM (K=128, Mtot=768) with fused V->vT transpose epilogue ----------------

__global__ __launch_bounds__(256) void gemm_qkv(const u16* __restrict__ A,
                                                const u16* __restrict__ BT,
                                                u16* __restrict__ qkv,
                                                u16* __restrict__ vT) {
    __shared__ __align__(16) u16 lds[8192];
    char* ldsc = (char*)lds;
    int t = threadIdx.x, lane = t & 63, wid = t >> 6;
    int row0 = blockIdx.x * 128, col0 = blockIdx.y * 128;

    f32x4 zero = {0.f, 0.f, 0.f, 0.f};
    f32x4 acc[4][4];
#pragma unroll
    for (int mt = 0; mt < 4; ++mt)
#pragma unroll
        for (int nt = 0; nt < 4; ++nt) acc[mt][nt] = zero;

    int wr = wid >> 1, wc = wid & 1;
    int rA = wr * 64 + (lane & 15);
    int rB = wc * 64 + (lane & 15);
    int kch = (lane >> 4) << 4;

    for (int kt = 0; kt < 4; ++kt) {
        int kc = kt << 5;
#pragma unroll
        for (int i = 0; i < 2; ++i) {
            int off = wid * 2048 + i * 1024 + lane * 16;
            int r = off >> 6, cb = off & 63;
            __builtin_amdgcn_global_load_lds((const u32*)((const char*)A + ((size_t)(row0 + r) * 128 + kc) * 2 + cb),
                                             (u32*)(ldsc + wid * 2048 + i * 1024), 16, 0, 0);
            __builtin_amdgcn_global_load_lds((const u32*)((const char*)BT + ((size_t)(col0 + r) * 128 + kc) * 2 + cb),
                                             (u32*)(ldsc + 8192 + wid * 2048 + i * 1024), 16, 0, 0);
        }
        __syncthreads();
        bf16x8 af[4], bfr[4];
#pragma unroll
        for (int mt = 0; mt < 4; ++mt)
            af[mt] = *(const bf16x8*)(ldsc + (rA + mt * 16) * 64 + kch);
#pragma unroll
        for (int nt = 0; nt < 4; ++nt)
            bfr[nt] = *(const bf16x8*)(ldsc + 8192 + (rB + nt * 16) * 64 + kch);
#pragma unroll
        for (int mt = 0; mt < 4; ++mt)
#pragma unroll
            for (int nt = 0; nt < 4; ++nt)
                acc[mt][nt] = __builtin_amdgcn_mfma_f32_16x16x32_bf16(af[mt], bfr[nt], acc[mt][nt], 0, 0, 0);
        __syncthreads();
    }

    int colb = col0 + wc * 64 + (lane & 15);
    int rowb = row0 + wr * 64 + ((lane >> 4) << 2);
    if (col0 < 512) {
#pragma unroll
        for (int mt = 0; mt < 4; ++mt)
#pragma unroll
            for (int nt = 0; nt < 4; ++nt)
#pragma unroll
                for (int r = 0; r < 4; ++r)
                    qkv[(size_t)(rowb + mt * 16 + r) * 768 + colb + nt * 16] = f2bf(acc[mt][nt][r]);
    } else {
        int bb = row0 >> 8;
#pragma unroll
        for (int mt = 0; mt < 4; ++mt) {
            int node0 = (rowb + mt * 16) & 255;
#pragma unroll
            for (int nt = 0; nt < 4; ++nt) {
                int c = colb + nt * 16 - 512;
                int hh = c >> 6, d = c & 63;
                u16 tmp[4];
#pragma unroll
                for (int r = 0; r < 4; ++r) tmp[r] = f2bf(acc[mt][nt][r]);
                *(ushort4*)(vT + (size_t)(bb * 4 + hh) * 16384 + d * 256 + node0) = *(ushort4*)tmp;
            }
        }
    }
}

// ---------------- final projection GEMM (K=128, f32 out + bias) ----------------

__global__ __launch_bounds__(256) void gemm_proj(const u16* __restrict__ A,
                                                 const u16* __restrict__ BT,
                                                 float* __restrict__ Out,
                                                 const float* __restrict__ bias) {
    __shared__ __align__(16) u16 lds[8192];
    char* ldsc = (char*)lds;
    int t = threadIdx.x, lane = t & 63, wid = t >> 6;
    int row0 = blockIdx.x * 128;

    f32x4 zero = {0.f, 0.f, 0.f, 0.f};
    f32x4 acc[4][4];
#pragma unroll
    for (int mt = 0; mt < 4; ++mt)
#pragma unroll
        for (int nt = 0; nt < 4; ++nt) acc[mt][nt] = zero;

    int wr = wid >> 1, wc = wid & 1;
    int rA = wr * 64 + (lane & 15);
    int rB = wc * 64 + (lane & 15);
    int kch = (lane >> 4) << 4;

    for (int kt = 0; kt < 4; ++kt) {
        int kc = kt << 5;
#pragma unroll
        for (int i = 0; i < 2; ++i) {
            int off = wid * 2048 + i * 1024 + lane * 16;
            int r = off >> 6, cb = off & 63;
            __builtin_amdgcn_global_load_lds((const u32*)((const char*)A + ((size_t)(row0 + r) * 128 + kc) * 2 + cb),
                                             (u32*)(ldsc + wid * 2048 + i * 1024), 16, 0, 0);
            __builtin_amdgcn_global_load_lds((const u32*)((const char*)BT + ((size_t)r * 128 + kc) * 2 + cb),
                                             (u32*)(ldsc + 8192 + wid * 2048 + i * 1024), 16, 0, 0);
        }
        __syncthreads();
        bf16x8 af[4], bfr[4];
#pragma unroll
        for (int mt = 0; mt < 4; ++mt)
            af[mt] = *(const bf16x8*)(ldsc + (rA + mt * 16) * 64 + kch);
#pragma unroll
        for (int nt = 0; nt < 4; ++nt)
            bfr[nt] = *(const bf16x8*)(ldsc + 8192 + (rB + nt * 16) * 64 + kch);
#pragma unroll
        for (int mt = 0; mt < 4; ++mt)
#pragma unroll
            for (int nt = 0; nt < 4; ++nt)
                acc[mt][nt] = __builtin_amdgcn_mfma_f32_16x16x32_bf16(af[mt], bfr[nt], acc[mt][nt], 0, 0, 0);
        __syncthreads();
    }

    int colb = wc * 64 + (lane & 15);
    int rowb = row0 + wr * 64 + ((lane >> 4) << 2);
#pragma unroll
    for (int mt = 0; mt < 4; ++mt)
#pragma unroll
        for (int nt = 0; nt < 4; ++nt)
#pragma unroll
            for (int r = 0; r < 4; ++r)
                Out[(size_t)(rowb + mt * 16 + r) * 128 + colb + nt * 16] =
                    acc[mt][nt][r] + bias[colb + nt * 16];
}

// ---------------- conv GEMM with fused bias + LN + relu ----------------

template<int KK>
__global__ __launch_bounds__(256) void gemm_conv_ln(const u16* __restrict__ A,
                                                    const u16* __restrict__ BT,
                                                    const float* __restrict__ rb,
                                                    const float* __restrict__ g,
                                                    const float* __restrict__ be,
                                                    u16* __restrict__ hout) {
    __shared__ __align__(16) u16 lds[8192];
    char* ldsc = (char*)lds;
    int t = threadIdx.x, lane = t & 63, wid = t >> 6;
    int row0 = blockIdx.x * 128;

    f32x4 zero = {0.f, 0.f, 0.f, 0.f};
    f32x4 acc[4][4];
#pragma unroll
    for (int mt = 0; mt < 4; ++mt)
#pragma unroll
        for (int nt = 0; nt < 4; ++nt) acc[mt][nt] = zero;

    int wr = wid >> 1, wc = wid & 1;
    int rA = wr * 64 + (lane & 15);
    int rB = wc * 64 + (lane & 15);
    int kch = (lane >> 4) << 4;

    for (int kt = 0; kt < (KK >> 5); ++kt) {
        int kc = kt << 5;
#pragma unroll
        for (int i = 0; i < 2; ++i) {
            int off = wid * 2048 + i * 1024 + lane * 16;
            int r = off >> 6, cb = off & 63;
            __builtin_amdgcn_global_load_lds((const u32*)((const char*)A + ((size_t)(row0 + r) * KK + kc) * 2 + cb),
                                             (u32*)(ldsc + wid * 2048 + i * 1024), 16, 0, 0);
            __builtin_amdgcn_global_load_lds((const u32*)((const char*)BT + ((size_t)r * KK + kc) * 2 + cb),
                                             (u32*)(ldsc + 8192 + wid * 2048 + i * 1024), 16, 0, 0);
        }
        __syncthreads();
        bf16x8 af[4], bfr[4];
#pragma unroll
        for (int mt = 0; mt < 4; ++mt)
            af[mt] = *(const bf16x8*)(ldsc + (rA + mt * 16) * 64 + kch);
#pragma unroll
        for (int nt = 0; nt < 4; ++nt)
            bfr[nt] = *(const bf16x8*)(ldsc + 8192 + (rB + nt * 16) * 64 + kch);
#pragma unroll
        for (int mt = 0; mt < 4; ++mt)
#pragma unroll
            for (int nt = 0; nt < 4; ++nt)
                acc[mt][nt] = __builtin_amdgcn_mfma_f32_16x16x32_bf16(af[mt], bfr[nt], acc[mt][nt], 0, 0, 0);
        __syncthreads();
    }

    float* redS = (float*)ldsc;            // [128][2]
    float* redQ = (float*)(ldsc + 2048);   // [128][2]
    int colbase = wc * 64 + (lane & 15);
    int qrow = (lane >> 4) << 2;
    float rbv[4], gv[4], bev[4];
#pragma unroll
    for (int nt = 0; nt < 4; ++nt) {
        int c = colbase + nt * 16;
        rbv[nt] = rb[c]; gv[nt] = g[c]; bev[nt] = be[c];
    }
#pragma unroll
    for (int mt = 0; mt < 4; ++mt)
#pragma unroll
        for (int r = 0; r < 4; ++r) {
            float s = 0.f, q = 0.f;
#pragma unroll
            for (int nt = 0; nt < 4; ++nt) {
                float v = acc[mt][nt][r] + rbv[nt];
                s += v; q += v * v;
            }
            s = red16(s); q = red16(q);
            if ((lane & 15) == 0) {
                int lr = wr * 64 + qrow + mt * 16 + r;
                redS[lr * 2 + wc] = s; redQ[lr * 2 + wc] = q;
            }
        }
    __syncthreads();
#pragma unroll
    for (int mt = 0; mt < 4; ++mt)
#pragma unroll
        for (int r = 0; r < 4; ++r) {
            int lr = wr * 64 + qrow + mt * 16 + r;
            float mu = (redS[lr * 2] + redS[lr * 2 + 1]) * (1.f / 128.f);
            float var = (redQ[lr * 2] + redQ[lr * 2 + 1]) * (1.f / 128.f) - mu * mu;
            float rs = rsqrtf(var + 1e-5f);
            size_t rbase = (size_t)(row0 + lr) * 128;
#pragma unroll
            for (int nt = 0; nt < 4; ++nt) {
                float v = acc[mt][nt][r] + rbv[nt];
                float o = (v - mu) * rs * gv[nt] + bev[nt];
                o = o < 0.f ? 0.f : o;
                hout[rbase + colbase + nt * 16] = f2bf(o);
            }
        }
}

// ---------------- fc GEMM with fused LN -> +residual -> LN (K=256, Mtot=128) ----------------

__global__ __launch_bounds__(256) void gemm_fc_ln2(const u16* __restrict__ A,
                                                   const u16* __restrict__ BT,
                                                   const float* __restrict__ mg,
                                                   const float* __restrict__ mb,
                                                   const float* __restrict__ eg,
                                                   const float* __restrict__ eb,
                                                   u16* __restrict__ h) {
    __shared__ __align__(16) u16 lds[8192];
    char* ldsc = (char*)lds;
    int t = threadIdx.x, lane = t & 63, wid = t >> 6;
    int row0 = blockIdx.x * 128;

    f32x4 zero = {0.f, 0.f, 0.f, 0.f};
    f32x4 acc[4][4];
#pragma unroll
    for (int mt = 0; mt < 4; ++mt)
#pragma unroll
        for (int nt = 0; nt < 4; ++nt) acc[mt][nt] = zero;

    int wr = wid >> 1, wc = wid & 1;
    int rA = wr * 64 + (lane & 15);
    int rB = wc * 64 + (lane & 15);
    int kch = (lane >> 4) << 4;

    for (int kt = 0; kt < 8; ++kt) {
        int kc = kt << 5;
#pragma unroll
        for (int i = 0; i < 2; ++i) {
            int off = wid * 2048 + i * 1024 + lane * 16;
            int r = off >> 6, cb = off & 63;
            __builtin_amdgcn_global_load_lds((const u32*)((const char*)A + ((size_t)(row0 + r) * 256 + kc) * 2 + cb),
                                             (u32*)(ldsc + wid * 2048 + i * 1024), 16, 0, 0);
            __builtin_amdgcn_global_load_lds((const u32*)((const char*)BT + ((size_t)r * 256 + kc) * 2 + cb),
                                             (u32*)(ldsc + 8192 + wid * 2048 + i * 1024), 16, 0, 0);
        }
        __syncthreads();
        bf16x8 af[4], bfr[4];
#pragma unroll
        for (int mt = 0; mt < 4; ++mt)
            af[mt] = *(const bf16x8*)(ldsc + (rA + mt * 16) * 64 + kch);
#pragma unroll
        for (int nt = 0; nt < 4; ++nt)
            bfr[nt] = *(const bf16x8*)(ldsc + 8192 + (rB + nt * 16) * 64 + kch);
#pragma unroll
        for (int mt = 0; mt < 4; ++mt)
#pragma unroll
            for (int nt = 0; nt < 4; ++nt)
                acc[mt][nt] = __builtin_amdgcn_mfma_f32_16x16x32_bf16(af[mt], bfr[nt], acc[mt][nt], 0, 0, 0);
        __syncthreads();
    }

    float* redS  = (float*)ldsc;
    float* redQ  = (float*)(ldsc + 2048);
    float* redS2 = (float*)(ldsc + 4096);
    float* redQ2 = (float*)(ldsc + 6144);
    int colbase = wc * 64 + (lane & 15);
    int qrow = (lane >> 4) << 2;
    float mgv[4], mbv[4], egv[4], ebv[4];
#pragma unroll
    for (int nt = 0; nt < 4; ++nt) {
        int c = colbase + nt * 16;
        mgv[nt] = mg[c]; mbv[nt] = mb[c]; egv[nt] = eg[c]; ebv[nt] = eb[c];
    }
#pragma unroll
    for (int mt = 0; mt < 4; ++mt)
#pragma unroll
        for (int r = 0; r < 4; ++r) {
            float s = 0.f, q = 0.f;
#pragma unroll
            for (int nt = 0; nt < 4; ++nt) {
                float v = acc[mt][nt][r];
                s += v; q += v * v;
            }
            s = red16(s); q = red16(q);
            if ((lane & 15) == 0) {
                int lr = wr * 64 + qrow + mt * 16 + r;
                redS[lr * 2 + wc] = s; redQ[lr * 2 + wc] = q;
            }
        }
    __syncthreads();
#pragma unroll
    for (int mt = 0; mt < 4; ++mt)
#pragma unroll
        for (int r = 0; r < 4; ++r) {
            int lr = wr * 64 + qrow + mt * 16 + r;
            float mu = (redS[lr * 2] + redS[lr * 2 + 1]) * (1.f / 128.f);
            float var = (redQ[lr * 2] + redQ[lr * 2 + 1]) * (1.f / 128.f) - mu * mu;
            float rs = rsqrtf(var + 1e-5f);
            size_t rbase = (size_t)(row0 + lr) * 128;
            float s2 = 0.f, q2 = 0.f;
#pragma unroll
            for (int nt = 0; nt < 4; ++nt) {
                float o = (acc[mt][nt][r] - mu) * rs * mgv[nt] + mbv[nt];
                float z = o + bf2f(h[rbase + colbase + nt * 16]);
                acc[mt][nt][r] = z;
                s2 += z; q2 += z * z;
            }
            s2 = red16(s2); q2 = red16(q2);
            if ((lane & 15) == 0) {
                redS2[lr * 2 + wc] = s2; redQ2[lr * 2 + wc] = q2;
            }
        }
    __syncthreads();
#pragma unroll
    for (int mt = 0; mt < 4; ++mt)
#pragma unroll
        for (int r = 0; r < 4; ++r) {
            int lr = wr * 64 + qrow + mt * 16 + r;
            float mu = (redS2[lr * 2] + redS2[lr * 2 + 1]) * (1.f / 128.f);
            float var = (redQ2[lr * 2] + redQ2[lr * 2 + 1]) * (1.f / 128.f) - mu * mu;
            float rs = rsqrtf(var + 1e-5f);
            size_t rbase = (size_t)(row0 + lr) * 128;
#pragma unroll
            for (int nt = 0; nt < 4; ++nt) {
                float z = acc[mt][nt][r];
                h[rbase + colbase + nt * 16] = f2bf((z - mu) * rs * egv[nt] + ebv[nt]);
            }
        }
}

// ---------------- fused attention: per (b, head) block; K/V staged in LDS; P in registers ----------------
// grid (NB, 4) b fastest (XCD locality on mat). 512 thd = 8 waves; wave w handles q-rows w*32..w*32+31
// in two groups of 16. Swapped QK^T: lane holds q = lane&15, k = nt*16 + lg*4 + r.

__global__ __launch_bounds__(512) void attn_k(const u16* __restrict__ qkv,
                                              const u16* __restrict__ vT,
                                              const float* __restrict__ mat,
                                              u16* __restrict__ ctx) {
    __shared__ __align__(16) u16 Kl[256 * 72];   // 36864 B, padded rows
    __shared__ __align__(16) u16 Vl[64 * 264];   // 33792 B, padded rows
    int t = threadIdx.x, lane = t & 63, w = t >> 6;
    int b = blockIdx.x, hh = blockIdx.y;
    int nbase = b * LL;
    int lg = lane >> 4, q16 = lane & 15;

    // --- bulk staging (one barrier) ---
    if (t < 256) {
        const u16* src = qkv + (size_t)(nbase + t) * 768 + 256 + hh * 64;
#pragma unroll
        for (int i = 0; i < 8; ++i)
            *(uint4*)(Kl + t * 72 + i * 8) = *(const uint4*)(src + i * 8);
    } else {
        int tt = t - 256;
        const u16* vsrc = vT + (size_t)(b * 4 + hh) * 16384;
#pragma unroll
        for (int i = 0; i < 8; ++i) {
            int idx = tt * 8 + i;
            int d = idx >> 5, p = idx & 31;
            *(uint4*)(Vl + d * 264 + p * 8) = *(const uint4*)(vsrc + d * 256 + p * 8);
        }
    }
    __syncthreads();

    f32x4 zero = {0.f, 0.f, 0.f, 0.f};
    bool loA = (lg < 2);
    int s01 = q16 + ((lg & 1) << 5);
    int s23 = s01 + 16;

    for (int qi = 0; qi < 2; ++qi) {
        int qrow_l = w * 32 + qi * 16;

        // Q as B-fragment from global
        const u16* qsrc = qkv + (size_t)(nbase + qrow_l + q16) * 768 + hh * 64 + (lg << 3);
        bf16x8 aq0 = *(const bf16x8*)(qsrc);
        bf16x8 aq1 = *(const bf16x8*)(qsrc + 32);

        // QK^T with K from LDS
        f32x4 sc[16];
#pragma unroll
        for (int nt = 0; nt < 16; ++nt) {
            const u16* ks = Kl + (nt * 16 + q16) * 72 + (lg << 3);
            bf16x8 k0 = *(const bf16x8*)(ks);
            bf16x8 k1 = *(const bf16x8*)(ks + 32);
            f32x4 a = __builtin_amdgcn_mfma_f32_16x16x32_bf16(k0, aq0, zero, 0, 0, 0);
            a = __builtin_amdgcn_mfma_f32_16x16x32_bf16(k1, aq1, a, 0, 0, 0);
            sc[nt] = a;
        }

        // mat: vector f32x4 loads
        const float* mrow = mat + ((size_t)b * LL + qrow_l + q16) * LL + (lg << 2);
#pragma unroll
        for (int nt = 0; nt < 16; ++nt) {
            f32x4 mv = *(const f32x4*)(mrow + nt * 16);
#pragma unroll
            for (int r = 0; r < 4; ++r)
                sc[nt][r] *= 0.125f * mv[r];
        }

        // softmax over k
        float mx = -1e30f;
#pragma unroll
        for (int nt = 0; nt < 16; ++nt)
#pragma unroll
            for (int r = 0; r < 4; ++r) mx = fmaxf(mx, sc[nt][r]);
        mx = fmaxf(mx, __shfl_xor(mx, 16, 64));
        mx = fmaxf(mx, __shfl_xor(mx, 32, 64));
        float sm = 0.f;
#pragma unroll
        for (int nt = 0; nt < 16; ++nt)
#pragma unroll
            for (int r = 0; r < 4; ++r) {
                float e = __expf(sc[nt][r] - mx);
                sc[nt][r] = e;
                sm += e;
            }
        sm += __shfl_xor(sm, 16, 64);
        sm += __shfl_xor(sm, 32, 64);
        float inv = 1.f / sm;
#pragma unroll
        for (int nt = 0; nt < 16; ++nt)
#pragma unroll
            for (int r = 0; r < 4; ++r) sc[nt][r] *= inv;

        // PV with V from LDS, P built in registers
        f32x4 oa[4];
#pragma unroll
        for (int dt = 0; dt < 4; ++dt) oa[dt] = zero;
#pragma unroll
        for (int kt = 0; kt < 8; ++kt) {
            u32 A0 = cvtpk(sc[2 * kt][0], sc[2 * kt][1]);
            u32 A1 = cvtpk(sc[2 * kt][2], sc[2 * kt][3]);
            u32 B0 = cvtpk(sc[2 * kt + 1][0], sc[2 * kt + 1][1]);
            u32 B1 = cvtpk(sc[2 * kt + 1][2], sc[2 * kt + 1][3]);
            u32 a0s = bperm(s01, A0), b0s = bperm(s01, B0);
            u32 a1s = bperm(s01, A1), b1s = bperm(s01, B1);
            u32 a0t = bperm(s23, A0), b0t = bperm(s23, B0);
            u32 a1t = bperm(s23, A1), b1t = bperm(s23, B1);
            union { u32 u[4]; bf16x8 v; } pa;
            pa.u[0] = loA ? a0s : b0s;
            pa.u[1] = loA ? a1s : b1s;
            pa.u[2] = loA ? a0t : b0t;
            pa.u[3] = loA ? a1t : b1t;
#pragma unroll
            for (int dt = 0; dt < 4; ++dt) {
                bf16x8 bv = *(const bf16x8*)(Vl + (dt * 16 + q16) * 264 + kt * 32 + (lg << 3));
                oa[dt] = __builtin_amdgcn_mfma_f32_16x16x32_bf16(pa.v, bv, oa[dt], 0, 0, 0);
            }
        }
#pragma unroll
        for (int dt = 0; dt < 4; ++dt)
#pragma unroll
            for (int r = 0; r < 4; ++r)
                ctx[(size_t)(nbase + qrow_l + (lg << 2) + r) * 256 + hh * 64 + dt * 16 + q16] = f2bf(oa[dt][r]);
    }
}

// ---------------- host launch ----------------

extern "C" void kernel_launch(void* const* d_in, const int* in_sizes, int n_in,
                              void* d_out, int out_size, void* d_ws, size_t ws_size,
                              hipStream_t stream) {
    (void)out_size; (void)ws_size; (void)n_in;
    const float* x        = (const float*)d_in[0];
    const int*   ei       = (const int*)d_in[1];
    const float* ea       = (const float*)d_in[2];
    const float* adj      = (const float*)d_in[3];
    const float* dis      = (const float*)d_in[4];
    int pb = (in_sizes[5] == 5120) ? 5 : 6;
    const float* g0_rel_w = (const float*)d_in[pb + 0];
    const float* g0_rel_b = (const float*)d_in[pb + 1];
    const float* g0_root_w= (const float*)d_in[pb + 2];
    const float* g_rel_w  = (const float*)d_in[pb + 3];
    const float* g_rel_b  = (const float*)d_in[pb + 4];
    const float* g_root_w = (const float*)d_in[pb + 5];
    const float* nm_g     = (const float*)d_in[pb + 6];
    const float* nm_b     = (const float*)d_in[pb + 7];
    const float* wq       = (const float*)d_in[pb + 8];
    const float* wk       = (const float*)d_in[pb + 9];
    const float* wv       = (const float*)d_in[pb + 10];
    const float* fc       = (const float*)d_in[pb + 11];
    const float* mha_g    = (const float*)d_in[pb + 12];
    const float* mha_b    = (const float*)d_in[pb + 13];
    const float* enc_g    = (const float*)d_in[pb + 14];
    const float* enc_b    = (const float*)d_in[pb + 15];
    const float* proj_w   = (const float*)d_in[pb + 16];
    const float* proj_b   = (const float*)d_in[pb + 17];
    const int* srcI = ei;
    const int* dstI = ei + EDGES;

    char* w = (char*)d_ws;
    float* Wf     = (float*)w; w += (size_t)33554432;   // W f32 scatter, then reused as `mat`
    u16*   Acat   = (u16*)w;   w += (size_t)16777216;   // ctx aliases this
    u16*   h      = (u16*)w;   w += (size_t)8388608;
    u16*   qkv    = (u16*)w;   w += (size_t)50331648;
    u16*   Wb     = (u16*)w;   w += (size_t)16777216;   // W bf16 [128][256][256]
    u16*   bigT   = (u16*)w;   w += (size_t)16777216;   // hT (8.4MB) / vT (16.7MB), temporally disjoint
    u16* wconvT0  = (u16*)w;   w += (size_t)32768;
    u16* wconvT   = (u16*)w;   w += (size_t)196608;
    u16* wqkvT    = (u16*)w;   w += (size_t)786432;
    u16* fcT      = (u16*)w;   w += (size_t)262144;
    u16* projT    = (u16*)w;   w += (size_t)32768;
    float* mat = Wf;
    u16*   ctx = Acat;
    u16*   hT  = bigT;
    u16*   vT  = bigT;

    // --- prep ---
    zero_f32<<<32768, 256, 0, stream>>>(Wf, 8388608);
    scatter_w_k<<<2048, 256, 0, stream>>>(srcI, dstI, ea, Wf);
    cast_w_k<<<8192, 256, 0, stream>>>(Wf, Wb);
    build_matrix_k<<<32768, 256, 0, stream>>>(adj, dis, mat, NB * LL * LL);

    build_wconvT0_k<<<64, 256, 0, stream>>>(g0_rel_w, g0_root_w, wconvT0);
    for (int i = 0; i < 3; ++i)
        build_wconvT_k<<<128, 256, 0, stream>>>(g_rel_w + i * 16384, g_root_w + i * 16384,
                                                wconvT + i * 32768);
    for (int i = 0; i < 4; ++i)
        build_wqkvT_k<<<384, 256, 0, stream>>>(wq + i * 32768, wk + i * 32768, wv + i * 32768,
                                               wqkvT + i * 98304);
    for (int i = 0; i < 4; ++i)
        transpose_cast_k<<<128, 256, 0, stream>>>(fc + i * 32768, fcT + i * 32768, 256, 128);
    transpose_cast_k<<<64, 256, 0, stream>>>(proj_w, projT, 128, 128);

    for (int L = 0; L < 4; ++L) {
        if (L == 0) {
            transpose_h_k<true><<<2048, 256, 0, stream>>>(h, x, hT);
            gemm_agg<true><<<256, 256, 0, stream>>>(Wb, hT, h, x, Acat);
            gemm_conv_ln<128><<<256, 256, 0, stream>>>(Acat, wconvT0, g0_rel_b,
                                                       nm_g, nm_b, h);
        } else {
            transpose_h_k<false><<<2048, 256, 0, stream>>>(h, x, hT);
            gemm_agg<false><<<256, 256, 0, stream>>>(Wb, hT, h, x, Acat);
            gemm_conv_ln<256><<<256, 256, 0, stream>>>(Acat, wconvT + (L - 1) * 32768,
                                                       g_rel_b + (L - 1) * 128,
                                                       nm_g + L * 128, nm_b + L * 128, h);
        }
        gemm_qkv<<<dim3(256, 6), 256, 0, stream>>>(h, wqkvT + L * 98304, qkv, vT);
        attn_k<<<dim3(NB, 4), 512, 0, stream>>>(qkv, vT, mat, ctx);
        gemm_fc_ln2<<<256, 256, 0, stream>>>(ctx, fcT + L * 32768,
                                             mha_g + L * 128, mha_b + L * 128,
                                             enc_g + L * 128, enc_b + L * 128, h);
    }
    gemm_proj<<<256, 256, 0, stream>>>(h, projT, (float*)d_out, proj_b);
}

// Round 11
// 548.546 us; speedup vs baseline: 1.2663x; 1.0587x over previous
//
#include <hip/hip_runtime.h>
#include <stdint.h>

typedef unsigned short u16;
typedef unsigned int u32;
typedef __attribute__((ext_vector_type(4))) float f32x4;
typedef __attribute__((ext_vector_type(8))) short bf16x8;

#define NB 128      // graphs
#define LL 256      // nodes per graph
#define DD 128      // hidden
#define EDGES 524288
#define EPG 4096    // edges per graph
#define NN (NB*LL)

__device__ __forceinline__ float bf2f(u16 u) {
    union { u32 i; float f; } v; v.i = ((u32)u) << 16; return v.f;
}
__device__ __forceinline__ u16 f2bf(float f) {
    union { float f; u32 i; } v; v.f = f;
    u32 i = v.i;
    u32 r = (i + 0x7fffu + ((i >> 16) & 1u)) >> 16;   // RNE
    return (u16)r;
}
__device__ __forceinline__ float matfn(float a, float dv) {
    if (a != 0.f) return (a == 1.2f) ? 1.1f : a;
    return (dv == 0.f) ? 0.f : exp2f((1.f - dv) * 0.5849625007211562f); // 1.5^(1-dis)
}
__device__ __forceinline__ float red16(float v) {
#pragma unroll
    for (int off = 1; off < 16; off <<= 1) v += __shfl_xor(v, off, 64);
    return v;
}
__device__ __forceinline__ u32 cvtpk(float lo, float hi) {
    u32 r;
    asm("v_cvt_pk_bf16_f32 %0, %1, %2" : "=v"(r) : "v"(lo), "v"(hi));
    return r;
}
__device__ __forceinline__ u32 bperm(int srcLane, u32 v) {
    return (u32)__builtin_amdgcn_ds_bpermute(srcLane << 2, (int)v);
}

// ---------------- prep kernels ----------------

__global__ __launch_bounds__(256) void zero_f32(float* __restrict__ p, int n) {
    int i = blockIdx.x * 256 + threadIdx.x;
    if (i < n) p[i] = 0.f;
}

__global__ __launch_bounds__(256) void scatter_w_k(const int* __restrict__ srcI,
                                                   const int* __restrict__ dstI,
                                                   const float* __restrict__ ew,
                                                   float* __restrict__ Wf) {
    int e = blockIdx.x * 256 + threadIdx.x;
    if (e >= EDGES) return;
    int b = e >> 12;
    atomicAdd(&Wf[(size_t)b * 65536 + (size_t)(dstI[e] & 255) * 256 + (srcI[e] & 255)], ew[e]);
}

// NOTE: must run BEFORE build_matrix_k (mat aliases Wf).
__global__ __launch_bounds__(256) void cast_w_k(const float* __restrict__ Wf, u16* __restrict__ Wb) {
    int i = blockIdx.x * 256 + threadIdx.x;
    float4 v = ((const float4*)Wf)[i];
    ushort4 o;
    o.x = f2bf(v.x); o.y = f2bf(v.y); o.z = f2bf(v.z); o.w = f2bf(v.w);
    ((ushort4*)Wb)[i] = o;
}

__global__ __launch_bounds__(256) void build_matrix_k(const float* __restrict__ adj,
                                                      const float* __restrict__ dis,
                                                      float* __restrict__ mat) {
    int i = blockIdx.x * 256 + threadIdx.x;
    mat[i] = matfn(adj[i], dis[i]);
}

// all weight transposes in one kernel (655360 elements, 2560 blocks)
__global__ __launch_bounds__(256) void prep_weights_k(
        const float* __restrict__ g0_rel_w, const float* __restrict__ g0_root_w,
        const float* __restrict__ g_rel_w,  const float* __restrict__ g_root_w,
        const float* __restrict__ wq, const float* __restrict__ wk,
        const float* __restrict__ wv, const float* __restrict__ fc,
        const float* __restrict__ proj_w,
        u16* __restrict__ wconvT0, u16* __restrict__ wconvT,
        u16* __restrict__ wqkvT, u16* __restrict__ fcT, u16* __restrict__ projT) {
    int i = blockIdx.x * 256 + threadIdx.x;
    if (i < 16384) {
        int m = i >> 7, k = i & 127;
        float v = 0.f;
        if (k < 40) v = g0_rel_w[k * 128 + m];
        else if (k >= 64 && k < 104) v = g0_root_w[(k - 64) * 128 + m];
        wconvT0[i] = f2bf(v);
        return;
    }
    i -= 16384;
    if (i < 98304) {
        int l = i >> 15, jj = i & 32767;
        int m = jj >> 8, k = jj & 255;
        float v = (k < 128) ? g_rel_w[l * 16384 + k * 128 + m]
                            : g_root_w[l * 16384 + (k - 128) * 128 + m];
        wconvT[i] = f2bf(v);
        return;
    }
    i -= 98304;
    if (i < 393216) {
        int l = i / 98304, jj = i % 98304;
        int m = jj >> 7, k = jj & 127;
        const float* s = (m < 256) ? wq : (m < 512) ? wk : wv;
        int mm = m & 255;
        wqkvT[i] = f2bf(s[l * 32768 + k * 256 + mm]);
        return;
    }
    i -= 393216;
    if (i < 131072) {
        int l = i >> 15, jj = i & 32767;
        int m = jj >> 8, k = jj & 255;
        fcT[i] = f2bf(fc[l * 32768 + k * 128 + m]);
        return;
    }
    i -= 131072;
    {
        int m = i >> 7, k = i & 127;
        projT[i] = f2bf(proj_w[k * 128 + m]);
    }
}

// per-graph transpose: h [N,128] bf16 (or x [N,40] f32, zero-padded) -> hT [b][128][256]
template<bool IS0>
__global__ __launch_bounds__(256) void transpose_h_k(const u16* __restrict__ h,
                                                     const float* __restrict__ x,
                                                     u16* __restrict__ hT) {
    int gw = blockIdx.x * 4 + (threadIdx.x >> 6);
    int lane = threadIdx.x & 63;
    int b = gw >> 6, rem = gw & 63, db = rem >> 5, jb = rem & 31;
    int d = (db << 6) + lane;
    u16 vals[8];
#pragma unroll
    for (int jj = 0; jj < 8; ++jj) {
        int node = (b << 8) + (jb << 3) + jj;
        if (IS0) vals[jj] = (d < 40) ? f2bf(x[(size_t)node * 40 + d]) : (u16)0;
        else     vals[jj] = h[(size_t)node * 128 + d];
    }
    *(uint4*)(hT + (size_t)b * 32768 + (size_t)d * 256 + (jb << 3)) = *(uint4*)vals;
}

// ---------------- per-graph aggregation GEMM: Aagg = W@h  ([N,128]) ----------------

template<bool IS0>
__global__ __launch_bounds__(256) void gemm_agg(const u16* __restrict__ Wb,
                                                const u16* __restrict__ BT0,
                                                const float* __restrict__ x,
                                                u16* __restrict__ Aagg) {
    __shared__ __align__(16) u16 lds[8192];
    char* ldsc = (char*)lds;
    int t = threadIdx.x, lane = t & 63, wid = t >> 6;
    int b = blockIdx.x >> 1, rt = blockIdx.x & 1;
    int row0 = rt << 7, nbase = b << 8;
    const u16* A = Wb + (size_t)b * 65536 + (size_t)row0 * 256;
    const u16* BT = BT0 + (size_t)b * 32768;

    f32x4 zero = {0.f, 0.f, 0.f, 0.f};
    f32x4 acc[4][4];
#pragma unroll
    for (int mt = 0; mt < 4; ++mt)
#pragma unroll
        for (int nt = 0; nt < 4; ++nt) acc[mt][nt] = zero;

    int wr = wid >> 1, wc = wid & 1;
    int rA = wr * 64 + (lane & 15);
    int rB = wc * 64 + (lane & 15);
    int kch = (lane >> 4) << 4;

    for (int kt = 0; kt < 8; ++kt) {
        int kc = kt << 5;
#pragma unroll
        for (int i = 0; i < 2; ++i) {
            int off = wid * 2048 + i * 1024 + lane * 16;
            int r = off >> 6, cb = off & 63;
            __builtin_amdgcn_global_load_lds((const u32*)((const char*)A + ((size_t)r * 256 + kc) * 2 + cb),
                                             (u32*)(ldsc + wid * 2048 + i * 1024), 16, 0, 0);
            __builtin_amdgcn_global_load_lds((const u32*)((const char*)BT + ((size_t)r * 256 + kc) * 2 + cb),
                                             (u32*)(ldsc + 8192 + wid * 2048 + i * 1024), 16, 0, 0);
        }
        __syncthreads();
        bf16x8 af[4], bfr[4];
#pragma unroll
        for (int mt = 0; mt < 4; ++mt)
            af[mt] = *(const bf16x8*)(ldsc + (rA + mt * 16) * 64 + kch);
#pragma unroll
        for (int nt = 0; nt < 4; ++nt)
            bfr[nt] = *(const bf16x8*)(ldsc + 8192 + (rB + nt * 16) * 64 + kch);
#pragma unroll
        for (int mt = 0; mt < 4; ++mt)
#pragma unroll
            for (int nt = 0; nt < 4; ++nt)
                acc[mt][nt] = __builtin_amdgcn_mfma_f32_16x16x32_bf16(af[mt], bfr[nt], acc[mt][nt], 0, 0, 0);
        __syncthreads();
    }

    int colb = wc * 64 + (lane & 15);
    int rowb = wr * 64 + ((lane >> 4) << 2);
#pragma unroll
    for (int mt = 0; mt < 4; ++mt)
#pragma unroll
        for (int nt = 0; nt < 4; ++nt)
#pragma unroll
            for (int r = 0; r < 4; ++r)
                Aagg[(size_t)(nbase + row0 + rowb + mt * 16 + r) * 128 + colb + nt * 16]
                    = f2bf(acc[mt][nt][r]);
    if (IS0) {
        for (int idx = t; idx < 128 * 40; idx += 256) {
            int i = idx / 40, c = idx - i * 40;
            int node = nbase + row0 + i;
            Aagg[(size_t)node * 128 + 64 + c] = f2bf(x[(size_t)node * 40 + c]);
        }
    }
}

// ---------------- qkv GEMM (K=128, Mtot=768) with fused V->vT transpose epilogue ----------------

__global__ __launch_bounds__(256) void gemm_qkv(const u16* __restrict__ A,
                                                const u16* __restrict__ BT,
                                                u16* __restrict__ qkv,
                                                u16* __restrict__ vT) {
    __shared__ __align__(16) u16 lds[8192];
    char* ldsc = (char*)lds;
    int t = threadIdx.x, lane = t & 63, wid = t >> 6;
    int row0 = blockIdx.x * 128, col0 = blockIdx.y * 128;

    f32x4 zero = {0.f, 0.f, 0.f, 0.f};
    f32x4 acc[4][4];
#pragma unroll
    for (int mt = 0; mt < 4; ++mt)
#pragma unroll
        for (int nt = 0; nt < 4; ++nt) acc[mt][nt] = zero;

    int wr = wid >> 1, wc = wid & 1;
    int rA = wr * 64 + (lane & 15);
    int rB = wc * 64 + (lane & 15);
    int kch = (lane >> 4) << 4;

    for (int kt = 0; kt < 4; ++kt) {
        int kc = kt << 5;
#pragma unroll
        for (int i = 0; i < 2; ++i) {
            int off = wid * 2048 + i * 1024 + lane * 16;
            int r = off >> 6, cb = off & 63;
            __builtin_amdgcn_global_load_lds((const u32*)((const char*)A + ((size_t)(row0 + r) * 128 + kc) * 2 + cb),
                                             (u32*)(ldsc + wid * 2048 + i * 1024), 16, 0, 0);
            __builtin_amdgcn_global_load_lds((const u32*)((const char*)BT + ((size_t)(col0 + r) * 128 + kc) * 2 + cb),
                                             (u32*)(ldsc + 8192 + wid * 2048 + i * 1024), 16, 0, 0);
        }
        __syncthreads();
        bf16x8 af[4], bfr[4];
#pragma unroll
        for (int mt = 0; mt < 4; ++mt)
            af[mt] = *(const bf16x8*)(ldsc + (rA + mt * 16) * 64 + kch);
#pragma unroll
        for (int nt = 0; nt < 4; ++nt)
            bfr[nt] = *(const bf16x8*)(ldsc + 8192 + (rB + nt * 16) * 64 + kch);
#pragma unroll
        for (int mt = 0; mt < 4; ++mt)
#pragma unroll
            for (int nt = 0; nt < 4; ++nt)
                acc[mt][nt] = __builtin_amdgcn_mfma_f32_16x16x32_bf16(af[mt], bfr[nt], acc[mt][nt], 0, 0, 0);
        __syncthreads();
    }

    int colb = col0 + wc * 64 + (lane & 15);
    int rowb = row0 + wr * 64 + ((lane >> 4) << 2);
    if (col0 < 512) {
#pragma unroll
        for (int mt = 0; mt < 4; ++mt)
#pragma unroll
            for (int nt = 0; nt < 4; ++nt)
#pragma unroll
                for (int r = 0; r < 4; ++r)
                    qkv[(size_t)(rowb + mt * 16 + r) * 768 + colb + nt * 16] = f2bf(acc[mt][nt][r]);
    } else {
        int bb = row0 >> 8;
#pragma unroll
        for (int mt = 0; mt < 4; ++mt) {
            int node0 = (rowb + mt * 16) & 255;
#pragma unroll
            for (int nt = 0; nt < 4; ++nt) {
                int c = colb + nt * 16 - 512;
                int hh = c >> 6, d = c & 63;
                u16 tmp[4];
#pragma unroll
                for (int r = 0; r < 4; ++r) tmp[r] = f2bf(acc[mt][nt][r]);
                *(ushort4*)(vT + (size_t)(bb * 4 + hh) * 16384 + d * 256 + node0) = *(ushort4*)tmp;
            }
        }
    }
}

// ---------------- final projection GEMM (K=128, f32 out + bias) ----------------

__global__ __launch_bounds__(256) void gemm_proj(const u16* __restrict__ A,
                                                 const u16* __restrict__ BT,
                                                 float* __restrict__ Out,
                                                 const float* __restrict__ bias) {
    __shared__ __align__(16) u16 lds[8192];
    char* ldsc = (char*)lds;
    int t = threadIdx.x, lane = t & 63, wid = t >> 6;
    int row0 = blockIdx.x * 128;

    f32x4 zero = {0.f, 0.f, 0.f, 0.f};
    f32x4 acc[4][4];
#pragma unroll
    for (int mt = 0; mt < 4; ++mt)
#pragma unroll
        for (int nt = 0; nt < 4; ++nt) acc[mt][nt] = zero;

    int wr = wid >> 1, wc = wid & 1;
    int rA = wr * 64 + (lane & 15);
    int rB = wc * 64 + (lane & 15);
    int kch = (lane >> 4) << 4;

    for (int kt = 0; kt < 4; ++kt) {
        int kc = kt << 5;
#pragma unroll
        for (int i = 0; i < 2; ++i) {
            int off = wid * 2048 + i * 1024 + lane * 16;
            int r = off >> 6, cb = off & 63;
            __builtin_amdgcn_global_load_lds((const u32*)((const char*)A + ((size_t)(row0 + r) * 128 + kc) * 2 + cb),
                                             (u32*)(ldsc + wid * 2048 + i * 1024), 16, 0, 0);
            __builtin_amdgcn_global_load_lds((const u32*)((const char*)BT + ((size_t)r * 128 + kc) * 2 + cb),
                                             (u32*)(ldsc + 8192 + wid * 2048 + i * 1024), 16, 0, 0);
        }
        __syncthreads();
        bf16x8 af[4], bfr[4];
#pragma unroll
        for (int mt = 0; mt < 4; ++mt)
            af[mt] = *(const bf16x8*)(ldsc + (rA + mt * 16) * 64 + kch);
#pragma unroll
        for (int nt = 0; nt < 4; ++nt)
            bfr[nt] = *(const bf16x8*)(ldsc + 8192 + (rB + nt * 16) * 64 + kch);
#pragma unroll
        for (int mt = 0; mt < 4; ++mt)
#pragma unroll
            for (int nt = 0; nt < 4; ++nt)
                acc[mt][nt] = __builtin_amdgcn_mfma_f32_16x16x32_bf16(af[mt], bfr[nt], acc[mt][nt], 0, 0, 0);
        __syncthreads();
    }

    int colb = wc * 64 + (lane & 15);
    int rowb = row0 + wr * 64 + ((lane >> 4) << 2);
#pragma unroll
    for (int mt = 0; mt < 4; ++mt)
#pragma unroll
        for (int nt = 0; nt < 4; ++nt)
#pragma unroll
            for (int r = 0; r < 4; ++r)
                Out[(size_t)(rowb + mt * 16 + r) * 128 + colb + nt * 16] =
                    acc[mt][nt][r] + bias[colb + nt * 16];
}

// ---------------- conv GEMM layer0: K=128 from Acat0, fused bias+LN+relu ----------------

__global__ __launch_bounds__(256) void gemm_conv_ln0(const u16* __restrict__ A,
                                                     const u16* __restrict__ BT,
                                                     const float* __restrict__ rb,
                                                     const float* __restrict__ g,
                                                     const float* __restrict__ be,
                                                     u16* __restrict__ hout) {
    __shared__ __align__(16) u16 lds[8192];
    char* ldsc = (char*)lds;
    int t = threadIdx.x, lane = t & 63, wid = t >> 6;
    int row0 = blockIdx.x * 128;

    f32x4 zero = {0.f, 0.f, 0.f, 0.f};
    f32x4 acc[4][4];
#pragma unroll
    for (int mt = 0; mt < 4; ++mt)
#pragma unroll
        for (int nt = 0; nt < 4; ++nt) acc[mt][nt] = zero;

    int wr = wid >> 1, wc = wid & 1;
    int rA = wr * 64 + (lane & 15);
    int rB = wc * 64 + (lane & 15);
    int kch = (lane >> 4) << 4;

    for (int kt = 0; kt < 4; ++kt) {
        int kc = kt << 5;
#pragma unroll
        for (int i = 0; i < 2; ++i) {
            int off = wid * 2048 + i * 1024 + lane * 16;
            int r = off >> 6, cb = off & 63;
            __builtin_amdgcn_global_load_lds((const u32*)((const char*)A + ((size_t)(row0 + r) * 128 + kc) * 2 + cb),
                                             (u32*)(ldsc + wid * 2048 + i * 1024), 16, 0, 0);
            __builtin_amdgcn_global_load_lds((const u32*)((const char*)BT + ((size_t)r * 128 + kc) * 2 + cb),
                                             (u32*)(ldsc + 8192 + wid * 2048 + i * 1024), 16, 0, 0);
        }
        __syncthreads();
        bf16x8 af[4], bfr[4];
#pragma unroll
        for (int mt = 0; mt < 4; ++mt)
            af[mt] = *(const bf16x8*)(ldsc + (rA + mt * 16) * 64 + kch);
#pragma unroll
        for (int nt = 0; nt < 4; ++nt)
            bfr[nt] = *(const bf16x8*)(ldsc + 8192 + (rB + nt * 16) * 64 + kch);
#pragma unroll
        for (int mt = 0; mt < 4; ++mt)
#pragma unroll
            for (int nt = 0; nt < 4; ++nt)
                acc[mt][nt] = __builtin_amdgcn_mfma_f32_16x16x32_bf16(af[mt], bfr[nt], acc[mt][nt], 0, 0, 0);
        __syncthreads();
    }

    float* redS = (float*)ldsc;
    float* redQ = (float*)(ldsc + 2048);
    int colbase = wc * 64 + (lane & 15);
    int qrow = (lane >> 4) << 2;
    float rbv[4], gv[4], bev[4];
#pragma unroll
    for (int nt = 0; nt < 4; ++nt) {
        int c = colbase + nt * 16;
        rbv[nt] = rb[c]; gv[nt] = g[c]; bev[nt] = be[c];
    }
#pragma unroll
    for (int mt = 0; mt < 4; ++mt)
#pragma unroll
        for (int r = 0; r < 4; ++r) {
            float s = 0.f, q = 0.f;
#pragma unroll
            for (int nt = 0; nt < 4; ++nt) {
                float v = acc[mt][nt][r] + rbv[nt];
                s += v; q += v * v;
            }
            s = red16(s); q = red16(q);
            if ((lane & 15) == 0) {
                int lr = wr * 64 + qrow + mt * 16 + r;
                redS[lr * 2 + wc] = s; redQ[lr * 2 + wc] = q;
            }
        }
    __syncthreads();
#pragma unroll
    for (int mt = 0; mt < 4; ++mt)
#pragma unroll
        for (int r = 0; r < 4; ++r) {
            int lr = wr * 64 + qrow + mt * 16 + r;
            float mu = (redS[lr * 2] + redS[lr * 2 + 1]) * (1.f / 128.f);
            float var = (redQ[lr * 2] + redQ[lr * 2 + 1]) * (1.f / 128.f) - mu * mu;
            float rs = rsqrtf(var + 1e-5f);
            size_t rbase = (size_t)(row0 + lr) * 128;
#pragma unroll
            for (int nt = 0; nt < 4; ++nt) {
                float v = acc[mt][nt][r] + rbv[nt];
                float o = (v - mu) * rs * gv[nt] + bev[nt];
                o = o < 0.f ? 0.f : o;
                hout[rbase + colbase + nt * 16] = f2bf(o);
            }
        }
}

// ---------------- conv GEMM layers>=1: K=256 split (Aagg | h), fused bias+LN+relu ----------------

__global__ __launch_bounds__(256) void gemm_conv_ln_split(const u16* __restrict__ Aagg,
                                                          u16* h,
                                                          const u16* __restrict__ BT,
                                                          const float* __restrict__ rb,
                                                          const float* __restrict__ g,
                                                          const float* __restrict__ be) {
    __shared__ __align__(16) u16 lds[8192];
    char* ldsc = (char*)lds;
    int t = threadIdx.x, lane = t & 63, wid = t >> 6;
    int row0 = blockIdx.x * 128;

    f32x4 zero = {0.f, 0.f, 0.f, 0.f};
    f32x4 acc[4][4];
#pragma unroll
    for (int mt = 0; mt < 4; ++mt)
#pragma unroll
        for (int nt = 0; nt < 4; ++nt) acc[mt][nt] = zero;

    int wr = wid >> 1, wc = wid & 1;
    int rA = wr * 64 + (lane & 15);
    int rB = wc * 64 + (lane & 15);
    int kch = (lane >> 4) << 4;

    for (int kt = 0; kt < 8; ++kt) {
        const u16* Abase = (kt < 4) ? Aagg : (const u16*)h;
        int kcl = (kt & 3) << 5;
        int kc = kt << 5;
#pragma unroll
        for (int i = 0; i < 2; ++i) {
            int off = wid * 2048 + i * 1024 + lane * 16;
            int r = off >> 6, cb = off & 63;
            __builtin_amdgcn_global_load_lds((const u32*)((const char*)Abase + ((size_t)(row0 + r) * 128 + kcl) * 2 + cb),
                                             (u32*)(ldsc + wid * 2048 + i * 1024), 16, 0, 0);
            __builtin_amdgcn_global_load_lds((const u32*)((const char*)BT + ((size_t)r * 256 + kc) * 2 + cb),
                                             (u32*)(ldsc + 8192 + wid * 2048 + i * 1024), 16, 0, 0);
        }
        __syncthreads();
        bf16x8 af[4], bfr[4];
#pragma unroll
        for (int mt = 0; mt < 4; ++mt)
            af[mt] = *(const bf16x8*)(ldsc + (rA + mt * 16) * 64 + kch);
#pragma unroll
        for (int nt = 0; nt < 4; ++nt)
            bfr[nt] = *(const bf16x8*)(ldsc + 8192 + (rB + nt * 16) * 64 + kch);
#pragma unroll
        for (int mt = 0; mt < 4; ++mt)
#pragma unroll
            for (int nt = 0; nt < 4; ++nt)
                acc[mt][nt] = __builtin_amdgcn_mfma_f32_16x16x32_bf16(af[mt], bfr[nt], acc[mt][nt], 0, 0, 0);
        __syncthreads();
    }

    float* redS = (float*)ldsc;
    float* redQ = (float*)(ldsc + 2048);
    int colbase = wc * 64 + (lane & 15);
    int qrow = (lane >> 4) << 2;
    float rbv[4], gv[4], bev[4];
#pragma unroll
    for (int nt = 0; nt < 4; ++nt) {
        int c = colbase + nt * 16;
        rbv[nt] = rb[c]; gv[nt] = g[c]; bev[nt] = be[c];
    }
#pragma unroll
    for (int mt = 0; mt < 4; ++mt)
#pragma unroll
        for (int r = 0; r < 4; ++r) {
            float s = 0.f, q = 0.f;
#pragma unroll
            for (int nt = 0; nt < 4; ++nt) {
                float v = acc[mt][nt][r] + rbv[nt];
                s += v; q += v * v;
            }
            s = red16(s); q = red16(q);
            if ((lane & 15) == 0) {
                int lr = wr * 64 + qrow + mt * 16 + r;
                redS[lr * 2 + wc] = s; redQ[lr * 2 + wc] = q;
            }
        }
    __syncthreads();
#pragma unroll
    for (int mt = 0; mt < 4; ++mt)
#pragma unroll
        for (int r = 0; r < 4; ++r) {
            int lr = wr * 64 + qrow + mt * 16 + r;
            float mu = (redS[lr * 2] + redS[lr * 2 + 1]) * (1.f / 128.f);
            float var = (redQ[lr * 2] + redQ[lr * 2 + 1]) * (1.f / 128.f) - mu * mu;
            float rs = rsqrtf(var + 1e-5f);
            size_t rbase = (size_t)(row0 + lr) * 128;
#pragma unroll
            for (int nt = 0; nt < 4; ++nt) {
                float v = acc[mt][nt][r] + rbv[nt];
                float o = (v - mu) * rs * gv[nt] + bev[nt];
                o = o < 0.f ? 0.f : o;
                h[rbase + colbase + nt * 16] = f2bf(o);
            }
        }
}

// ---------------- fc GEMM with fused LN -> +residual -> LN (K=256, Mtot=128) ----------------

__global__ __launch_bounds__(256) void gemm_fc_ln2(const u16* __restrict__ A,
                                                   const u16* __restrict__ BT,
                                                   const float* __restrict__ mg,
                                                   const float* __restrict__ mb,
                                                   const float* __restrict__ eg,
                                                   const float* __restrict__ eb,
                                                   u16* __restrict__ h) {
    __shared__ __align__(16) u16 lds[8192];
    char* ldsc = (char*)lds;
    int t = threadIdx.x, lane = t & 63, wid = t >> 6;
    int row0 = blockIdx.x * 128;

    f32x4 zero = {0.f, 0.f, 0.f, 0.f};
    f32x4 acc[4][4];
#pragma unroll
    for (int mt = 0; mt < 4; ++mt)
#pragma unroll
        for (int nt = 0; nt < 4; ++nt) acc[mt][nt] = zero;

    int wr = wid >> 1, wc = wid & 1;
    int rA = wr * 64 + (lane & 15);
    int rB = wc * 64 + (lane & 15);
    int kch = (lane >> 4) << 4;

    for (int kt = 0; kt < 8; ++kt) {
        int kc = kt << 5;
#pragma unroll
        for (int i = 0; i < 2; ++i) {
            int off = wid * 2048 + i * 1024 + lane * 16;
            int r = off >> 6, cb = off & 63;
            __builtin_amdgcn_global_load_lds((const u32*)((const char*)A + ((size_t)(row0 + r) * 256 + kc) * 2 + cb),
                                             (u32*)(ldsc + wid * 2048 + i * 1024), 16, 0, 0);
            __builtin_amdgcn_global_load_lds((const u32*)((const char*)BT + ((size_t)r * 256 + kc) * 2 + cb),
                                             (u32*)(ldsc + 8192 + wid * 2048 + i * 1024), 16, 0, 0);
        }
        __syncthreads();
        bf16x8 af[4], bfr[4];
#pragma unroll
        for (int mt = 0; mt < 4; ++mt)
            af[mt] = *(const bf16x8*)(ldsc + (rA + mt * 16) * 64 + kch);
#pragma unroll
        for (int nt = 0; nt < 4; ++nt)
            bfr[nt] = *(const bf16x8*)(ldsc + 8192 + (rB + nt * 16) * 64 + kch);
#pragma unroll
        for (int mt = 0; mt < 4; ++mt)
#pragma unroll
            for (int nt = 0; nt < 4; ++nt)
                acc[mt][nt] = __builtin_amdgcn_mfma_f32_16x16x32_bf16(af[mt], bfr[nt], acc[mt][nt], 0, 0, 0);
        __syncthreads();
    }

    float* redS  = (float*)ldsc;
    float* redQ  = (float*)(ldsc + 2048);
    float* redS2 = (float*)(ldsc + 4096);
    float* redQ2 = (float*)(ldsc + 6144);
    int colbase = wc * 64 + (lane & 15);
    int qrow = (lane >> 4) << 2;
    float mgv[4], mbv[4], egv[4], ebv[4];
#pragma unroll
    for (int nt = 0; nt < 4; ++nt) {
        int c = colbase + nt * 16;
        mgv[nt] = mg[c]; mbv[nt] = mb[c]; egv[nt] = eg[c]; ebv[nt] = eb[c];
    }
#pragma unroll
    for (int mt = 0; mt < 4; ++mt)
#pragma unroll
        for (int r = 0; r < 4; ++r) {
            float s = 0.f, q = 0.f;
#pragma unroll
            for (int nt = 0; nt < 4; ++nt) {
                float v = acc[mt][nt][r];
                s += v; q += v * v;
            }
            s = red16(s); q = red16(q);
            if ((lane & 15) == 0) {
                int lr = wr * 64 + qrow + mt * 16 + r;
                redS[lr * 2 + wc] = s; redQ[lr * 2 + wc] = q;
            }
        }
    __syncthreads();
#pragma unroll
    for (int mt = 0; mt < 4; ++mt)
#pragma unroll
        for (int r = 0; r < 4; ++r) {
            int lr = wr * 64 + qrow + mt * 16 + r;
            float mu = (redS[lr * 2] + redS[lr * 2 + 1]) * (1.f / 128.f);
            float var = (redQ[lr * 2] + redQ[lr * 2 + 1]) * (1.f / 128.f) - mu * mu;
            float rs = rsqrtf(var + 1e-5f);
            size_t rbase = (size_t)(row0 + lr) * 128;
            float s2 = 0.f, q2 = 0.f;
#pragma unroll
            for (int nt = 0; nt < 4; ++nt) {
                float o = (acc[mt][nt][r] - mu) * rs * mgv[nt] + mbv[nt];
                float z = o + bf2f(h[rbase + colbase + nt * 16]);
                acc[mt][nt][r] = z;
                s2 += z; q2 += z * z;
            }
            s2 = red16(s2); q2 = red16(q2);
            if ((lane & 15) == 0) {
                redS2[lr * 2 + wc] = s2; redQ2[lr * 2 + wc] = q2;
            }
        }
    __syncthreads();
#pragma unroll
    for (int mt = 0; mt < 4; ++mt)
#pragma unroll
        for (int r = 0; r < 4; ++r) {
            int lr = wr * 64 + qrow + mt * 16 + r;
            float mu = (redS2[lr * 2] + redS2[lr * 2 + 1]) * (1.f / 128.f);
            float var = (redQ2[lr * 2] + redQ2[lr * 2 + 1]) * (1.f / 128.f) - mu * mu;
            float rs = rsqrtf(var + 1e-5f);
            size_t rbase = (size_t)(row0 + lr) * 128;
#pragma unroll
            for (int nt = 0; nt < 4; ++nt) {
                float z = acc[mt][nt][r];
                h[rbase + colbase + nt * 16] = f2bf((z - mu) * rs * egv[nt] + ebv[nt]);
            }
        }
}

// ---------------- fused attention: per (b, head) block; K/V staged; P in registers ----------------

__global__ __launch_bounds__(512) void attn_k(const u16* __restrict__ qkv,
                                              const u16* __restrict__ vT,
                                              const float* __restrict__ mat,
                                              u16* __restrict__ ctx) {
    __shared__ __align__(16) u16 Kl[256 * 72];   // 36864 B
    __shared__ __align__(16) u16 Vl[64 * 264];   // 33792 B
    int t = threadIdx.x, lane = t & 63, w = t >> 6;
    int b = blockIdx.x, hh = blockIdx.y;
    int nbase = b * LL;
    int lg = lane >> 4, q16 = lane & 15;

    // --- bulk staging, coalescing-ordered ---
    if (t < 256) {
        const u16* kb = qkv + (size_t)nbase * 768 + 256 + hh * 64;
#pragma unroll
        for (int i = 0; i < 8; ++i) {
            int idx = i * 256 + t;
            int node = idx >> 3, oct = idx & 7;
            *(uint4*)(Kl + node * 72 + oct * 8) = *(const uint4*)(kb + (size_t)node * 768 + oct * 8);
        }
    } else {
        int tt = t - 256;
        const u16* vsrc = vT + (size_t)(b * 4 + hh) * 16384;
#pragma unroll
        for (int i = 0; i < 8; ++i) {
            int idx = i * 256 + tt;
            int d = idx >> 5, p = idx & 31;
            *(uint4*)(Vl + d * 264 + p * 8) = *(const uint4*)(vsrc + d * 256 + p * 8);
        }
    }
    __syncthreads();

    f32x4 zero = {0.f, 0.f, 0.f, 0.f};
    bool loA = (lg < 2);
    int s01 = q16 + ((lg & 1) << 5);
    int s23 = s01 + 16;

    for (int qi = 0; qi < 2; ++qi) {
        int qrow_l = w * 32 + qi * 16;

        const u16* qsrc = qkv + (size_t)(nbase + qrow_l + q16) * 768 + hh * 64 + (lg << 3);
        bf16x8 aq0 = *(const bf16x8*)(qsrc);
        bf16x8 aq1 = *(const bf16x8*)(qsrc + 32);

        f32x4 sc[16];
#pragma unroll
        for (int nt = 0; nt < 16; ++nt) {
            const u16* ks = Kl + (nt * 16 + q16) * 72 + (lg << 3);
            bf16x8 k0 = *(const bf16x8*)(ks);
            bf16x8 k1 = *(const bf16x8*)(ks + 32);
            f32x4 a = __builtin_amdgcn_mfma_f32_16x16x32_bf16(k0, aq0, zero, 0, 0, 0);
            a = __builtin_amdgcn_mfma_f32_16x16x32_bf16(k1, aq1, a, 0, 0, 0);
            sc[nt] = a;
        }

        const float* mrow = mat + ((size_t)b * LL + qrow_l + q16) * LL + (lg << 2);
#pragma unroll
        for (int nt = 0; nt < 16; ++nt) {
            f32x4 mv = *(const f32x4*)(mrow + nt * 16);
#pragma unroll
            for (int r = 0; r < 4; ++r)
                sc[nt][r] *= 0.125f * mv[r];
        }

        float mx = -1e30f;
#pragma unroll
        for (int nt = 0; nt < 16; ++nt)
#pragma unroll
            for (int r = 0; r < 4; ++r) mx = fmaxf(mx, sc[nt][r]);
        mx = fmaxf(mx, __shfl_xor(mx, 16, 64));
        mx = fmaxf(mx, __shfl_xor(mx, 32, 64));
        float sm = 0.f;
#pragma unroll
        for (int nt = 0; nt < 16; ++nt)
#pragma unroll
            for (int r = 0; r < 4; ++r) {
                float e = __expf(sc[nt][r] - mx);
                sc[nt][r] = e;
                sm += e;
            }
        sm += __shfl_xor(sm, 16, 64);
        sm += __shfl_xor(sm, 32, 64);
        float inv = 1.f / sm;
#pragma unroll
        for (int nt = 0; nt < 16; ++nt)
#pragma unroll
            for (int r = 0; r < 4; ++r) sc[nt][r] *= inv;

        f32x4 oa[4];
#pragma unroll
        for (int dt = 0; dt < 4; ++dt) oa[dt] = zero;
#pragma unroll
        for (int kt = 0; kt < 8; ++kt) {
            u32 A0 = cvtpk(sc[2 * kt][0], sc[2 * kt][1]);
            u32 A1 = cvtpk(sc[2 * kt][2], sc[2 * kt][3]);
            u32 B0 = cvtpk(sc[2 * kt + 1][0], sc[2 * kt + 1][1]);
            u32 B1 = cvtpk(sc[2 * kt + 1][2], sc[2 * kt + 1][3]);
            u32 a0s = bperm(s01, A0), b0s = bperm(s01, B0);
            u32 a1s = bperm(s01, A1), b1s = bperm(s01, B1);
            u32 a0t = bperm(s23, A0), b0t = bperm(s23, B0);
            u32 a1t = bperm(s23, A1), b1t = bperm(s23, B1);
            union { u32 u[4]; bf16x8 v; } pa;
            pa.u[0] = loA ? a0s : b0s;
            pa.u[1] = loA ? a1s : b1s;
            pa.u[2] = loA ? a0t : b0t;
            pa.u[3] = loA ? a1t : b1t;
#pragma unroll
            for (int dt = 0; dt < 4; ++dt) {
                bf16x8 bv = *(const bf16x8*)(Vl + (dt * 16 + q16) * 264 + kt * 32 + (lg << 3));
                oa[dt] = __builtin_amdgcn_mfma_f32_16x16x32_bf16(pa.v, bv, oa[dt], 0, 0, 0);
            }
        }
#pragma unroll
        for (int dt = 0; dt < 4; ++dt)
#pragma unroll
            for (int r = 0; r < 4; ++r)
                ctx[(size_t)(nbase + qrow_l + (lg << 2) + r) * 256 + hh * 64 + dt * 16 + q16] = f2bf(oa[dt][r]);
    }
}

// ---------------- host launch ----------------

extern "C" void kernel_launch(void* const* d_in, const int* in_sizes, int n_in,
                              void* d_out, int out_size, void* d_ws, size_t ws_size,
                              hipStream_t stream) {
    (void)out_size; (void)ws_size; (void)n_in;
    const float* x        = (const float*)d_in[0];
    const int*   ei       = (const int*)d_in[1];
    const float* ea       = (const float*)d_in[2];
    const float* adj      = (const float*)d_in[3];
    const float* dis      = (const float*)d_in[4];
    int pb = (in_sizes[5] == 5120) ? 5 : 6;
    const float* g0_rel_w = (const float*)d_in[pb + 0];
    const float* g0_rel_b = (const float*)d_in[pb + 1];
    const float* g0_root_w= (const float*)d_in[pb + 2];
    const float* g_rel_w  = (const float*)d_in[pb + 3];
    const float* g_rel_b  = (const float*)d_in[pb + 4];
    const float* g_root_w = (const float*)d_in[pb + 5];
    const float* nm_g     = (const float*)d_in[pb + 6];
    const float* nm_b     = (const float*)d_in[pb + 7];
    const float* wq       = (const float*)d_in[pb + 8];
    const float* wk       = (const float*)d_in[pb + 9];
    const float* wv       = (const float*)d_in[pb + 10];
    const float* fc       = (const float*)d_in[pb + 11];
    const float* mha_g    = (const float*)d_in[pb + 12];
    const float* mha_b    = (const float*)d_in[pb + 13];
    const float* enc_g    = (const float*)d_in[pb + 14];
    const float* enc_b    = (const float*)d_in[pb + 15];
    const float* proj_w   = (const float*)d_in[pb + 16];
    const float* proj_b   = (const float*)d_in[pb + 17];
    const int* srcI = ei;
    const int* dstI = ei + EDGES;

    char* w = (char*)d_ws;
    float* Wf     = (float*)w; w += (size_t)33554432;   // W f32 scatter, then reused as `mat`
    u16*   Acat   = (u16*)w;   w += (size_t)16777216;   // Aagg [N,128] / ctx [N,256] (time-disjoint)
    u16*   h      = (u16*)w;   w += (size_t)8388608;
    u16*   qkv    = (u16*)w;   w += (size_t)50331648;
    u16*   Wb     = (u16*)w;   w += (size_t)16777216;   // W bf16 [128][256][256]
    u16*   bigT   = (u16*)w;   w += (size_t)16777216;   // hT (8.4MB) / vT (16.7MB), time-disjoint
    u16* wconvT0  = (u16*)w;   w += (size_t)32768;
    u16* wconvT   = (u16*)w;   w += (size_t)196608;
    u16* wqkvT    = (u16*)w;   w += (size_t)786432;
    u16* fcT      = (u16*)w;   w += (size_t)262144;
    u16* projT    = (u16*)w;   w += (size_t)32768;
    float* mat = Wf;
    u16*   ctx = Acat;
    u16*   hT  = bigT;
    u16*   vT  = bigT;

    // --- prep (5 launches; cast MUST precede build_matrix: mat aliases Wf) ---
    zero_f32<<<32768, 256, 0, stream>>>(Wf, 8388608);
    scatter_w_k<<<2048, 256, 0, stream>>>(srcI, dstI, ea, Wf);
    cast_w_k<<<8192, 256, 0, stream>>>(Wf, Wb);
    build_matrix_k<<<32768, 256, 0, stream>>>(adj, dis, mat);
    prep_weights_k<<<2560, 256, 0, stream>>>(g0_rel_w, g0_root_w, g_rel_w, g_root_w,
                                             wq, wk, wv, fc, proj_w,
                                             wconvT0, wconvT, wqkvT, fcT, projT);

    for (int L = 0; L < 4; ++L) {
        if (L == 0) {
            transpose_h_k<true><<<2048, 256, 0, stream>>>(h, x, hT);
            gemm_agg<true><<<256, 256, 0, stream>>>(Wb, hT, x, Acat);
            gemm_conv_ln0<<<256, 256, 0, stream>>>(Acat, wconvT0, g0_rel_b, nm_g, nm_b, h);
        } else {
            transpose_h_k<false><<<2048, 256, 0, stream>>>(h, x, hT);
            gemm_agg<false><<<256, 256, 0, stream>>>(Wb, hT, x, Acat);
            gemm_conv_ln_split<<<256, 256, 0, stream>>>(Acat, h, wconvT + (L - 1) * 32768,
                                                        g_rel_b + (L - 1) * 128,
                                                        nm_g + L * 128, nm_b + L * 128);
        }
        gemm_qkv<<<dim3(256, 6), 256, 0, stream>>>(h, wqkvT + L * 98304, qkv, vT);
        attn_k<<<dim3(NB, 4), 512, 0, stream>>>(qkv, vT, mat, ctx);
        gemm_fc_ln2<<<256, 256, 0, stream>>>(ctx, fcT + L * 32768,
                                             mha_g + L * 128, mha_b + L * 128,
                                             enc_g + L * 128, enc_b + L * 128, h);
    }
    gemm_proj<<<256, 256, 0, stream>>>(h, projT, (float*)d_out, proj_b);
}

// Round 13
// 521.597 us; speedup vs baseline: 1.3317x; 1.0517x over previous
//
#include <hip/hip_runtime.h>
#include <stdint.h>

typedef unsigned short u16;
typedef unsigned int u32;
typedef __attribute__((ext_vector_type(4))) float f32x4;
typedef __attribute__((ext_vector_type(8))) short bf16x8;

#define NB 128      // graphs
#define LL 256      // nodes per graph
#define DD 128      // hidden
#define EDGES 524288
#define EPG 4096    // edges per graph
#define NN (NB*LL)

__device__ __forceinline__ float bf2f(u16 u) {
    union { u32 i; float f; } v; v.i = ((u32)u) << 16; return v.f;
}
__device__ __forceinline__ u16 f2bf(float f) {
    union { float f; u32 i; } v; v.f = f;
    u32 i = v.i;
    u32 r = (i + 0x7fffu + ((i >> 16) & 1u)) >> 16;   // RNE
    return (u16)r;
}
__device__ __forceinline__ float matfn(float a, float dv) {
    if (a != 0.f) return (a == 1.2f) ? 1.1f : a;
    return (dv == 0.f) ? 0.f : exp2f((1.f - dv) * 0.5849625007211562f); // 1.5^(1-dis)
}
__device__ __forceinline__ float red16(float v) {
#pragma unroll
    for (int off = 1; off < 16; off <<= 1) v += __shfl_xor(v, off, 64);
    return v;
}
__device__ __forceinline__ u32 cvtpk(float lo, float hi) {
    u32 r;
    asm("v_cvt_pk_bf16_f32 %0, %1, %2" : "=v"(r) : "v"(lo), "v"(hi));
    return r;
}
__device__ __forceinline__ u32 bperm(int srcLane, u32 v) {
    return (u32)__builtin_amdgcn_ds_bpermute(srcLane << 2, (int)v);
}

// ---------------- prep kernels ----------------

__global__ __launch_bounds__(256) void scatter_w_k(const int* __restrict__ srcI,
                                                   const int* __restrict__ dstI,
                                                   const float* __restrict__ ew,
                                                   float* __restrict__ Wf) {
    int e = blockIdx.x * 256 + threadIdx.x;
    if (e >= EDGES) return;
    int b = e >> 12;
    atomicAdd(&Wf[(size_t)b * 65536 + (size_t)(dstI[e] & 255) * 256 + (srcI[e] & 255)], ew[e]);
}

// NOTE: must run BEFORE build_matrix_k (mat aliases Wf).
__global__ __launch_bounds__(256) void cast_w_k(const float* __restrict__ Wf, u16* __restrict__ Wb) {
    int i = blockIdx.x * 256 + threadIdx.x;
    float4 v = ((const float4*)Wf)[i];
    ushort4 o;
    o.x = f2bf(v.x); o.y = f2bf(v.y); o.z = f2bf(v.z); o.w = f2bf(v.w);
    ((ushort4*)Wb)[i] = o;
}

// mat holds 0.125 * matfn (attn scale folded in)
__global__ __launch_bounds__(256) void build_matrix_k(const float* __restrict__ adj,
                                                      const float* __restrict__ dis,
                                                      float* __restrict__ mat) {
    int i = blockIdx.x * 256 + threadIdx.x;
    mat[i] = 0.125f * matfn(adj[i], dis[i]);
}

// all weight transposes in one kernel (655360 elements, 2560 blocks)
__global__ __launch_bounds__(256) void prep_weights_k(
        const float* __restrict__ g0_rel_w, const float* __restrict__ g0_root_w,
        const float* __restrict__ g_rel_w,  const float* __restrict__ g_root_w,
        const float* __restrict__ wq, const float* __restrict__ wk,
        const float* __restrict__ wv, const float* __restrict__ fc,
        const float* __restrict__ proj_w,
        u16* __restrict__ wconvT0, u16* __restrict__ wconvT,
        u16* __restrict__ wqkvT, u16* __restrict__ fcT, u16* __restrict__ projT) {
    int i = blockIdx.x * 256 + threadIdx.x;
    if (i < 16384) {
        int m = i >> 7, k = i & 127;
        float v = 0.f;
        if (k < 40) v = g0_rel_w[k * 128 + m];
        else if (k >= 64 && k < 104) v = g0_root_w[(k - 64) * 128 + m];
        wconvT0[i] = f2bf(v);
        return;
    }
    i -= 16384;
    if (i < 98304) {
        int l = i >> 15, jj = i & 32767;
        int m = jj >> 8, k = jj & 255;
        float v = (k < 128) ? g_rel_w[l * 16384 + k * 128 + m]
                            : g_root_w[l * 16384 + (k - 128) * 128 + m];
        wconvT[i] = f2bf(v);
        return;
    }
    i -= 98304;
    if (i < 393216) {
        int l = i / 98304, jj = i % 98304;
        int m = jj >> 7, k = jj & 127;
        const float* s = (m < 256) ? wq : (m < 512) ? wk : wv;
        int mm = m & 255;
        wqkvT[i] = f2bf(s[l * 32768 + k * 256 + mm]);
        return;
    }
    i -= 393216;
    if (i < 131072) {
        int l = i >> 15, jj = i & 32767;
        int m = jj >> 8, k = jj & 255;
        fcT[i] = f2bf(fc[l * 32768 + k * 128 + m]);
        return;
    }
    i -= 131072;
    {
        int m = i >> 7, k = i & 127;
        projT[i] = f2bf(proj_w[k * 128 + m]);
    }
}

// layer-0 transpose: x [N,40] f32 (zero-padded to 128) -> hT [b][128][256]
__global__ __launch_bounds__(256) void transpose_x_k(const float* __restrict__ x,
                                                     u16* __restrict__ hT) {
    int gw = blockIdx.x * 4 + (threadIdx.x >> 6);
    int lane = threadIdx.x & 63;
    int b = gw >> 6, rem = gw & 63, db = rem >> 5, jb = rem & 31;
    int d = (db << 6) + lane;
    u16 vals[8];
#pragma unroll
    for (int jj = 0; jj < 8; ++jj) {
        int node = (b << 8) + (jb << 3) + jj;
        vals[jj] = (d < 40) ? f2bf(x[(size_t)node * 40 + d]) : (u16)0;
    }
    *(uint4*)(hT + (size_t)b * 32768 + (size_t)d * 256 + (jb << 3)) = *(uint4*)vals;
}

// ---------------- per-graph aggregation GEMM: Aagg = W@h  ([N,128]) ----------------

template<bool IS0>
__global__ __launch_bounds__(256) void gemm_agg(const u16* __restrict__ Wb,
                                                const u16* __restrict__ BT0,
                                                const float* __restrict__ x,
                                                u16* __restrict__ Aagg) {
    __shared__ __align__(16) u16 lds[8192];
    char* ldsc = (char*)lds;
    int t = threadIdx.x, lane = t & 63, wid = t >> 6;
    int b = blockIdx.x >> 1, rt = blockIdx.x & 1;
    int row0 = rt << 7, nbase = b << 8;
    const u16* A = Wb + (size_t)b * 65536 + (size_t)row0 * 256;
    const u16* BT = BT0 + (size_t)b * 32768;

    f32x4 zero = {0.f, 0.f, 0.f, 0.f};
    f32x4 acc[4][4];
#pragma unroll
    for (int mt = 0; mt < 4; ++mt)
#pragma unroll
        for (int nt = 0; nt < 4; ++nt) acc[mt][nt] = zero;

    int wr = wid >> 1, wc = wid & 1;
    int rA = wr * 64 + (lane & 15);
    int rB = wc * 64 + (lane & 15);
    int kch = (lane >> 4) << 4;

    for (int kt = 0; kt < 8; ++kt) {
        int kc = kt << 5;
#pragma unroll
        for (int i = 0; i < 2; ++i) {
            int off = wid * 2048 + i * 1024 + lane * 16;
            int r = off >> 6, cb = off & 63;
            __builtin_amdgcn_global_load_lds((const u32*)((const char*)A + ((size_t)r * 256 + kc) * 2 + cb),
                                             (u32*)(ldsc + wid * 2048 + i * 1024), 16, 0, 0);
            __builtin_amdgcn_global_load_lds((const u32*)((const char*)BT + ((size_t)r * 256 + kc) * 2 + cb),
                                             (u32*)(ldsc + 8192 + wid * 2048 + i * 1024), 16, 0, 0);
        }
        __syncthreads();
        bf16x8 af[4], bfr[4];
#pragma unroll
        for (int mt = 0; mt < 4; ++mt)
            af[mt] = *(const bf16x8*)(ldsc + (rA + mt * 16) * 64 + kch);
#pragma unroll
        for (int nt = 0; nt < 4; ++nt)
            bfr[nt] = *(const bf16x8*)(ldsc + 8192 + (rB + nt * 16) * 64 + kch);
#pragma unroll
        for (int mt = 0; mt < 4; ++mt)
#pragma unroll
            for (int nt = 0; nt < 4; ++nt)
                acc[mt][nt] = __builtin_amdgcn_mfma_f32_16x16x32_bf16(af[mt], bfr[nt], acc[mt][nt], 0, 0, 0);
        __syncthreads();
    }

    int colb = wc * 64 + (lane & 15);
    int rowb = wr * 64 + ((lane >> 4) << 2);
#pragma unroll
    for (int mt = 0; mt < 4; ++mt)
#pragma unroll
        for (int nt = 0; nt < 4; ++nt)
#pragma unroll
            for (int r = 0; r < 4; ++r)
                Aagg[(size_t)(nbase + row0 + rowb + mt * 16 + r) * 128 + colb + nt * 16]
                    = f2bf(acc[mt][nt][r]);
    if (IS0) {
        for (int idx = t; idx < 128 * 40; idx += 256) {
            int i = idx / 40, c = idx - i * 40;
            int node = nbase + row0 + i;
            Aagg[(size_t)node * 128 + 64 + c] = f2bf(x[(size_t)node * 40 + c]);
        }
    }
}

// ---------------- qkv GEMM (K=128, Mtot=768): Q,K -> packed [bh][256][64]; V -> vT [bh][64][256] ----------------

__global__ __launch_bounds__(256) void gemm_qkv(const u16* __restrict__ A,
                                                const u16* __restrict__ BT,
                                                u16* __restrict__ qP,
                                                u16* __restrict__ kP,
                                                u16* __restrict__ vT) {
    __shared__ __align__(16) u16 lds[8192];
    char* ldsc = (char*)lds;
    int t = threadIdx.x, lane = t & 63, wid = t >> 6;
    int row0 = blockIdx.x * 128, col0 = blockIdx.y * 128;

    f32x4 zero = {0.f, 0.f, 0.f, 0.f};
    f32x4 acc[4][4];
#pragma unroll
    for (int mt = 0; mt < 4; ++mt)
#pragma unroll
        for (int nt = 0; nt < 4; ++nt) acc[mt][nt] = zero;

    int wr = wid >> 1, wc = wid & 1;
    int rA = wr * 64 + (lane & 15);
    int rB = wc * 64 + (lane & 15);
    int kch = (lane >> 4) << 4;

    for (int kt = 0; kt < 4; ++kt) {
        int kc = kt << 5;
#pragma unroll
        for (int i = 0; i < 2; ++i) {
            int off = wid * 2048 + i * 1024 + lane * 16;
            int r = off >> 6, cb = off & 63;
            __builtin_amdgcn_global_load_lds((const u32*)((const char*)A + ((size_t)(row0 + r) * 128 + kc) * 2 + cb),
                                             (u32*)(ldsc + wid * 2048 + i * 1024), 16, 0, 0);
            __builtin_amdgcn_global_load_lds((const u32*)((const char*)BT + ((size_t)(col0 + r) * 128 + kc) * 2 + cb),
                                             (u32*)(ldsc + 8192 + wid * 2048 + i * 1024), 16, 0, 0);
        }
        __syncthreads();
        bf16x8 af[4], bfr[4];
#pragma unroll
        for (int mt = 0; mt < 4; ++mt)
            af[mt] = *(const bf16x8*)(ldsc + (rA + mt * 16) * 64 + kch);
#pragma unroll
        for (int nt = 0; nt < 4; ++nt)
            bfr[nt] = *(const bf16x8*)(ldsc + 8192 + (rB + nt * 16) * 64 + kch);
#pragma unroll
        for (int mt = 0; mt < 4; ++mt)
#pragma unroll
            for (int nt = 0; nt < 4; ++nt)
                acc[mt][nt] = __builtin_amdgcn_mfma_f32_16x16x32_bf16(af[mt], bfr[nt], acc[mt][nt], 0, 0, 0);
        __syncthreads();
    }

    int colb = col0 + wc * 64 + (lane & 15);
    int rowb = row0 + wr * 64 + ((lane >> 4) << 2);
    int bb = row0 >> 8;
    if (col0 < 512) {
        u16* dst = (col0 < 256) ? qP : kP;
#pragma unroll
        for (int mt = 0; mt < 4; ++mt) {
#pragma unroll
            for (int nt = 0; nt < 4; ++nt) {
                int c = (colb + nt * 16) & 255;
                int hh = c >> 6, d = c & 63;
#pragma unroll
                for (int r = 0; r < 4; ++r) {
                    int node = (rowb + mt * 16 + r) & 255;
                    dst[(size_t)(bb * 4 + hh) * 16384 + node * 64 + d] = f2bf(acc[mt][nt][r]);
                }
            }
        }
    } else {
#pragma unroll
        for (int mt = 0; mt < 4; ++mt) {
            int node0 = (rowb + mt * 16) & 255;
#pragma unroll
            for (int nt = 0; nt < 4; ++nt) {
                int c = colb + nt * 16 - 512;
                int hh = c >> 6, d = c & 63;
                u16 tmp[4];
#pragma unroll
                for (int r = 0; r < 4; ++r) tmp[r] = f2bf(acc[mt][nt][r]);
                *(ushort4*)(vT + (size_t)(bb * 4 + hh) * 16384 + d * 256 + node0) = *(ushort4*)tmp;
            }
        }
    }
}

// ---------------- final projection GEMM (K=128, f32 out + bias) ----------------

__global__ __launch_bounds__(256) void gemm_proj(const u16* __restrict__ A,
                                                 const u16* __restrict__ BT,
                                                 float* __restrict__ Out,
                                                 const float* __restrict__ bias) {
    __shared__ __align__(16) u16 lds[8192];
    char* ldsc = (char*)lds;
    int t = threadIdx.x, lane = t & 63, wid = t >> 6;
    int row0 = blockIdx.x * 128;

    f32x4 zero = {0.f, 0.f, 0.f, 0.f};
    f32x4 acc[4][4];
#pragma unroll
    for (int mt = 0; mt < 4; ++mt)
#pragma unroll
        for (int nt = 0; nt < 4; ++nt) acc[mt][nt] = zero;

    int wr = wid >> 1, wc = wid & 1;
    int rA = wr * 64 + (lane & 15);
    int rB = wc * 64 + (lane & 15);
    int kch = (lane >> 4) << 4;

    for (int kt = 0; kt < 4; ++kt) {
        int kc = kt << 5;
#pragma unroll
        for (int i = 0; i < 2; ++i) {
            int off = wid * 2048 + i * 1024 + lane * 16;
            int r = off >> 6, cb = off & 63;
            __builtin_amdgcn_global_load_lds((const u32*)((const char*)A + ((size_t)(row0 + r) * 128 + kc) * 2 + cb),
                                             (u32*)(ldsc + wid * 2048 + i * 1024), 16, 0, 0);
            __builtin_amdgcn_global_load_lds((const u32*)((const char*)BT + ((size_t)r * 128 + kc) * 2 + cb),
                                             (u32*)(ldsc + 8192 + wid * 2048 + i * 1024), 16, 0, 0);
        }
        __syncthreads();
        bf16x8 af[4], bfr[4];
#pragma unroll
        for (int mt = 0; mt < 4; ++mt)
            af[mt] = *(const bf16x8*)(ldsc + (rA + mt * 16) * 64 + kch);
#pragma unroll
        for (int nt = 0; nt < 4; ++nt)
            bfr[nt] = *(const bf16x8*)(ldsc + 8192 + (rB + nt * 16) * 64 + kch);
#pragma unroll
        for (int mt = 0; mt < 4; ++mt)
#pragma unroll
            for (int nt = 0; nt < 4; ++nt)
                acc[mt][nt] = __builtin_amdgcn_mfma_f32_16x16x32_bf16(af[mt], bfr[nt], acc[mt][nt], 0, 0, 0);
        __syncthreads();
    }

    int colb = wc * 64 + (lane & 15);
    int rowb = row0 + wr * 64 + ((lane >> 4) << 2);
#pragma unroll
    for (int mt = 0; mt < 4; ++mt)
#pragma unroll
        for (int nt = 0; nt < 4; ++nt)
#pragma unroll
            for (int r = 0; r < 4; ++r)
                Out[(size_t)(rowb + mt * 16 + r) * 128 + colb + nt * 16] =
                    acc[mt][nt][r] + bias[colb + nt * 16];
}

// ---------------- conv GEMM layer0: K=128, fused bias+LN+relu ----------------

__global__ __launch_bounds__(256) void gemm_conv_ln0(const u16* __restrict__ A,
                                                     const u16* __restrict__ BT,
                                                     const float* __restrict__ rb,
                                                     const float* __restrict__ g,
                                                     const float* __restrict__ be,
                                                     u16* __restrict__ hout) {
    __shared__ __align__(16) u16 lds[8192];
    char* ldsc = (char*)lds;
    int t = threadIdx.x, lane = t & 63, wid = t >> 6;
    int row0 = blockIdx.x * 128;

    f32x4 zero = {0.f, 0.f, 0.f, 0.f};
    f32x4 acc[4][4];
#pragma unroll
    for (int mt = 0; mt < 4; ++mt)
#pragma unroll
        for (int nt = 0; nt < 4; ++nt) acc[mt][nt] = zero;

    int wr = wid >> 1, wc = wid & 1;
    int rA = wr * 64 + (lane & 15);
    int rB = wc * 64 + (lane & 15);
    int kch = (lane >> 4) << 4;

    for (int kt = 0; kt < 4; ++kt) {
        int kc = kt << 5;
#pragma unroll
        for (int i = 0; i < 2; ++i) {
            int off = wid * 2048 + i * 1024 + lane * 16;
            int r = off >> 6, cb = off & 63;
            __builtin_amdgcn_global_load_lds((const u32*)((const char*)A + ((size_t)(row0 + r) * 128 + kc) * 2 + cb),
                                             (u32*)(ldsc + wid * 2048 + i * 1024), 16, 0, 0);
            __builtin_amdgcn_global_load_lds((const u32*)((const char*)BT + ((size_t)r * 128 + kc) * 2 + cb),
                                             (u32*)(ldsc + 8192 + wid * 2048 + i * 1024), 16, 0, 0);
        }
        __syncthreads();
        bf16x8 af[4], bfr[4];
#pragma unroll
        for (int mt = 0; mt < 4; ++mt)
            af[mt] = *(const bf16x8*)(ldsc + (rA + mt * 16) * 64 + kch);
#pragma unroll
        for (int nt = 0; nt < 4; ++nt)
            bfr[nt] = *(const bf16x8*)(ldsc + 8192 + (rB + nt * 16) * 64 + kch);
#pragma unroll
        for (int mt = 0; mt < 4; ++mt)
#pragma unroll
            for (int nt = 0; nt < 4; ++nt)
                acc[mt][nt] = __builtin_amdgcn_mfma_f32_16x16x32_bf16(af[mt], bfr[nt], acc[mt][nt], 0, 0, 0);
        __syncthreads();
    }

    float* redS = (float*)ldsc;
    float* redQ = (float*)(ldsc + 2048);
    int colbase = wc * 64 + (lane & 15);
    int qrow = (lane >> 4) << 2;
    float rbv[4], gv[4], bev[4];
#pragma unroll
    for (int nt = 0; nt < 4; ++nt) {
        int c = colbase + nt * 16;
        rbv[nt] = rb[c]; gv[nt] = g[c]; bev[nt] = be[c];
    }
#pragma unroll
    for (int mt = 0; mt < 4; ++mt)
#pragma unroll
        for (int r = 0; r < 4; ++r) {
            float s = 0.f, q = 0.f;
#pragma unroll
            for (int nt = 0; nt < 4; ++nt) {
                float v = acc[mt][nt][r] + rbv[nt];
                s += v; q += v * v;
            }
            s = red16(s); q = red16(q);
            if ((lane & 15) == 0) {
                int lr = wr * 64 + qrow + mt * 16 + r;
                redS[lr * 2 + wc] = s; redQ[lr * 2 + wc] = q;
            }
        }
    __syncthreads();
#pragma unroll
    for (int mt = 0; mt < 4; ++mt)
#pragma unroll
        for (int r = 0; r < 4; ++r) {
            int lr = wr * 64 + qrow + mt * 16 + r;
            float mu = (redS[lr * 2] + redS[lr * 2 + 1]) * (1.f / 128.f);
            float var = (redQ[lr * 2] + redQ[lr * 2 + 1]) * (1.f / 128.f) - mu * mu;
            float rs = rsqrtf(var + 1e-5f);
            size_t rbase = (size_t)(row0 + lr) * 128;
#pragma unroll
            for (int nt = 0; nt < 4; ++nt) {
                float v = acc[mt][nt][r] + rbv[nt];
                float o = (v - mu) * rs * gv[nt] + bev[nt];
                o = o < 0.f ? 0.f : o;
                hout[rbase + colbase + nt * 16] = f2bf(o);
            }
        }
}

// ---------------- conv GEMM layers>=1: K=256 split (Aagg | h), fused bias+LN+relu ----------------

__global__ __launch_bounds__(256) void gemm_conv_ln_split(const u16* __restrict__ Aagg,
                                                          u16* h,
                                                          const u16* __restrict__ BT,
                                                          const float* __restrict__ rb,
                                                          const float* __restrict__ g,
                                                          const float* __restrict__ be) {
    __shared__ __align__(16) u16 lds[8192];
    char* ldsc = (char*)lds;
    int t = threadIdx.x, lane = t & 63, wid = t >> 6;
    int row0 = blockIdx.x * 128;

    f32x4 zero = {0.f, 0.f, 0.f, 0.f};
    f32x4 acc[4][4];
#pragma unroll
    for (int mt = 0; mt < 4; ++mt)
#pragma unroll
        for (int nt = 0; nt < 4; ++nt) acc[mt][nt] = zero;

    int wr = wid >> 1, wc = wid & 1;
    int rA = wr * 64 + (lane & 15);
    int rB = wc * 64 + (lane & 15);
    int kch = (lane >> 4) << 4;

    for (int kt = 0; kt < 8; ++kt) {
        const u16* Abase = (kt < 4) ? Aagg : (const u16*)h;
        int kcl = (kt & 3) << 5;
        int kc = kt << 5;
#pragma unroll
        for (int i = 0; i < 2; ++i) {
            int off = wid * 2048 + i * 1024 + lane * 16;
            int r = off >> 6, cb = off & 63;
            __builtin_amdgcn_global_load_lds((const u32*)((const char*)Abase + ((size_t)(row0 + r) * 128 + kcl) * 2 + cb),
                                             (u32*)(ldsc + wid * 2048 + i * 1024), 16, 0, 0);
            __builtin_amdgcn_global_load_lds((const u32*)((const char*)BT + ((size_t)r * 256 + kc) * 2 + cb),
                                             (u32*)(ldsc + 8192 + wid * 2048 + i * 1024), 16, 0, 0);
        }
        __syncthreads();
        bf16x8 af[4], bfr[4];
#pragma unroll
        for (int mt = 0; mt < 4; ++mt)
            af[mt] = *(const bf16x8*)(ldsc + (rA + mt * 16) * 64 + kch);
#pragma unroll
        for (int nt = 0; nt < 4; ++nt)
            bfr[nt] = *(const bf16x8*)(ldsc + 8192 + (rB + nt * 16) * 64 + kch);
#pragma unroll
        for (int mt = 0; mt < 4; ++mt)
#pragma unroll
            for (int nt = 0; nt < 4; ++nt)
                acc[mt][nt] = __builtin_amdgcn_mfma_f32_16x16x32_bf16(af[mt], bfr[nt], acc[mt][nt], 0, 0, 0);
        __syncthreads();
    }

    float* redS = (float*)ldsc;
    float* redQ = (float*)(ldsc + 2048);
    int colbase = wc * 64 + (lane & 15);
    int qrow = (lane >> 4) << 2;
    float rbv[4], gv[4], bev[4];
#pragma unroll
    for (int nt = 0; nt < 4; ++nt) {
        int c = colbase + nt * 16;
        rbv[nt] = rb[c]; gv[nt] = g[c]; bev[nt] = be[c];
    }
#pragma unroll
    for (int mt = 0; mt < 4; ++mt)
#pragma unroll
        for (int r = 0; r < 4; ++r) {
            float s = 0.f, q = 0.f;
#pragma unroll
            for (int nt = 0; nt < 4; ++nt) {
                float v = acc[mt][nt][r] + rbv[nt];
                s += v; q += v * v;
            }
            s = red16(s); q = red16(q);
            if ((lane & 15) == 0) {
                int lr = wr * 64 + qrow + mt * 16 + r;
                redS[lr * 2 + wc] = s; redQ[lr * 2 + wc] = q;
            }
        }
    __syncthreads();
#pragma unroll
    for (int mt = 0; mt < 4; ++mt)
#pragma unroll
        for (int r = 0; r < 4; ++r) {
            int lr = wr * 64 + qrow + mt * 16 + r;
            float mu = (redS[lr * 2] + redS[lr * 2 + 1]) * (1.f / 128.f);
            float var = (redQ[lr * 2] + redQ[lr * 2 + 1]) * (1.f / 128.f) - mu * mu;
            float rs = rsqrtf(var + 1e-5f);
            size_t rbase = (size_t)(row0 + lr) * 128;
#pragma unroll
            for (int nt = 0; nt < 4; ++nt) {
                float v = acc[mt][nt][r] + rbv[nt];
                float o = (v - mu) * rs * gv[nt] + bev[nt];
                o = o < 0.f ? 0.f : o;
                h[rbase + colbase + nt * 16] = f2bf(o);
            }
        }
}

// ---------------- fc GEMM: fused LN -> +residual -> LN; writes h AND hT (for next layer's agg) ----------------

__global__ __launch_bounds__(256) void gemm_fc_ln2(const u16* __restrict__ A,
                                                   const u16* __restrict__ BT,
                                                   const float* __restrict__ mg,
                                                   const float* __restrict__ mb,
                                                   const float* __restrict__ eg,
                                                   const float* __restrict__ eb,
                                                   u16* __restrict__ h,
                                                   u16* __restrict__ hT) {
    __shared__ __align__(16) u16 lds[8192];
    char* ldsc = (char*)lds;
    int t = threadIdx.x, lane = t & 63, wid = t >> 6;
    int row0 = blockIdx.x * 128;

    f32x4 zero = {0.f, 0.f, 0.f, 0.f};
    f32x4 acc[4][4];
#pragma unroll
    for (int mt = 0; mt < 4; ++mt)
#pragma unroll
        for (int nt = 0; nt < 4; ++nt) acc[mt][nt] = zero;

    int wr = wid >> 1, wc = wid & 1;
    int rA = wr * 64 + (lane & 15);
    int rB = wc * 64 + (lane & 15);
    int kch = (lane >> 4) << 4;

    for (int kt = 0; kt < 8; ++kt) {
        int kc = kt << 5;
#pragma unroll
        for (int i = 0; i < 2; ++i) {
            int off = wid * 2048 + i * 1024 + lane * 16;
            int r = off >> 6, cb = off & 63;
            __builtin_amdgcn_global_load_lds((const u32*)((const char*)A + ((size_t)(row0 + r) * 256 + kc) * 2 + cb),
                                             (u32*)(ldsc + wid * 2048 + i * 1024), 16, 0, 0);
            __builtin_amdgcn_global_load_lds((const u32*)((const char*)BT + ((size_t)r * 256 + kc) * 2 + cb),
                                             (u32*)(ldsc + 8192 + wid * 2048 + i * 1024), 16, 0, 0);
        }
        __syncthreads();
        bf16x8 af[4], bfr[4];
#pragma unroll
        for (int mt = 0; mt < 4; ++mt)
            af[mt] = *(const bf16x8*)(ldsc + (rA + mt * 16) * 64 + kch);
#pragma unroll
        for (int nt = 0; nt < 4; ++nt)
            bfr[nt] = *(const bf16x8*)(ldsc + 8192 + (rB + nt * 16) * 64 + kch);
#pragma unroll
        for (int mt = 0; mt < 4; ++mt)
#pragma unroll
            for (int nt = 0; nt < 4; ++nt)
                acc[mt][nt] = __builtin_amdgcn_mfma_f32_16x16x32_bf16(af[mt], bfr[nt], acc[mt][nt], 0, 0, 0);
        __syncthreads();
    }

    float* redS  = (float*)ldsc;
    float* redQ  = (float*)(ldsc + 2048);
    float* redS2 = (float*)(ldsc + 4096);
    float* redQ2 = (float*)(ldsc + 6144);
    int colbase = wc * 64 + (lane & 15);
    int qrow = (lane >> 4) << 2;
    float mgv[4], mbv[4], egv[4], ebv[4];
#pragma unroll
    for (int nt = 0; nt < 4; ++nt) {
        int c = colbase + nt * 16;
        mgv[nt] = mg[c]; mbv[nt] = mb[c]; egv[nt] = eg[c]; ebv[nt] = eb[c];
    }
#pragma unroll
    for (int mt = 0; mt < 4; ++mt)
#pragma unroll
        for (int r = 0; r < 4; ++r) {
            float s = 0.f, q = 0.f;
#pragma unroll
            for (int nt = 0; nt < 4; ++nt) {
                float v = acc[mt][nt][r];
                s += v; q += v * v;
            }
            s = red16(s); q = red16(q);
            if ((lane & 15) == 0) {
                int lr = wr * 64 + qrow + mt * 16 + r;
                redS[lr * 2 + wc] = s; redQ[lr * 2 + wc] = q;
            }
        }
    __syncthreads();
#pragma unroll
    for (int mt = 0; mt < 4; ++mt)
#pragma unroll
        for (int r = 0; r < 4; ++r) {
            int lr = wr * 64 + qrow + mt * 16 + r;
            float mu = (redS[lr * 2] + redS[lr * 2 + 1]) * (1.f / 128.f);
            float var = (redQ[lr * 2] + redQ[lr * 2 + 1]) * (1.f / 128.f) - mu * mu;
            float rs = rsqrtf(var + 1e-5f);
            size_t rbase = (size_t)(row0 + lr) * 128;
            float s2 = 0.f, q2 = 0.f;
#pragma unroll
            for (int nt = 0; nt < 4; ++nt) {
                float o = (acc[mt][nt][r] - mu) * rs * mgv[nt] + mbv[nt];
                float z = o + bf2f(h[rbase + colbase + nt * 16]);
                acc[mt][nt][r] = z;
                s2 += z; q2 += z * z;
            }
            s2 = red16(s2); q2 = red16(q2);
            if ((lane & 15) == 0) {
                redS2[lr * 2 + wc] = s2; redQ2[lr * 2 + wc] = q2;
            }
        }
    __syncthreads();
    int bb = row0 >> 8;
#pragma unroll
    for (int mt = 0; mt < 4; ++mt) {
        u16 tvals[4][4];   // [nt][r]
#pragma unroll
        for (int r = 0; r < 4; ++r) {
            int lr = wr * 64 + qrow + mt * 16 + r;
            float mu = (redS2[lr * 2] + redS2[lr * 2 + 1]) * (1.f / 128.f);
            float var = (redQ2[lr * 2] + redQ2[lr * 2 + 1]) * (1.f / 128.f) - mu * mu;
            float rs = rsqrtf(var + 1e-5f);
            size_t rbase = (size_t)(row0 + lr) * 128;
#pragma unroll
            for (int nt = 0; nt < 4; ++nt) {
                float z = acc[mt][nt][r];
                u16 o = f2bf((z - mu) * rs * egv[nt] + ebv[nt]);
                h[rbase + colbase + nt * 16] = o;
                tvals[nt][r] = o;
            }
        }
        int node0 = ((row0 & 255) + wr * 64 + qrow + mt * 16);
#pragma unroll
        for (int nt = 0; nt < 4; ++nt) {
            int d = colbase + nt * 16;
            *(ushort4*)(hT + (size_t)bb * 32768 + (size_t)d * 256 + node0) = *(ushort4*)tvals[nt];
        }
    }
}

// ---------------- fused attention: per (b, head) block; packed Q/K/V; P in registers ----------------

__global__ __launch_bounds__(512) void attn_k(const u16* __restrict__ qP,
                                              const u16* __restrict__ kP,
                                              const u16* __restrict__ vT,
                                              const float* __restrict__ mat,
                                              u16* __restrict__ ctx) {
    __shared__ __align__(16) u16 Kl[256 * 72];   // 36864 B (padded rows)
    __shared__ __align__(16) u16 Vl[64 * 264];   // 33792 B (padded rows)
    int t = threadIdx.x, lane = t & 63, w = t >> 6;
    int b = blockIdx.x, hh = blockIdx.y;
    int bh = b * 4 + hh;
    int lg = lane >> 4, q16 = lane & 15;

    // --- staging from packed buffers (dense 32KB each), all 512 threads ---
    {
        const u16* kb = kP + (size_t)bh * 16384;
#pragma unroll
        for (int i = 0; i < 4; ++i) {
            int idx = i * 512 + t;              // 2048 x 16B; K row = 64 u16 = 8 chunks
            int node = idx >> 3, oct = idx & 7;
            *(uint4*)(Kl + node * 72 + oct * 8) = *(const uint4*)(kb + node * 64 + oct * 8);
        }
        const u16* vb = vT + (size_t)bh * 16384;
#pragma unroll
        for (int i = 0; i < 4; ++i) {
            int idx = i * 512 + t;              // 2048 x 16B; V row = 256 u16 = 32 chunks
            int d = idx >> 5, p = idx & 31;
            *(uint4*)(Vl + d * 264 + p * 8) = *(const uint4*)(vb + d * 256 + p * 8);
        }
    }
    __syncthreads();

    f32x4 zero = {0.f, 0.f, 0.f, 0.f};
    bool loA = (lg < 2);
    int s01 = q16 + ((lg & 1) << 5);
    int s23 = s01 + 16;

    for (int qi = 0; qi < 2; ++qi) {
        int qrow_l = w * 32 + qi * 16;

        const u16* qsrc = qP + (size_t)bh * 16384 + (qrow_l + q16) * 64 + (lg << 3);
        bf16x8 aq0 = *(const bf16x8*)(qsrc);
        bf16x8 aq1 = *(const bf16x8*)(qsrc + 32);

        f32x4 sc[16];
#pragma unroll
        for (int nt = 0; nt < 16; ++nt) {
            const u16* ks = Kl + (nt * 16 + q16) * 72 + (lg << 3);
            bf16x8 k0 = *(const bf16x8*)(ks);
            bf16x8 k1 = *(const bf16x8*)(ks + 32);
            f32x4 a = __builtin_amdgcn_mfma_f32_16x16x32_bf16(k0, aq0, zero, 0, 0, 0);
            a = __builtin_amdgcn_mfma_f32_16x16x32_bf16(k1, aq1, a, 0, 0, 0);
            sc[nt] = a;
        }

        const float* mrow = mat + ((size_t)b * LL + qrow_l + q16) * LL + (lg << 2);
#pragma unroll
        for (int nt = 0; nt < 16; ++nt) {
            f32x4 mv = *(const f32x4*)(mrow + nt * 16);
#pragma unroll
            for (int r = 0; r < 4; ++r)
                sc[nt][r] *= mv[r];          // mat pre-scaled by 0.125
        }

        float mx = -1e30f;
#pragma unroll
        for (int nt = 0; nt < 16; ++nt)
#pragma unroll
            for (int r = 0; r < 4; ++r) mx = fmaxf(mx, sc[nt][r]);
        mx = fmaxf(mx, __shfl_xor(mx, 16, 64));
        mx = fmaxf(mx, __shfl_xor(mx, 32, 64));
        float sm = 0.f;
#pragma unroll
        for (int nt = 0; nt < 16; ++nt)
#pragma unroll
            for (int r = 0; r < 4; ++r) {
                float e = __expf(sc[nt][r] - mx);
                sc[nt][r] = e;
                sm += e;
            }
        sm += __shfl_xor(sm, 16, 64);
        sm += __shfl_xor(sm, 32, 64);
        float inv = 1.f / sm;
#pragma unroll
        for (int nt = 0; nt < 16; ++nt)
#pragma unroll
            for (int r = 0; r < 4; ++r) sc[nt][r] *= inv;

        f32x4 oa[4];
#pragma unroll
        for (int dt = 0; dt < 4; ++dt) oa[dt] = zero;
#pragma unroll
        for (int kt = 0; kt < 8; ++kt) {
            u32 A0 = cvtpk(sc[2 * kt][0], sc[2 * kt][1]);
            u32 A1 = cvtpk(sc[2 * kt][2], sc[2 * kt][3]);
            u32 B0 = cvtpk(sc[2 * kt + 1][0], sc[2 * kt + 1][1]);
            u32 B1 = cvtpk(sc[2 * kt + 1][2], sc[2 * kt + 1][3]);
            u32 a0s = bperm(s01, A0), b0s = bperm(s01, B0);
            u32 a1s = bperm(s01, A1), b1s = bperm(s01, B1);
            u32 a0t = bperm(s23, A0), b0t = bperm(s23, B0);
            u32 a1t = bperm(s23, A1), b1t = bperm(s23, B1);
            union { u32 u[4]; bf16x8 v; } pa;
            pa.u[0] = loA ? a0s : b0s;
            pa.u[1] = loA ? a1s : b1s;
            pa.u[2] = loA ? a0t : b0t;
            pa.u[3] = loA ? a1t : b1t;
#pragma unroll
            for (int dt = 0; dt < 4; ++dt) {
                bf16x8 bv = *(const bf16x8*)(Vl + (dt * 16 + q16) * 264 + kt * 32 + (lg << 3));
                oa[dt] = __builtin_amdgcn_mfma_f32_16x16x32_bf16(pa.v, bv, oa[dt], 0, 0, 0);
            }
        }
#pragma unroll
        for (int dt = 0; dt < 4; ++dt)
#pragma unroll
            for (int r = 0; r < 4; ++r)
                ctx[(size_t)(b * LL + qrow_l + (lg << 2) + r) * 256 + hh * 64 + dt * 16 + q16] = f2bf(oa[dt][r]);
    }
}

// ---------------- host launch ----------------

extern "C" void kernel_launch(void* const* d_in, const int* in_sizes, int n_in,
                              void* d_out, int out_size, void* d_ws, size_t ws_size,
                              hipStream_t stream) {
    (void)out_size; (void)ws_size; (void)n_in;
    const float* x        = (const float*)d_in[0];
    const int*   ei       = (const int*)d_in[1];
    const float* ea       = (const float*)d_in[2];
    const float* adj      = (const float*)d_in[3];
    const float* dis      = (const float*)d_in[4];
    int pb = (in_sizes[5] == 5120) ? 5 : 6;
    const float* g0_rel_w = (const float*)d_in[pb + 0];
    const float* g0_rel_b = (const float*)d_in[pb + 1];
    const float* g0_root_w= (const float*)d_in[pb + 2];
    const float* g_rel_w  = (const float*)d_in[pb + 3];
    const float* g_rel_b  = (const float*)d_in[pb + 4];
    const float* g_root_w = (const float*)d_in[pb + 5];
    const float* nm_g     = (const float*)d_in[pb + 6];
    const float* nm_b     = (const float*)d_in[pb + 7];
    const float* wq       = (const float*)d_in[pb + 8];
    const float* wk       = (const float*)d_in[pb + 9];
    const float* wv       = (const float*)d_in[pb + 10];
    const float* fc       = (const float*)d_in[pb + 11];
    const float* mha_g    = (const float*)d_in[pb + 12];
    const float* mha_b    = (const float*)d_in[pb + 13];
    const float* enc_g    = (const float*)d_in[pb + 14];
    const float* enc_b    = (const float*)d_in[pb + 15];
    const float* proj_w   = (const float*)d_in[pb + 16];
    const float* proj_b   = (const float*)d_in[pb + 17];
    const int* srcI = ei;
    const int* dstI = ei + EDGES;

    char* w = (char*)d_ws;
    float* Wf     = (float*)w; w += (size_t)33554432;   // W f32 scatter, then reused as `mat`
    u16*   Acat   = (u16*)w;   w += (size_t)16777216;   // Aagg [N,128] / ctx [N,256] (time-disjoint)
    u16*   h      = (u16*)w;   w += (size_t)8388608;
    u16*   qP     = (u16*)w;   w += (size_t)16777216;   // packed Q [bh][256][64]
    u16*   kP     = (u16*)w;   w += (size_t)16777216;   // packed K [bh][256][64]
    u16*   Wb     = (u16*)w;   w += (size_t)16777216;   // W bf16 [128][256][256]
    u16*   bigT   = (u16*)w;   w += (size_t)16777216;   // hT (8.4MB) / vT (16.7MB), time-disjoint
    u16* wconvT0  = (u16*)w;   w += (size_t)32768;
    u16* wconvT   = (u16*)w;   w += (size_t)196608;
    u16* wqkvT    = (u16*)w;   w += (size_t)786432;
    u16* fcT      = (u16*)w;   w += (size_t)262144;
    u16* projT    = (u16*)w;   w += (size_t)32768;
    float* mat = Wf;
    u16*   ctx = Acat;
    u16*   hT  = bigT;
    u16*   vT  = bigT;

    // --- prep (cast MUST precede build_matrix: mat aliases Wf) ---
    hipMemsetAsync(Wf, 0, 33554432, stream);
    scatter_w_k<<<2048, 256, 0, stream>>>(srcI, dstI, ea, Wf);
    cast_w_k<<<8192, 256, 0, stream>>>(Wf, Wb);
    build_matrix_k<<<32768, 256, 0, stream>>>(adj, dis, mat);
    prep_weights_k<<<2560, 256, 0, stream>>>(g0_rel_w, g0_root_w, g_rel_w, g_root_w,
                                             wq, wk, wv, fc, proj_w,
                                             wconvT0, wconvT, wqkvT, fcT, projT);
    transpose_x_k<<<2048, 256, 0, stream>>>(x, hT);

    for (int L = 0; L < 4; ++L) {
        if (L == 0) {
            gemm_agg<true><<<256, 256, 0, stream>>>(Wb, hT, x, Acat);
            gemm_conv_ln0<<<256, 256, 0, stream>>>(Acat, wconvT0, g0_rel_b, nm_g, nm_b, h);
        } else {
            gemm_agg<false><<<256, 256, 0, stream>>>(Wb, hT, x, Acat);
            gemm_conv_ln_split<<<256, 256, 0, stream>>>(Acat, h, wconvT + (L - 1) * 32768,
                                                        g_rel_b + (L - 1) * 128,
                                                        nm_g + L * 128, nm_b + L * 128);
        }
        gemm_qkv<<<dim3(256, 6), 256, 0, stream>>>(h, wqkvT + L * 98304, qP, kP, vT);
        attn_k<<<dim3(NB, 4), 512, 0, stream>>>(qP, kP, vT, mat, ctx);
        gemm_fc_ln2<<<256, 256, 0, stream>>>(ctx, fcT + L * 32768,
                                             mha_g + L * 128, mha_b + L * 128,
                                             enc_g + L * 128, enc_b + L * 128, h, hT);
    }
    gemm_proj<<<256, 256, 0, stream>>>(h, projT, (float*)d_out, proj_b);
}

// Round 14
// 505.721 us; speedup vs baseline: 1.3735x; 1.0314x over previous
//
#include <hip/hip_runtime.h>
#include <stdint.h>

typedef unsigned short u16;
typedef unsigned int u32;
typedef __attribute__((ext_vector_type(4))) float f32x4;
typedef __attribute__((ext_vector_type(8))) short bf16x8;

#define NB 128      // graphs
#define LL 256      // nodes per graph
#define DD 128      // hidden
#define EDGES 524288
#define EPG 4096    // edges per graph
#define NN (NB*LL)

__device__ __forceinline__ float bf2f(u16 u) {
    union { u32 i; float f; } v; v.i = ((u32)u) << 16; return v.f;
}
__device__ __forceinline__ u16 f2bf(float f) {
    union { float f; u32 i; } v; v.f = f;
    u32 i = v.i;
    u32 r = (i + 0x7fffu + ((i >> 16) & 1u)) >> 16;   // RNE
    return (u16)r;
}
__device__ __forceinline__ float matfn(float a, float dv) {
    if (a != 0.f) return (a == 1.2f) ? 1.1f : a;
    return (dv == 0.f) ? 0.f : exp2f((1.f - dv) * 0.5849625007211562f); // 1.5^(1-dis)
}
__device__ __forceinline__ float red16(float v) {
#pragma unroll
    for (int off = 1; off < 16; off <<= 1) v += __shfl_xor(v, off, 64);
    return v;
}
__device__ __forceinline__ u32 cvtpk(float lo, float hi) {
    u32 r;
    asm("v_cvt_pk_bf16_f32 %0, %1, %2" : "=v"(r) : "v"(lo), "v"(hi));
    return r;
}
__device__ __forceinline__ u32 bperm(int srcLane, u32 v) {
    return (u32)__builtin_amdgcn_ds_bpermute(srcLane << 2, (int)v);
}

// ---------------- prep kernels ----------------

__global__ __launch_bounds__(256) void scatter_w_k(const int* __restrict__ srcI,
                                                   const int* __restrict__ dstI,
                                                   const float* __restrict__ ew,
                                                   float* __restrict__ Wf) {
    int e = blockIdx.x * 256 + threadIdx.x;
    if (e >= EDGES) return;
    int b = e >> 12;
    atomicAdd(&Wf[(size_t)b * 65536 + (size_t)(dstI[e] & 255) * 256 + (srcI[e] & 255)], ew[e]);
}

// NOTE: must run BEFORE build_matrix_k (matB aliases Wf).
__global__ __launch_bounds__(256) void cast_w_k(const float* __restrict__ Wf, u16* __restrict__ Wb) {
    int i = blockIdx.x * 256 + threadIdx.x;
    float4 v = ((const float4*)Wf)[i];
    ushort4 o;
    o.x = f2bf(v.x); o.y = f2bf(v.y); o.z = f2bf(v.z); o.w = f2bf(v.w);
    ((ushort4*)Wb)[i] = o;
}

// matB holds bf16(0.125 * matfn) (attn scale folded in)
__global__ __launch_bounds__(256) void build_matrix_k(const float* __restrict__ adj,
                                                      const float* __restrict__ dis,
                                                      u16* __restrict__ matB) {
    int i = blockIdx.x * 256 + threadIdx.x;
    matB[i] = f2bf(0.125f * matfn(adj[i], dis[i]));
}

// all weight transposes in one kernel (655360 elements, 2560 blocks)
__global__ __launch_bounds__(256) void prep_weights_k(
        const float* __restrict__ g0_rel_w, const float* __restrict__ g0_root_w,
        const float* __restrict__ g_rel_w,  const float* __restrict__ g_root_w,
        const float* __restrict__ wq, const float* __restrict__ wk,
        const float* __restrict__ wv, const float* __restrict__ fc,
        const float* __restrict__ proj_w,
        u16* __restrict__ wconvT0, u16* __restrict__ wconvT,
        u16* __restrict__ wqkvT, u16* __restrict__ fcT, u16* __restrict__ projT) {
    int i = blockIdx.x * 256 + threadIdx.x;
    if (i < 16384) {
        int m = i >> 7, k = i & 127;
        float v = 0.f;
        if (k < 40) v = g0_rel_w[k * 128 + m];
        else if (k >= 64 && k < 104) v = g0_root_w[(k - 64) * 128 + m];
        wconvT0[i] = f2bf(v);
        return;
    }
    i -= 16384;
    if (i < 98304) {
        int l = i >> 15, jj = i & 32767;
        int m = jj >> 8, k = jj & 255;
        float v = (k < 128) ? g_rel_w[l * 16384 + k * 128 + m]
                            : g_root_w[l * 16384 + (k - 128) * 128 + m];
        wconvT[i] = f2bf(v);
        return;
    }
    i -= 98304;
    if (i < 393216) {
        int l = i / 98304, jj = i % 98304;
        int m = jj >> 7, k = jj & 127;
        const float* s = (m < 256) ? wq : (m < 512) ? wk : wv;
        int mm = m & 255;
        wqkvT[i] = f2bf(s[l * 32768 + k * 256 + mm]);
        return;
    }
    i -= 393216;
    if (i < 131072) {
        int l = i >> 15, jj = i & 32767;
        int m = jj >> 8, k = jj & 255;
        fcT[i] = f2bf(fc[l * 32768 + k * 128 + m]);
        return;
    }
    i -= 131072;
    {
        int m = i >> 7, k = i & 127;
        projT[i] = f2bf(proj_w[k * 128 + m]);
    }
}

// layer-0 transpose: x [N,40] f32 (zero-padded to 128) -> hT [b][128][256]
__global__ __launch_bounds__(256) void transpose_x_k(const float* __restrict__ x,
                                                     u16* __restrict__ hT) {
    int gw = blockIdx.x * 4 + (threadIdx.x >> 6);
    int lane = threadIdx.x & 63;
    int b = gw >> 6, rem = gw & 63, db = rem >> 5, jb = rem & 31;
    int d = (db << 6) + lane;
    u16 vals[8];
#pragma unroll
    for (int jj = 0; jj < 8; ++jj) {
        int node = (b << 8) + (jb << 3) + jj;
        vals[jj] = (d < 40) ? f2bf(x[(size_t)node * 40 + d]) : (u16)0;
    }
    *(uint4*)(hT + (size_t)b * 32768 + (size_t)d * 256 + (jb << 3)) = *(uint4*)vals;
}

// ---------------- FUSED per-graph agg GEMM + conv GEMM + bias+LN+relu ----------------
// block (b, rt): rows nbase+row0 .. +127.
// Phase A: agg = W@h (K=256, staged Wb+hT) -> acc
// Phase B: acc -> aggT LDS [128][136] bf16 (IS0: also overwrite cols 64..103 with x)
// Phase C: conv GEMM: A-chunks kt<4 from aggT, kt>=4 (layers>=1) from global h; B = wconvT
// Phase D: bias + LN + relu -> h

template<bool IS0>
__global__ __launch_bounds__(256) void gemm_agg_conv(const u16* __restrict__ Wb,
                                                     const u16* __restrict__ BT0,
                                                     const float* __restrict__ x,
                                                     u16* h,
                                                     const u16* __restrict__ BTc,
                                                     const float* __restrict__ rb,
                                                     const float* __restrict__ g,
                                                     const float* __restrict__ be) {
    __shared__ __align__(16) u16 lds[8192 + 128 * 136];   // 16KB stage + 34816B aggT
    char* ldsc = (char*)lds;
    u16* aggT = lds + 8192;
    int t = threadIdx.x, lane = t & 63, wid = t >> 6;
    int b = blockIdx.x >> 1, rt = blockIdx.x & 1;
    int row0 = rt << 7, nbase = b << 8;
    const u16* A = Wb + (size_t)b * 65536 + (size_t)row0 * 256;
    const u16* BT = BT0 + (size_t)b * 32768;

    f32x4 zero = {0.f, 0.f, 0.f, 0.f};
    f32x4 acc[4][4];
#pragma unroll
    for (int mt = 0; mt < 4; ++mt)
#pragma unroll
        for (int nt = 0; nt < 4; ++nt) acc[mt][nt] = zero;

    int wr = wid >> 1, wc = wid & 1;
    int rA = wr * 64 + (lane & 15);
    int rB = wc * 64 + (lane & 15);
    int kch = (lane >> 4) << 4;

    // ---- Phase A: agg GEMM (identical structure to previous gemm_agg) ----
    for (int kt = 0; kt < 8; ++kt) {
        int kc = kt << 5;
#pragma unroll
        for (int i = 0; i < 2; ++i) {
            int off = wid * 2048 + i * 1024 + lane * 16;
            int r = off >> 6, cb = off & 63;
            __builtin_amdgcn_global_load_lds((const u32*)((const char*)A + ((size_t)r * 256 + kc) * 2 + cb),
                                             (u32*)(ldsc + wid * 2048 + i * 1024), 16, 0, 0);
            __builtin_amdgcn_global_load_lds((const u32*)((const char*)BT + ((size_t)r * 256 + kc) * 2 + cb),
                                             (u32*)(ldsc + 8192 + wid * 2048 + i * 1024), 16, 0, 0);
        }
        __syncthreads();
        bf16x8 af[4], bfr[4];
#pragma unroll
        for (int mt = 0; mt < 4; ++mt)
            af[mt] = *(const bf16x8*)(ldsc + (rA + mt * 16) * 64 + kch);
#pragma unroll
        for (int nt = 0; nt < 4; ++nt)
            bfr[nt] = *(const bf16x8*)(ldsc + 8192 + (rB + nt * 16) * 64 + kch);
#pragma unroll
        for (int mt = 0; mt < 4; ++mt)
#pragma unroll
            for (int nt = 0; nt < 4; ++nt)
                acc[mt][nt] = __builtin_amdgcn_mfma_f32_16x16x32_bf16(af[mt], bfr[nt], acc[mt][nt], 0, 0, 0);
        __syncthreads();
    }

    // ---- Phase B: acc -> aggT (local rows 0..127, cols 0..127) ----
    {
        int colb = wc * 64 + (lane & 15);
        int rowb = wr * 64 + ((lane >> 4) << 2);
#pragma unroll
        for (int mt = 0; mt < 4; ++mt)
#pragma unroll
            for (int nt = 0; nt < 4; ++nt)
#pragma unroll
                for (int r = 0; r < 4; ++r)
                    aggT[(rowb + mt * 16 + r) * 136 + colb + nt * 16] = f2bf(acc[mt][nt][r]);
        if (IS0) {
            for (int idx = t; idx < 128 * 40; idx += 256) {
                int i = idx / 40, c = idx - i * 40;
                aggT[i * 136 + 64 + c] = f2bf(x[(size_t)(nbase + row0 + i) * 40 + c]);
            }
        }
    }
    __syncthreads();

    // ---- Phase C: conv GEMM ----
#pragma unroll
    for (int mt = 0; mt < 4; ++mt)
#pragma unroll
        for (int nt = 0; nt < 4; ++nt) acc[mt][nt] = zero;

    const int NKT = IS0 ? 4 : 8;
    const int KK = IS0 ? 128 : 256;
    for (int kt = 0; kt < NKT; ++kt) {
        int kc = kt << 5;
        bool fromLds = IS0 || (kt < 4);
#pragma unroll
        for (int i = 0; i < 2; ++i) {
            int off = wid * 2048 + i * 1024 + lane * 16;
            int r = off >> 6, cb = off & 63;
            if (!fromLds) {
                int kcl = (kt - 4) << 5;
                __builtin_amdgcn_global_load_lds((const u32*)((const char*)h + ((size_t)(nbase + row0 + r) * 128 + kcl) * 2 + cb),
                                                 (u32*)(ldsc + wid * 2048 + i * 1024), 16, 0, 0);
            }
            __builtin_amdgcn_global_load_lds((const u32*)((const char*)BTc + ((size_t)r * KK + kc) * 2 + cb),
                                             (u32*)(ldsc + 8192 + wid * 2048 + i * 1024), 16, 0, 0);
        }
        __syncthreads();
        bf16x8 af[4], bfr[4];
        if (fromLds) {
#pragma unroll
            for (int mt = 0; mt < 4; ++mt)
                af[mt] = *(const bf16x8*)((const char*)aggT + (rA + mt * 16) * 272 + kt * 64 + kch);
        } else {
#pragma unroll
            for (int mt = 0; mt < 4; ++mt)
                af[mt] = *(const bf16x8*)(ldsc + (rA + mt * 16) * 64 + kch);
        }
#pragma unroll
        for (int nt = 0; nt < 4; ++nt)
            bfr[nt] = *(const bf16x8*)(ldsc + 8192 + (rB + nt * 16) * 64 + kch);
#pragma unroll
        for (int mt = 0; mt < 4; ++mt)
#pragma unroll
            for (int nt = 0; nt < 4; ++nt)
                acc[mt][nt] = __builtin_amdgcn_mfma_f32_16x16x32_bf16(af[mt], bfr[nt], acc[mt][nt], 0, 0, 0);
        __syncthreads();
    }

    // ---- Phase D: bias + LN + relu -> h ----
    float* redS = (float*)ldsc;
    float* redQ = (float*)(ldsc + 2048);
    int colbase = wc * 64 + (lane & 15);
    int qrow = (lane >> 4) << 2;
    float rbv[4], gv[4], bev[4];
#pragma unroll
    for (int nt = 0; nt < 4; ++nt) {
        int c = colbase + nt * 16;
        rbv[nt] = rb[c]; gv[nt] = g[c]; bev[nt] = be[c];
    }
#pragma unroll
    for (int mt = 0; mt < 4; ++mt)
#pragma unroll
        for (int r = 0; r < 4; ++r) {
            float s = 0.f, q = 0.f;
#pragma unroll
            for (int nt = 0; nt < 4; ++nt) {
                float v = acc[mt][nt][r] + rbv[nt];
                s += v; q += v * v;
            }
            s = red16(s); q = red16(q);
            if ((lane & 15) == 0) {
                int lr = wr * 64 + qrow + mt * 16 + r;
                redS[lr * 2 + wc] = s; redQ[lr * 2 + wc] = q;
            }
        }
    __syncthreads();
#pragma unroll
    for (int mt = 0; mt < 4; ++mt)
#pragma unroll
        for (int r = 0; r < 4; ++r) {
            int lr = wr * 64 + qrow + mt * 16 + r;
            float mu = (redS[lr * 2] + redS[lr * 2 + 1]) * (1.f / 128.f);
            float var = (redQ[lr * 2] + redQ[lr * 2 + 1]) * (1.f / 128.f) - mu * mu;
            float rs = rsqrtf(var + 1e-5f);
            size_t rbase = (size_t)(nbase + row0 + lr) * 128;
#pragma unroll
            for (int nt = 0; nt < 4; ++nt) {
                float v = acc[mt][nt][r] + rbv[nt];
                float o = (v - mu) * rs * gv[nt] + bev[nt];
                o = o < 0.f ? 0.f : o;
                h[rbase + colbase + nt * 16] = f2bf(o);
            }
        }
}

// ---------------- qkv GEMM (K=128, Mtot=768): Q,K -> packed [bh][256][64]; V -> vT [bh][64][256] ----------------

__global__ __launch_bounds__(256) void gemm_qkv(const u16* __restrict__ A,
                                                const u16* __restrict__ BT,
                                                u16* __restrict__ qP,
                                                u16* __restrict__ kP,
                                                u16* __restrict__ vT) {
    __shared__ __align__(16) u16 lds[8192];
    char* ldsc = (char*)lds;
    int t = threadIdx.x, lane = t & 63, wid = t >> 6;
    int row0 = blockIdx.x * 128, col0 = blockIdx.y * 128;

    f32x4 zero = {0.f, 0.f, 0.f, 0.f};
    f32x4 acc[4][4];
#pragma unroll
    for (int mt = 0; mt < 4; ++mt)
#pragma unroll
        for (int nt = 0; nt < 4; ++nt) acc[mt][nt] = zero;

    int wr = wid >> 1, wc = wid & 1;
    int rA = wr * 64 + (lane & 15);
    int rB = wc * 64 + (lane & 15);
    int kch = (lane >> 4) << 4;

    for (int kt = 0; kt < 4; ++kt) {
        int kc = kt << 5;
#pragma unroll
        for (int i = 0; i < 2; ++i) {
            int off = wid * 2048 + i * 1024 + lane * 16;
            int r = off >> 6, cb = off & 63;
            __builtin_amdgcn_global_load_lds((const u32*)((const char*)A + ((size_t)(row0 + r) * 128 + kc) * 2 + cb),
                                             (u32*)(ldsc + wid * 2048 + i * 1024), 16, 0, 0);
            __builtin_amdgcn_global_load_lds((const u32*)((const char*)BT + ((size_t)(col0 + r) * 128 + kc) * 2 + cb),
                                             (u32*)(ldsc + 8192 + wid * 2048 + i * 1024), 16, 0, 0);
        }
        __syncthreads();
        bf16x8 af[4], bfr[4];
#pragma unroll
        for (int mt = 0; mt < 4; ++mt)
            af[mt] = *(const bf16x8*)(ldsc + (rA + mt * 16) * 64 + kch);
#pragma unroll
        for (int nt = 0; nt < 4; ++nt)
            bfr[nt] = *(const bf16x8*)(ldsc + 8192 + (rB + nt * 16) * 64 + kch);
#pragma unroll
        for (int mt = 0; mt < 4; ++mt)
#pragma unroll
            for (int nt = 0; nt < 4; ++nt)
                acc[mt][nt] = __builtin_amdgcn_mfma_f32_16x16x32_bf16(af[mt], bfr[nt], acc[mt][nt], 0, 0, 0);
        __syncthreads();
    }

    int colb = col0 + wc * 64 + (lane & 15);
    int rowb = row0 + wr * 64 + ((lane >> 4) << 2);
    int bb = row0 >> 8;
    if (col0 < 512) {
        u16* dst = (col0 < 256) ? qP : kP;
#pragma unroll
        for (int mt = 0; mt < 4; ++mt) {
#pragma unroll
            for (int nt = 0; nt < 4; ++nt) {
                int c = (colb + nt * 16) & 255;
                int hh = c >> 6, d = c & 63;
#pragma unroll
                for (int r = 0; r < 4; ++r) {
                    int node = (rowb + mt * 16 + r) & 255;
                    dst[(size_t)(bb * 4 + hh) * 16384 + node * 64 + d] = f2bf(acc[mt][nt][r]);
                }
            }
        }
    } else {
#pragma unroll
        for (int mt = 0; mt < 4; ++mt) {
            int node0 = (rowb + mt * 16) & 255;
#pragma unroll
            for (int nt = 0; nt < 4; ++nt) {
                int c = colb + nt * 16 - 512;
                int hh = c >> 6, d = c & 63;
                u16 tmp[4];
#pragma unroll
                for (int r = 0; r < 4; ++r) tmp[r] = f2bf(acc[mt][nt][r]);
                *(ushort4*)(vT + (size_t)(bb * 4 + hh) * 16384 + d * 256 + node0) = *(ushort4*)tmp;
            }
        }
    }
}

// ---------------- final projection GEMM (K=128, f32 out + bias) ----------------

__global__ __launch_bounds__(256) void gemm_proj(const u16* __restrict__ A,
                                                 const u16* __restrict__ BT,
                                                 float* __restrict__ Out,
                                                 const float* __restrict__ bias) {
    __shared__ __align__(16) u16 lds[8192];
    char* ldsc = (char*)lds;
    int t = threadIdx.x, lane = t & 63, wid = t >> 6;
    int row0 = blockIdx.x * 128;

    f32x4 zero = {0.f, 0.f, 0.f, 0.f};
    f32x4 acc[4][4];
#pragma unroll
    for (int mt = 0; mt < 4; ++mt)
#pragma unroll
        for (int nt = 0; nt < 4; ++nt) acc[mt][nt] = zero;

    int wr = wid >> 1, wc = wid & 1;
    int rA = wr * 64 + (lane & 15);
    int rB = wc * 64 + (lane & 15);
    int kch = (lane >> 4) << 4;

    for (int kt = 0; kt < 4; ++kt) {
        int kc = kt << 5;
#pragma unroll
        for (int i = 0; i < 2; ++i) {
            int off = wid * 2048 + i * 1024 + lane * 16;
            int r = off >> 6, cb = off & 63;
            __builtin_amdgcn_global_load_lds((const u32*)((const char*)A + ((size_t)(row0 + r) * 128 + kc) * 2 + cb),
                                             (u32*)(ldsc + wid * 2048 + i * 1024), 16, 0, 0);
            __builtin_amdgcn_global_load_lds((const u32*)((const char*)BT + ((size_t)r * 128 + kc) * 2 + cb),
                                             (u32*)(ldsc + 8192 + wid * 2048 + i * 1024), 16, 0, 0);
        }
        __syncthreads();
        bf16x8 af[4], bfr[4];
#pragma unroll
        for (int mt = 0; mt < 4; ++mt)
            af[mt] = *(const bf16x8*)(ldsc + (rA + mt * 16) * 64 + kch);
#pragma unroll
        for (int nt = 0; nt < 4; ++nt)
            bfr[nt] = *(const bf16x8*)(ldsc + 8192 + (rB + nt * 16) * 64 + kch);
#pragma unroll
        for (int mt = 0; mt < 4; ++mt)
#pragma unroll
            for (int nt = 0; nt < 4; ++nt)
                acc[mt][nt] = __builtin_amdgcn_mfma_f32_16x16x32_bf16(af[mt], bfr[nt], acc[mt][nt], 0, 0, 0);
        __syncthreads();
    }

    int colb = wc * 64 + (lane & 15);
    int rowb = row0 + wr * 64 + ((lane >> 4) << 2);
#pragma unroll
    for (int mt = 0; mt < 4; ++mt)
#pragma unroll
        for (int nt = 0; nt < 4; ++nt)
#pragma unroll
            for (int r = 0; r < 4; ++r)
                Out[(size_t)(rowb + mt * 16 + r) * 128 + colb + nt * 16] =
                    acc[mt][nt][r] + bias[colb + nt * 16];
}

// ---------------- fc GEMM: fused LN -> +residual -> LN; writes h AND hT (for next layer's agg) ----------------

__global__ __launch_bounds__(256) void gemm_fc_ln2(const u16* __restrict__ A,
                                                   const u16* __restrict__ BT,
                                                   const float* __restrict__ mg,
                                                   const float* __restrict__ mb,
                                                   const float* __restrict__ eg,
                                                   const float* __restrict__ eb,
                                                   u16* __restrict__ h,
                                                   u16* __restrict__ hT) {
    __shared__ __align__(16) u16 lds[8192];
    char* ldsc = (char*)lds;
    int t = threadIdx.x, lane = t & 63, wid = t >> 6;
    int row0 = blockIdx.x * 128;

    f32x4 zero = {0.f, 0.f, 0.f, 0.f};
    f32x4 acc[4][4];
#pragma unroll
    for (int mt = 0; mt < 4; ++mt)
#pragma unroll
        for (int nt = 0; nt < 4; ++nt) acc[mt][nt] = zero;

    int wr = wid >> 1, wc = wid & 1;
    int rA = wr * 64 + (lane & 15);
    int rB = wc * 64 + (lane & 15);
    int kch = (lane >> 4) << 4;

    for (int kt = 0; kt < 8; ++kt) {
        int kc = kt << 5;
#pragma unroll
        for (int i = 0; i < 2; ++i) {
            int off = wid * 2048 + i * 1024 + lane * 16;
            int r = off >> 6, cb = off & 63;
            __builtin_amdgcn_global_load_lds((const u32*)((const char*)A + ((size_t)(row0 + r) * 256 + kc) * 2 + cb),
                                             (u32*)(ldsc + wid * 2048 + i * 1024), 16, 0, 0);
            __builtin_amdgcn_global_load_lds((const u32*)((const char*)BT + ((size_t)r * 256 + kc) * 2 + cb),
                                             (u32*)(ldsc + 8192 + wid * 2048 + i * 1024), 16, 0, 0);
        }
        __syncthreads();
        bf16x8 af[4], bfr[4];
#pragma unroll
        for (int mt = 0; mt < 4; ++mt)
            af[mt] = *(const bf16x8*)(ldsc + (rA + mt * 16) * 64 + kch);
#pragma unroll
        for (int nt = 0; nt < 4; ++nt)
            bfr[nt] = *(const bf16x8*)(ldsc + 8192 + (rB + nt * 16) * 64 + kch);
#pragma unroll
        for (int mt = 0; mt < 4; ++mt)
#pragma unroll
            for (int nt = 0; nt < 4; ++nt)
                acc[mt][nt] = __builtin_amdgcn_mfma_f32_16x16x32_bf16(af[mt], bfr[nt], acc[mt][nt], 0, 0, 0);
        __syncthreads();
    }

    float* redS  = (float*)ldsc;
    float* redQ  = (float*)(ldsc + 2048);
    float* redS2 = (float*)(ldsc + 4096);
    float* redQ2 = (float*)(ldsc + 6144);
    int colbase = wc * 64 + (lane & 15);
    int qrow = (lane >> 4) << 2;
    float mgv[4], mbv[4], egv[4], ebv[4];
#pragma unroll
    for (int nt = 0; nt < 4; ++nt) {
        int c = colbase + nt * 16;
        mgv[nt] = mg[c]; mbv[nt] = mb[c]; egv[nt] = eg[c]; ebv[nt] = eb[c];
    }
#pragma unroll
    for (int mt = 0; mt < 4; ++mt)
#pragma unroll
        for (int r = 0; r < 4; ++r) {
            float s = 0.f, q = 0.f;
#pragma unroll
            for (int nt = 0; nt < 4; ++nt) {
                float v = acc[mt][nt][r];
                s += v; q += v * v;
            }
            s = red16(s); q = red16(q);
            if ((lane & 15) == 0) {
                int lr = wr * 64 + qrow + mt * 16 + r;
                redS[lr * 2 + wc] = s; redQ[lr * 2 + wc] = q;
            }
        }
    __syncthreads();
#pragma unroll
    for (int mt = 0; mt < 4; ++mt)
#pragma unroll
        for (int r = 0; r < 4; ++r) {
            int lr = wr * 64 + qrow + mt * 16 + r;
            float mu = (redS[lr * 2] + redS[lr * 2 + 1]) * (1.f / 128.f);
            float var = (redQ[lr * 2] + redQ[lr * 2 + 1]) * (1.f / 128.f) - mu * mu;
            float rs = rsqrtf(var + 1e-5f);
            size_t rbase = (size_t)(row0 + lr) * 128;
            float s2 = 0.f, q2 = 0.f;
#pragma unroll
            for (int nt = 0; nt < 4; ++nt) {
                float o = (acc[mt][nt][r] - mu) * rs * mgv[nt] + mbv[nt];
                float z = o + bf2f(h[rbase + colbase + nt * 16]);
                acc[mt][nt][r] = z;
                s2 += z; q2 += z * z;
            }
            s2 = red16(s2); q2 = red16(q2);
            if ((lane & 15) == 0) {
                redS2[lr * 2 + wc] = s2; redQ2[lr * 2 + wc] = q2;
            }
        }
    __syncthreads();
    int bb = row0 >> 8;
#pragma unroll
    for (int mt = 0; mt < 4; ++mt) {
        u16 tvals[4][4];   // [nt][r]
#pragma unroll
        for (int r = 0; r < 4; ++r) {
            int lr = wr * 64 + qrow + mt * 16 + r;
            float mu = (redS2[lr * 2] + redS2[lr * 2 + 1]) * (1.f / 128.f);
            float var = (redQ2[lr * 2] + redQ2[lr * 2 + 1]) * (1.f / 128.f) - mu * mu;
            float rs = rsqrtf(var + 1e-5f);
            size_t rbase = (size_t)(row0 + lr) * 128;
#pragma unroll
            for (int nt = 0; nt < 4; ++nt) {
                float z = acc[mt][nt][r];
                u16 o = f2bf((z - mu) * rs * egv[nt] + ebv[nt]);
                h[rbase + colbase + nt * 16] = o;
                tvals[nt][r] = o;
            }
        }
        int node0 = ((row0 & 255) + wr * 64 + qrow + mt * 16);
#pragma unroll
        for (int nt = 0; nt < 4; ++nt) {
            int d = colbase + nt * 16;
            *(ushort4*)(hT + (size_t)bb * 32768 + (size_t)d * 256 + node0) = *(ushort4*)tvals[nt];
        }
    }
}

// ---------------- fused attention: per (b, head) block; packed Q/K/V; bf16 mat; P in registers ----------------

__global__ __launch_bounds__(512) void attn_k(const u16* __restrict__ qP,
                                              const u16* __restrict__ kP,
                                              const u16* __restrict__ vT,
                                              const u16* __restrict__ matB,
                                              u16* __restrict__ ctx) {
    __shared__ __align__(16) u16 Kl[256 * 72];   // 36864 B (padded rows)
    __shared__ __align__(16) u16 Vl[64 * 264];   // 33792 B (padded rows)
    int t = threadIdx.x, lane = t & 63, w = t >> 6;
    int b = blockIdx.x, hh = blockIdx.y;
    int bh = b * 4 + hh;
    int lg = lane >> 4, q16 = lane & 15;

    // --- staging from packed buffers (dense 32KB each), all 512 threads ---
    {
        const u16* kb = kP + (size_t)bh * 16384;
#pragma unroll
        for (int i = 0; i < 4; ++i) {
            int idx = i * 512 + t;              // 2048 x 16B; K row = 64 u16 = 8 chunks
            int node = idx >> 3, oct = idx & 7;
            *(uint4*)(Kl + node * 72 + oct * 8) = *(const uint4*)(kb + node * 64 + oct * 8);
        }
        const u16* vb = vT + (size_t)bh * 16384;
#pragma unroll
        for (int i = 0; i < 4; ++i) {
            int idx = i * 512 + t;              // 2048 x 16B; V row = 256 u16 = 32 chunks
            int d = idx >> 5, p = idx & 31;
            *(uint4*)(Vl + d * 264 + p * 8) = *(const uint4*)(vb + d * 256 + p * 8);
        }
    }
    __syncthreads();

    f32x4 zero = {0.f, 0.f, 0.f, 0.f};
    bool loA = (lg < 2);
    int s01 = q16 + ((lg & 1) << 5);
    int s23 = s01 + 16;

    for (int qi = 0; qi < 2; ++qi) {
        int qrow_l = w * 32 + qi * 16;

        const u16* qsrc = qP + (size_t)bh * 16384 + (qrow_l + q16) * 64 + (lg << 3);
        bf16x8 aq0 = *(const bf16x8*)(qsrc);
        bf16x8 aq1 = *(const bf16x8*)(qsrc + 32);

        f32x4 sc[16];
#pragma unroll
        for (int nt = 0; nt < 16; ++nt) {
            const u16* ks = Kl + (nt * 16 + q16) * 72 + (lg << 3);
            bf16x8 k0 = *(const bf16x8*)(ks);
            bf16x8 k1 = *(const bf16x8*)(ks + 32);
            f32x4 a = __builtin_amdgcn_mfma_f32_16x16x32_bf16(k0, aq0, zero, 0, 0, 0);
            a = __builtin_amdgcn_mfma_f32_16x16x32_bf16(k1, aq1, a, 0, 0, 0);
            sc[nt] = a;
        }

        const u16* mrow = matB + ((size_t)b * LL + qrow_l + q16) * LL + (lg << 2);
#pragma unroll
        for (int nt = 0; nt < 16; ++nt) {
            ushort4 mv = *(const ushort4*)(mrow + nt * 16);
            sc[nt][0] *= bf2f(mv.x);
            sc[nt][1] *= bf2f(mv.y);
            sc[nt][2] *= bf2f(mv.z);
            sc[nt][3] *= bf2f(mv.w);
        }

        float mx = -1e30f;
#pragma unroll
        for (int nt = 0; nt < 16; ++nt)
#pragma unroll
            for (int r = 0; r < 4; ++r) mx = fmaxf(mx, sc[nt][r]);
        mx = fmaxf(mx, __shfl_xor(mx, 16, 64));
        mx = fmaxf(mx, __shfl_xor(mx, 32, 64));
        float sm = 0.f;
#pragma unroll
        for (int nt = 0; nt < 16; ++nt)
#pragma unroll
            for (int r = 0; r < 4; ++r) {
                float e = __expf(sc[nt][r] - mx);
                sc[nt][r] = e;
                sm += e;
            }
        sm += __shfl_xor(sm, 16, 64);
        sm += __shfl_xor(sm, 32, 64);
        float inv = 1.f / sm;
#pragma unroll
        for (int nt = 0; nt < 16; ++nt)
#pragma unroll
            for (int r = 0; r < 4; ++r) sc[nt][r] *= inv;

        f32x4 oa[4];
#pragma unroll
        for (int dt = 0; dt < 4; ++dt) oa[dt] = zero;
#pragma unroll
        for (int kt = 0; kt < 8; ++kt) {
            u32 A0 = cvtpk(sc[2 * kt][0], sc[2 * kt][1]);
            u32 A1 = cvtpk(sc[2 * kt][2], sc[2 * kt][3]);
            u32 B0 = cvtpk(sc[2 * kt + 1][0], sc[2 * kt + 1][1]);
            u32 B1 = cvtpk(sc[2 * kt + 1][2], sc[2 * kt + 1][3]);
            u32 a0s = bperm(s01, A0), b0s = bperm(s01, B0);
            u32 a1s = bperm(s01, A1), b1s = bperm(s01, B1);
            u32 a0t = bperm(s23, A0), b0t = bperm(s23, B0);
            u32 a1t = bperm(s23, A1), b1t = bperm(s23, B1);
            union { u32 u[4]; bf16x8 v; } pa;
            pa.u[0] = loA ? a0s : b0s;
            pa.u[1] = loA ? a1s : b1s;
            pa.u[2] = loA ? a0t : b0t;
            pa.u[3] = loA ? a1t : b1t;
#pragma unroll
            for (int dt = 0; dt < 4; ++dt) {
                bf16x8 bv = *(const bf16x8*)(Vl + (dt * 16 + q16) * 264 + kt * 32 + (lg << 3));
                oa[dt] = __builtin_amdgcn_mfma_f32_16x16x32_bf16(pa.v, bv, oa[dt], 0, 0, 0);
            }
        }
#pragma unroll
        for (int dt = 0; dt < 4; ++dt)
#pragma unroll
            for (int r = 0; r < 4; ++r)
                ctx[(size_t)(b * LL + qrow_l + (lg << 2) + r) * 256 + hh * 64 + dt * 16 + q16] = f2bf(oa[dt][r]);
    }
}

// ---------------- host launch ----------------

extern "C" void kernel_launch(void* const* d_in, const int* in_sizes, int n_in,
                              void* d_out, int out_size, void* d_ws, size_t ws_size,
                              hipStream_t stream) {
    (void)out_size; (void)ws_size; (void)n_in;
    const float* x        = (const float*)d_in[0];
    const int*   ei       = (const int*)d_in[1];
    const float* ea       = (const float*)d_in[2];
    const float* adj      = (const float*)d_in[3];
    const float* dis      = (const float*)d_in[4];
    int pb = (in_sizes[5] == 5120) ? 5 : 6;
    const float* g0_rel_w = (const float*)d_in[pb + 0];
    const float* g0_rel_b = (const float*)d_in[pb + 1];
    const float* g0_root_w= (const float*)d_in[pb + 2];
    const float* g_rel_w  = (const float*)d_in[pb + 3];
    const float* g_rel_b  = (const float*)d_in[pb + 4];
    const float* g_root_w = (const float*)d_in[pb + 5];
    const float* nm_g     = (const float*)d_in[pb + 6];
    const float* nm_b     = (const float*)d_in[pb + 7];
    const float* wq       = (const float*)d_in[pb + 8];
    const float* wk       = (const float*)d_in[pb + 9];
    const float* wv       = (const float*)d_in[pb + 10];
    const float* fc       = (const float*)d_in[pb + 11];
    const float* mha_g    = (const float*)d_in[pb + 12];
    const float* mha_b    = (const float*)d_in[pb + 13];
    const float* enc_g    = (const float*)d_in[pb + 14];
    const float* enc_b    = (const float*)d_in[pb + 15];
    const float* proj_w   = (const float*)d_in[pb + 16];
    const float* proj_b   = (const float*)d_in[pb + 17];
    const int* srcI = ei;
    const int* dstI = ei + EDGES;

    char* w = (char*)d_ws;
    float* Wf     = (float*)w; w += (size_t)33554432;   // W f32 scatter, then reused as matB (bf16)
    u16*   ctx    = (u16*)w;   w += (size_t)16777216;   // attn output [N,256]
    u16*   h      = (u16*)w;   w += (size_t)8388608;
    u16*   qP     = (u16*)w;   w += (size_t)16777216;   // packed Q [bh][256][64]
    u16*   kP     = (u16*)w;   w += (size_t)16777216;   // packed K [bh][256][64]
    u16*   Wb     = (u16*)w;   w += (size_t)16777216;   // W bf16 [128][256][256]
    u16*   bigT   = (u16*)w;   w += (size_t)16777216;   // hT (8.4MB) / vT (16.7MB), time-disjoint
    u16* wconvT0  = (u16*)w;   w += (size_t)32768;
    u16* wconvT   = (u16*)w;   w += (size_t)196608;
    u16* wqkvT    = (u16*)w;   w += (size_t)786432;
    u16* fcT      = (u16*)w;   w += (size_t)262144;
    u16* projT    = (u16*)w;   w += (size_t)32768;
    u16*   matB = (u16*)Wf;
    u16*   hT  = bigT;
    u16*   vT  = bigT;

    // --- prep (cast MUST precede build_matrix: matB aliases Wf) ---
    hipMemsetAsync(Wf, 0, 33554432, stream);
    scatter_w_k<<<2048, 256, 0, stream>>>(srcI, dstI, ea, Wf);
    cast_w_k<<<8192, 256, 0, stream>>>(Wf, Wb);
    build_matrix_k<<<32768, 256, 0, stream>>>(adj, dis, matB);
    prep_weights_k<<<2560, 256, 0, stream>>>(g0_rel_w, g0_root_w, g_rel_w, g_root_w,
                                             wq, wk, wv, fc, proj_w,
                                             wconvT0, wconvT, wqkvT, fcT, projT);
    transpose_x_k<<<2048, 256, 0, stream>>>(x, hT);

    for (int L = 0; L < 4; ++L) {
        if (L == 0)
            gemm_agg_conv<true><<<256, 256, 0, stream>>>(Wb, hT, x, h, wconvT0,
                                                         g0_rel_b, nm_g, nm_b);
        else
            gemm_agg_conv<false><<<256, 256, 0, stream>>>(Wb, hT, x, h, wconvT + (L - 1) * 32768,
                                                          g_rel_b + (L - 1) * 128,
                                                          nm_g + L * 128, nm_b + L * 128);
        gemm_qkv<<<dim3(256, 6), 256, 0, stream>>>(h, wqkvT + L * 98304, qP, kP, vT);
        attn_k<<<dim3(NB, 4), 512, 0, stream>>>(qP, kP, vT, matB, ctx);
        gemm_fc_ln2<<<256, 256, 0, stream>>>(ctx, fcT + L * 32768,
                                             mha_g + L * 128, mha_b + L * 128,
                                             enc_g + L * 128, enc_b + L * 128, h, hT);
    }
    gemm_proj<<<256, 256, 0, stream>>>(h, projT, (float*)d_out, proj_b);
}

// Round 15
// 472.876 us; speedup vs baseline: 1.4689x; 1.0695x over previous
//
#include <hip/hip_runtime.h>
#include <stdint.h>

typedef unsigned short u16;
typedef unsigned int u32;
typedef __attribute__((ext_vector_type(4))) float f32x4;
typedef __attribute__((ext_vector_type(8))) short bf16x8;

#define NB 128      // graphs
#define LL 256      // nodes per graph
#define DD 128      // hidden
#define EDGES 524288
#define EPG 4096    // edges per graph
#define NN (NB*LL)

__device__ __forceinline__ float bf2f(u16 u) {
    union { u32 i; float f; } v; v.i = ((u32)u) << 16; return v.f;
}
__device__ __forceinline__ u16 f2bf(float f) {
    union { float f; u32 i; } v; v.f = f;
    u32 i = v.i;
    u32 r = (i + 0x7fffu + ((i >> 16) & 1u)) >> 16;   // RNE
    return (u16)r;
}
__device__ __forceinline__ float matfn(float a, float dv) {
    if (a != 0.f) return (a == 1.2f) ? 1.1f : a;
    return (dv == 0.f) ? 0.f : exp2f((1.f - dv) * 0.5849625007211562f); // 1.5^(1-dis)
}
__device__ __forceinline__ float red16(float v) {
#pragma unroll
    for (int off = 1; off < 16; off <<= 1) v += __shfl_xor(v, off, 64);
    return v;
}
__device__ __forceinline__ u32 cvtpk(float lo, float hi) {
    u32 r;
    asm("v_cvt_pk_bf16_f32 %0, %1, %2" : "=v"(r) : "v"(lo), "v"(hi));
    return r;
}
__device__ __forceinline__ u32 bperm(int srcLane, u32 v) {
    return (u32)__builtin_amdgcn_ds_bpermute(srcLane << 2, (int)v);
}

// ---------------- prep kernels ----------------

__global__ __launch_bounds__(256) void scatter_w_k(const int* __restrict__ srcI,
                                                   const int* __restrict__ dstI,
                                                   const float* __restrict__ ew,
                                                   float* __restrict__ Wf) {
    int e = blockIdx.x * 256 + threadIdx.x;
    if (e >= EDGES) return;
    int b = e >> 12;
    atomicAdd(&Wf[(size_t)b * 65536 + (size_t)(dstI[e] & 255) * 256 + (srcI[e] & 255)], ew[e]);
}

// NOTE: must run BEFORE build_matrix_k (matB aliases Wf).
__global__ __launch_bounds__(256) void cast_w_k(const float* __restrict__ Wf, u16* __restrict__ Wb) {
    int i = blockIdx.x * 256 + threadIdx.x;
    float4 v = ((const float4*)Wf)[i];
    ushort4 o;
    o.x = f2bf(v.x); o.y = f2bf(v.y); o.z = f2bf(v.z); o.w = f2bf(v.w);
    ((ushort4*)Wb)[i] = o;
}

// matB holds bf16(0.125 * matfn) (attn scale folded in)
__global__ __launch_bounds__(256) void build_matrix_k(const float* __restrict__ adj,
                                                      const float* __restrict__ dis,
                                                      u16* __restrict__ matB) {
    int i = blockIdx.x * 256 + threadIdx.x;
    matB[i] = f2bf(0.125f * matfn(adj[i], dis[i]));
}

// all weight transposes in one kernel (655360 elements, 2560 blocks)
__global__ __launch_bounds__(256) void prep_weights_k(
        const float* __restrict__ g0_rel_w, const float* __restrict__ g0_root_w,
        const float* __restrict__ g_rel_w,  const float* __restrict__ g_root_w,
        const float* __restrict__ wq, const float* __restrict__ wk,
        const float* __restrict__ wv, const float* __restrict__ fc,
        const float* __restrict__ proj_w,
        u16* __restrict__ wconvT0, u16* __restrict__ wconvT,
        u16* __restrict__ wqkvT, u16* __restrict__ fcT, u16* __restrict__ projT) {
    int i = blockIdx.x * 256 + threadIdx.x;
    if (i < 16384) {
        int m = i >> 7, k = i & 127;
        float v = 0.f;
        if (k < 40) v = g0_rel_w[k * 128 + m];
        else if (k >= 64 && k < 104) v = g0_root_w[(k - 64) * 128 + m];
        wconvT0[i] = f2bf(v);
        return;
    }
    i -= 16384;
    if (i < 98304) {
        int l = i >> 15, jj = i & 32767;
        int m = jj >> 8, k = jj & 255;
        float v = (k < 128) ? g_rel_w[l * 16384 + k * 128 + m]
                            : g_root_w[l * 16384 + (k - 128) * 128 + m];
        wconvT[i] = f2bf(v);
        return;
    }
    i -= 98304;
    if (i < 393216) {
        int l = i / 98304, jj = i % 98304;
        int m = jj >> 7, k = jj & 127;
        const float* s = (m < 256) ? wq : (m < 512) ? wk : wv;
        int mm = m & 255;
        wqkvT[i] = f2bf(s[l * 32768 + k * 256 + mm]);
        return;
    }
    i -= 393216;
    if (i < 131072) {
        int l = i >> 15, jj = i & 32767;
        int m = jj >> 8, k = jj & 255;
        fcT[i] = f2bf(fc[l * 32768 + k * 128 + m]);
        return;
    }
    i -= 131072;
    {
        int m = i >> 7, k = i & 127;
        projT[i] = f2bf(proj_w[k * 128 + m]);
    }
}

// layer-0 transpose: x [N,40] f32 (zero-padded to 128) -> hT [b][128][256]
__global__ __launch_bounds__(256) void transpose_x_k(const float* __restrict__ x,
                                                     u16* __restrict__ hT) {
    int gw = blockIdx.x * 4 + (threadIdx.x >> 6);
    int lane = threadIdx.x & 63;
    int b = gw >> 6, rem = gw & 63, db = rem >> 5, jb = rem & 31;
    int d = (db << 6) + lane;
    u16 vals[8];
#pragma unroll
    for (int jj = 0; jj < 8; ++jj) {
        int node = (b << 8) + (jb << 3) + jj;
        vals[jj] = (d < 40) ? f2bf(x[(size_t)node * 40 + d]) : (u16)0;
    }
    *(uint4*)(hT + (size_t)b * 32768 + (size_t)d * 256 + (jb << 3)) = *(uint4*)vals;
}

// ---------------- FUSED per-graph agg GEMM + conv GEMM + bias+LN+relu ----------------

template<bool IS0>
__global__ __launch_bounds__(256) void gemm_agg_conv(const u16* __restrict__ Wb,
                                                     const u16* __restrict__ BT0,
                                                     const float* __restrict__ x,
                                                     u16* h,
                                                     const u16* __restrict__ BTc,
                                                     const float* __restrict__ rb,
                                                     const float* __restrict__ g,
                                                     const float* __restrict__ be) {
    __shared__ __align__(16) u16 lds[8192 + 128 * 136];   // 16KB stage + 34816B aggT
    char* ldsc = (char*)lds;
    u16* aggT = lds + 8192;
    int t = threadIdx.x, lane = t & 63, wid = t >> 6;
    int b = blockIdx.x >> 1, rt = blockIdx.x & 1;
    int row0 = rt << 7, nbase = b << 8;
    const u16* A = Wb + (size_t)b * 65536 + (size_t)row0 * 256;
    const u16* BT = BT0 + (size_t)b * 32768;

    f32x4 zero = {0.f, 0.f, 0.f, 0.f};
    f32x4 acc[4][4];
#pragma unroll
    for (int mt = 0; mt < 4; ++mt)
#pragma unroll
        for (int nt = 0; nt < 4; ++nt) acc[mt][nt] = zero;

    int wr = wid >> 1, wc = wid & 1;
    int rA = wr * 64 + (lane & 15);
    int rB = wc * 64 + (lane & 15);
    int kch = (lane >> 4) << 4;

    // ---- Phase A: agg GEMM ----
    for (int kt = 0; kt < 8; ++kt) {
        int kc = kt << 5;
#pragma unroll
        for (int i = 0; i < 2; ++i) {
            int off = wid * 2048 + i * 1024 + lane * 16;
            int r = off >> 6, cb = off & 63;
            __builtin_amdgcn_global_load_lds((const u32*)((const char*)A + ((size_t)r * 256 + kc) * 2 + cb),
                                             (u32*)(ldsc + wid * 2048 + i * 1024), 16, 0, 0);
            __builtin_amdgcn_global_load_lds((const u32*)((const char*)BT + ((size_t)r * 256 + kc) * 2 + cb),
                                             (u32*)(ldsc + 8192 + wid * 2048 + i * 1024), 16, 0, 0);
        }
        __syncthreads();
        bf16x8 af[4], bfr[4];
#pragma unroll
        for (int mt = 0; mt < 4; ++mt)
            af[mt] = *(const bf16x8*)(ldsc + (rA + mt * 16) * 64 + kch);
#pragma unroll
        for (int nt = 0; nt < 4; ++nt)
            bfr[nt] = *(const bf16x8*)(ldsc + 8192 + (rB + nt * 16) * 64 + kch);
#pragma unroll
        for (int mt = 0; mt < 4; ++mt)
#pragma unroll
            for (int nt = 0; nt < 4; ++nt)
                acc[mt][nt] = __builtin_amdgcn_mfma_f32_16x16x32_bf16(af[mt], bfr[nt], acc[mt][nt], 0, 0, 0);
        __syncthreads();
    }

    // ---- Phase B: acc -> aggT ----
    {
        int colb = wc * 64 + (lane & 15);
        int rowb = wr * 64 + ((lane >> 4) << 2);
#pragma unroll
        for (int mt = 0; mt < 4; ++mt)
#pragma unroll
            for (int nt = 0; nt < 4; ++nt)
#pragma unroll
                for (int r = 0; r < 4; ++r)
                    aggT[(rowb + mt * 16 + r) * 136 + colb + nt * 16] = f2bf(acc[mt][nt][r]);
        if (IS0) {
            for (int idx = t; idx < 128 * 40; idx += 256) {
                int i = idx / 40, c = idx - i * 40;
                aggT[i * 136 + 64 + c] = f2bf(x[(size_t)(nbase + row0 + i) * 40 + c]);
            }
        }
    }
    __syncthreads();

    // ---- Phase C: conv GEMM ----
#pragma unroll
    for (int mt = 0; mt < 4; ++mt)
#pragma unroll
        for (int nt = 0; nt < 4; ++nt) acc[mt][nt] = zero;

    const int NKT = IS0 ? 4 : 8;
    const int KK = IS0 ? 128 : 256;
    for (int kt = 0; kt < NKT; ++kt) {
        int kc = kt << 5;
        bool fromLds = IS0 || (kt < 4);
#pragma unroll
        for (int i = 0; i < 2; ++i) {
            int off = wid * 2048 + i * 1024 + lane * 16;
            int r = off >> 6, cb = off & 63;
            if (!fromLds) {
                int kcl = (kt - 4) << 5;
                __builtin_amdgcn_global_load_lds((const u32*)((const char*)h + ((size_t)(nbase + row0 + r) * 128 + kcl) * 2 + cb),
                                                 (u32*)(ldsc + wid * 2048 + i * 1024), 16, 0, 0);
            }
            __builtin_amdgcn_global_load_lds((const u32*)((const char*)BTc + ((size_t)r * KK + kc) * 2 + cb),
                                             (u32*)(ldsc + 8192 + wid * 2048 + i * 1024), 16, 0, 0);
        }
        __syncthreads();
        bf16x8 af[4], bfr[4];
        if (fromLds) {
#pragma unroll
            for (int mt = 0; mt < 4; ++mt)
                af[mt] = *(const bf16x8*)((const char*)aggT + (rA + mt * 16) * 272 + kt * 64 + kch);
        } else {
#pragma unroll
            for (int mt = 0; mt < 4; ++mt)
                af[mt] = *(const bf16x8*)(ldsc + (rA + mt * 16) * 64 + kch);
        }
#pragma unroll
        for (int nt = 0; nt < 4; ++nt)
            bfr[nt] = *(const bf16x8*)(ldsc + 8192 + (rB + nt * 16) * 64 + kch);
#pragma unroll
        for (int mt = 0; mt < 4; ++mt)
#pragma unroll
            for (int nt = 0; nt < 4; ++nt)
                acc[mt][nt] = __builtin_amdgcn_mfma_f32_16x16x32_bf16(af[mt], bfr[nt], acc[mt][nt], 0, 0, 0);
        __syncthreads();
    }

    // ---- Phase D: bias + LN + relu -> h ----
    float* redS = (float*)ldsc;
    float* redQ = (float*)(ldsc + 2048);
    int colbase = wc * 64 + (lane & 15);
    int qrow = (lane >> 4) << 2;
    float rbv[4], gv[4], bev[4];
#pragma unroll
    for (int nt = 0; nt < 4; ++nt) {
        int c = colbase + nt * 16;
        rbv[nt] = rb[c]; gv[nt] = g[c]; bev[nt] = be[c];
    }
#pragma unroll
    for (int mt = 0; mt < 4; ++mt)
#pragma unroll
        for (int r = 0; r < 4; ++r) {
            float s = 0.f, q = 0.f;
#pragma unroll
            for (int nt = 0; nt < 4; ++nt) {
                float v = acc[mt][nt][r] + rbv[nt];
                s += v; q += v * v;
            }
            s = red16(s); q = red16(q);
            if ((lane & 15) == 0) {
                int lr = wr * 64 + qrow + mt * 16 + r;
                redS[lr * 2 + wc] = s; redQ[lr * 2 + wc] = q;
            }
        }
    __syncthreads();
#pragma unroll
    for (int mt = 0; mt < 4; ++mt)
#pragma unroll
        for (int r = 0; r < 4; ++r) {
            int lr = wr * 64 + qrow + mt * 16 + r;
            float mu = (redS[lr * 2] + redS[lr * 2 + 1]) * (1.f / 128.f);
            float var = (redQ[lr * 2] + redQ[lr * 2 + 1]) * (1.f / 128.f) - mu * mu;
            float rs = rsqrtf(var + 1e-5f);
            size_t rbase = (size_t)(nbase + row0 + lr) * 128;
#pragma unroll
            for (int nt = 0; nt < 4; ++nt) {
                float v = acc[mt][nt][r] + rbv[nt];
                float o = (v - mu) * rs * gv[nt] + bev[nt];
                o = o < 0.f ? 0.f : o;
                h[rbase + colbase + nt * 16] = f2bf(o);
            }
        }
}

// ---------------- qkv GEMM (K=128, Mtot=768): Q,K -> packed [bh][256][64]; V -> vT [bh][64][256] ----------------

__global__ __launch_bounds__(256) void gemm_qkv(const u16* __restrict__ A,
                                                const u16* __restrict__ BT,
                                                u16* __restrict__ qP,
                                                u16* __restrict__ kP,
                                                u16* __restrict__ vT) {
    __shared__ __align__(16) u16 lds[8192];
    char* ldsc = (char*)lds;
    int t = threadIdx.x, lane = t & 63, wid = t >> 6;
    int row0 = blockIdx.x * 128, col0 = blockIdx.y * 128;

    f32x4 zero = {0.f, 0.f, 0.f, 0.f};
    f32x4 acc[4][4];
#pragma unroll
    for (int mt = 0; mt < 4; ++mt)
#pragma unroll
        for (int nt = 0; nt < 4; ++nt) acc[mt][nt] = zero;

    int wr = wid >> 1, wc = wid & 1;
    int rA = wr * 64 + (lane & 15);
    int rB = wc * 64 + (lane & 15);
    int kch = (lane >> 4) << 4;

    for (int kt = 0; kt < 4; ++kt) {
        int kc = kt << 5;
#pragma unroll
        for (int i = 0; i < 2; ++i) {
            int off = wid * 2048 + i * 1024 + lane * 16;
            int r = off >> 6, cb = off & 63;
            __builtin_amdgcn_global_load_lds((const u32*)((const char*)A + ((size_t)(row0 + r) * 128 + kc) * 2 + cb),
                                             (u32*)(ldsc + wid * 2048 + i * 1024), 16, 0, 0);
            __builtin_amdgcn_global_load_lds((const u32*)((const char*)BT + ((size_t)(col0 + r) * 128 + kc) * 2 + cb),
                                             (u32*)(ldsc + 8192 + wid * 2048 + i * 1024), 16, 0, 0);
        }
        __syncthreads();
        bf16x8 af[4], bfr[4];
#pragma unroll
        for (int mt = 0; mt < 4; ++mt)
            af[mt] = *(const bf16x8*)(ldsc + (rA + mt * 16) * 64 + kch);
#pragma unroll
        for (int nt = 0; nt < 4; ++nt)
            bfr[nt] = *(const bf16x8*)(ldsc + 8192 + (rB + nt * 16) * 64 + kch);
#pragma unroll
        for (int mt = 0; mt < 4; ++mt)
#pragma unroll
            for (int nt = 0; nt < 4; ++nt)
                acc[mt][nt] = __builtin_amdgcn_mfma_f32_16x16x32_bf16(af[mt], bfr[nt], acc[mt][nt], 0, 0, 0);
        __syncthreads();
    }

    int colb = col0 + wc * 64 + (lane & 15);
    int rowb = row0 + wr * 64 + ((lane >> 4) << 2);
    int bb = row0 >> 8;
    if (col0 < 512) {
        u16* dst = (col0 < 256) ? qP : kP;
#pragma unroll
        for (int mt = 0; mt < 4; ++mt) {
#pragma unroll
            for (int nt = 0; nt < 4; ++nt) {
                int c = (colb + nt * 16) & 255;
                int hh = c >> 6, d = c & 63;
#pragma unroll
                for (int r = 0; r < 4; ++r) {
                    int node = (rowb + mt * 16 + r) & 255;
                    dst[(size_t)(bb * 4 + hh) * 16384 + node * 64 + d] = f2bf(acc[mt][nt][r]);
                }
            }
        }
    } else {
#pragma unroll
        for (int mt = 0; mt < 4; ++mt) {
            int node0 = (rowb + mt * 16) & 255;
#pragma unroll
            for (int nt = 0; nt < 4; ++nt) {
                int c = colb + nt * 16 - 512;
                int hh = c >> 6, d = c & 63;
                u16 tmp[4];
#pragma unroll
                for (int r = 0; r < 4; ++r) tmp[r] = f2bf(acc[mt][nt][r]);
                *(ushort4*)(vT + (size_t)(bb * 4 + hh) * 16384 + d * 256 + node0) = *(ushort4*)tmp;
            }
        }
    }
}

// ---------------- final projection GEMM (K=128, f32 out + bias) ----------------

__global__ __launch_bounds__(256) void gemm_proj(const u16* __restrict__ A,
                                                 const u16* __restrict__ BT,
                                                 float* __restrict__ Out,
                                                 const float* __restrict__ bias) {
    __shared__ __align__(16) u16 lds[8192];
    char* ldsc = (char*)lds;
    int t = threadIdx.x, lane = t & 63, wid = t >> 6;
    int row0 = blockIdx.x * 128;

    f32x4 zero = {0.f, 0.f, 0.f, 0.f};
    f32x4 acc[4][4];
#pragma unroll
    for (int mt = 0; mt < 4; ++mt)
#pragma unroll
        for (int nt = 0; nt < 4; ++nt) acc[mt][nt] = zero;

    int wr = wid >> 1, wc = wid & 1;
    int rA = wr * 64 + (lane & 15);
    int rB = wc * 64 + (lane & 15);
    int kch = (lane >> 4) << 4;

    for (int kt = 0; kt < 4; ++kt) {
        int kc = kt << 5;
#pragma unroll
        for (int i = 0; i < 2; ++i) {
            int off = wid * 2048 + i * 1024 + lane * 16;
            int r = off >> 6, cb = off & 63;
            __builtin_amdgcn_global_load_lds((const u32*)((const char*)A + ((size_t)(row0 + r) * 128 + kc) * 2 + cb),
                                             (u32*)(ldsc + wid * 2048 + i * 1024), 16, 0, 0);
            __builtin_amdgcn_global_load_lds((const u32*)((const char*)BT + ((size_t)r * 128 + kc) * 2 + cb),
                                             (u32*)(ldsc + 8192 + wid * 2048 + i * 1024), 16, 0, 0);
        }
        __syncthreads();
        bf16x8 af[4], bfr[4];
#pragma unroll
        for (int mt = 0; mt < 4; ++mt)
            af[mt] = *(const bf16x8*)(ldsc + (rA + mt * 16) * 64 + kch);
#pragma unroll
        for (int nt = 0; nt < 4; ++nt)
            bfr[nt] = *(const bf16x8*)(ldsc + 8192 + (rB + nt * 16) * 64 + kch);
#pragma unroll
        for (int mt = 0; mt < 4; ++mt)
#pragma unroll
            for (int nt = 0; nt < 4; ++nt)
                acc[mt][nt] = __builtin_amdgcn_mfma_f32_16x16x32_bf16(af[mt], bfr[nt], acc[mt][nt], 0, 0, 0);
        __syncthreads();
    }

    int colb = wc * 64 + (lane & 15);
    int rowb = row0 + wr * 64 + ((lane >> 4) << 2);
#pragma unroll
    for (int mt = 0; mt < 4; ++mt)
#pragma unroll
        for (int nt = 0; nt < 4; ++nt)
#pragma unroll
            for (int r = 0; r < 4; ++r)
                Out[(size_t)(rowb + mt * 16 + r) * 128 + colb + nt * 16] =
                    acc[mt][nt][r] + bias[colb + nt * 16];
}

// ---------------- fc GEMM: fused LN -> +residual -> LN; writes h AND hT (for next layer's agg) ----------------

__global__ __launch_bounds__(256) void gemm_fc_ln2(const u16* __restrict__ A,
                                                   const u16* __restrict__ BT,
                                                   const float* __restrict__ mg,
                                                   const float* __restrict__ mb,
                                                   const float* __restrict__ eg,
                                                   const float* __restrict__ eb,
                                                   u16* __restrict__ h,
                                                   u16* __restrict__ hT) {
    __shared__ __align__(16) u16 lds[8192];
    char* ldsc = (char*)lds;
    int t = threadIdx.x, lane = t & 63, wid = t >> 6;
    int row0 = blockIdx.x * 128;

    f32x4 zero = {0.f, 0.f, 0.f, 0.f};
    f32x4 acc[4][4];
#pragma unroll
    for (int mt = 0; mt < 4; ++mt)
#pragma unroll
        for (int nt = 0; nt < 4; ++nt) acc[mt][nt] = zero;

    int wr = wid >> 1, wc = wid & 1;
    int rA = wr * 64 + (lane & 15);
    int rB = wc * 64 + (lane & 15);
    int kch = (lane >> 4) << 4;

    for (int kt = 0; kt < 8; ++kt) {
        int kc = kt << 5;
#pragma unroll
        for (int i = 0; i < 2; ++i) {
            int off = wid * 2048 + i * 1024 + lane * 16;
            int r = off >> 6, cb = off & 63;
            __builtin_amdgcn_global_load_lds((const u32*)((const char*)A + ((size_t)(row0 + r) * 256 + kc) * 2 + cb),
                                             (u32*)(ldsc + wid * 2048 + i * 1024), 16, 0, 0);
            __builtin_amdgcn_global_load_lds((const u32*)((const char*)BT + ((size_t)r * 256 + kc) * 2 + cb),
                                             (u32*)(ldsc + 8192 + wid * 2048 + i * 1024), 16, 0, 0);
        }
        __syncthreads();
        bf16x8 af[4], bfr[4];
#pragma unroll
        for (int mt = 0; mt < 4; ++mt)
            af[mt] = *(const bf16x8*)(ldsc + (rA + mt * 16) * 64 + kch);
#pragma unroll
        for (int nt = 0; nt < 4; ++nt)
            bfr[nt] = *(const bf16x8*)(ldsc + 8192 + (rB + nt * 16) * 64 + kch);
#pragma unroll
        for (int mt = 0; mt < 4; ++mt)
#pragma unroll
            for (int nt = 0; nt < 4; ++nt)
                acc[mt][nt] = __builtin_amdgcn_mfma_f32_16x16x32_bf16(af[mt], bfr[nt], acc[mt][nt], 0, 0, 0);
        __syncthreads();
    }

    float* redS  = (float*)ldsc;
    float* redQ  = (float*)(ldsc + 2048);
    float* redS2 = (float*)(ldsc + 4096);
    float* redQ2 = (float*)(ldsc + 6144);
    int colbase = wc * 64 + (lane & 15);
    int qrow = (lane >> 4) << 2;
    float mgv[4], mbv[4], egv[4], ebv[4];
#pragma unroll
    for (int nt = 0; nt < 4; ++nt) {
        int c = colbase + nt * 16;
        mgv[nt] = mg[c]; mbv[nt] = mb[c]; egv[nt] = eg[c]; ebv[nt] = eb[c];
    }
#pragma unroll
    for (int mt = 0; mt < 4; ++mt)
#pragma unroll
        for (int r = 0; r < 4; ++r) {
            float s = 0.f, q = 0.f;
#pragma unroll
            for (int nt = 0; nt < 4; ++nt) {
                float v = acc[mt][nt][r];
                s += v; q += v * v;
            }
            s = red16(s); q = red16(q);
            if ((lane & 15) == 0) {
                int lr = wr * 64 + qrow + mt * 16 + r;
                redS[lr * 2 + wc] = s; redQ[lr * 2 + wc] = q;
            }
        }
    __syncthreads();
#pragma unroll
    for (int mt = 0; mt < 4; ++mt)
#pragma unroll
        for (int r = 0; r < 4; ++r) {
            int lr = wr * 64 + qrow + mt * 16 + r;
            float mu = (redS[lr * 2] + redS[lr * 2 + 1]) * (1.f / 128.f);
            float var = (redQ[lr * 2] + redQ[lr * 2 + 1]) * (1.f / 128.f) - mu * mu;
            float rs = rsqrtf(var + 1e-5f);
            size_t rbase = (size_t)(row0 + lr) * 128;
            float s2 = 0.f, q2 = 0.f;
#pragma unroll
            for (int nt = 0; nt < 4; ++nt) {
                float o = (acc[mt][nt][r] - mu) * rs * mgv[nt] + mbv[nt];
                float z = o + bf2f(h[rbase + colbase + nt * 16]);
                acc[mt][nt][r] = z;
                s2 += z; q2 += z * z;
            }
            s2 = red16(s2); q2 = red16(q2);
            if ((lane & 15) == 0) {
                redS2[lr * 2 + wc] = s2; redQ2[lr * 2 + wc] = q2;
            }
        }
    __syncthreads();
    int bb = row0 >> 8;
#pragma unroll
    for (int mt = 0; mt < 4; ++mt) {
        u16 tvals[4][4];   // [nt][r]
#pragma unroll
        for (int r = 0; r < 4; ++r) {
            int lr = wr * 64 + qrow + mt * 16 + r;
            float mu = (redS2[lr * 2] + redS2[lr * 2 + 1]) * (1.f / 128.f);
            float var = (redQ2[lr * 2] + redQ2[lr * 2 + 1]) * (1.f / 128.f) - mu * mu;
            float rs = rsqrtf(var + 1e-5f);
            size_t rbase = (size_t)(row0 + lr) * 128;
#pragma unroll
            for (int nt = 0; nt < 4; ++nt) {
                float z = acc[mt][nt][r];
                u16 o = f2bf((z - mu) * rs * egv[nt] + ebv[nt]);
                h[rbase + colbase + nt * 16] = o;
                tvals[nt][r] = o;
            }
        }
        int node0 = ((row0 & 255) + wr * 64 + qrow + mt * 16);
#pragma unroll
        for (int nt = 0; nt < 4; ++nt) {
            int d = colbase + nt * 16;
            *(ushort4*)(hT + (size_t)bb * 32768 + (size_t)d * 256 + node0) = *(ushort4*)tvals[nt];
        }
    }
}

// ---------------- fused attention: per (b, head, qhalf) block; packed Q/K/V; bf16 mat; P in registers ----------------
// grid (NB, 4, 2): 1024 blocks -> 2 scheduling rounds, staging overlaps compute across rounds.

__global__ __launch_bounds__(512) void attn_k(const u16* __restrict__ qP,
                                              const u16* __restrict__ kP,
                                              const u16* __restrict__ vT,
                                              const u16* __restrict__ matB,
                                              u16* __restrict__ ctx) {
    __shared__ __align__(16) u16 Kl[256 * 72];   // 36864 B (padded rows)
    __shared__ __align__(16) u16 Vl[64 * 264];   // 33792 B (padded rows)
    int t = threadIdx.x, lane = t & 63, w = t >> 6;
    int b = blockIdx.x, hh = blockIdx.y, zh = blockIdx.z;
    int bh = b * 4 + hh;
    int lg = lane >> 4, q16 = lane & 15;
    int qrow_l = zh * 128 + w * 16;

    // Q-fragment load hoisted above the barrier (global, independent of LDS staging)
    const u16* qsrc = qP + (size_t)bh * 16384 + (qrow_l + q16) * 64 + (lg << 3);
    bf16x8 aq0 = *(const bf16x8*)(qsrc);
    bf16x8 aq1 = *(const bf16x8*)(qsrc + 32);

    // --- staging from packed buffers (dense 32KB each), all 512 threads ---
    {
        const u16* kb = kP + (size_t)bh * 16384;
#pragma unroll
        for (int i = 0; i < 4; ++i) {
            int idx = i * 512 + t;              // 2048 x 16B; K row = 64 u16 = 8 chunks
            int node = idx >> 3, oct = idx & 7;
            *(uint4*)(Kl + node * 72 + oct * 8) = *(const uint4*)(kb + node * 64 + oct * 8);
        }
        const u16* vb = vT + (size_t)bh * 16384;
#pragma unroll
        for (int i = 0; i < 4; ++i) {
            int idx = i * 512 + t;              // 2048 x 16B; V row = 256 u16 = 32 chunks
            int d = idx >> 5, p = idx & 31;
            *(uint4*)(Vl + d * 264 + p * 8) = *(const uint4*)(vb + d * 256 + p * 8);
        }
    }
    __syncthreads();

    f32x4 zero = {0.f, 0.f, 0.f, 0.f};
    bool loA = (lg < 2);
    int s01 = q16 + ((lg & 1) << 5);
    int s23 = s01 + 16;

    f32x4 sc[16];
    __builtin_amdgcn_s_setprio(1);
#pragma unroll
    for (int nt = 0; nt < 16; ++nt) {
        const u16* ks = Kl + (nt * 16 + q16) * 72 + (lg << 3);
        bf16x8 k0 = *(const bf16x8*)(ks);
        bf16x8 k1 = *(const bf16x8*)(ks + 32);
        f32x4 a = __builtin_amdgcn_mfma_f32_16x16x32_bf16(k0, aq0, zero, 0, 0, 0);
        a = __builtin_amdgcn_mfma_f32_16x16x32_bf16(k1, aq1, a, 0, 0, 0);
        sc[nt] = a;
    }
    __builtin_amdgcn_s_setprio(0);

    const u16* mrow = matB + ((size_t)b * LL + qrow_l + q16) * LL + (lg << 2);
#pragma unroll
    for (int nt = 0; nt < 16; ++nt) {
        ushort4 mv = *(const ushort4*)(mrow + nt * 16);
        sc[nt][0] *= bf2f(mv.x);
        sc[nt][1] *= bf2f(mv.y);
        sc[nt][2] *= bf2f(mv.z);
        sc[nt][3] *= bf2f(mv.w);
    }

    float mx = -1e30f;
#pragma unroll
    for (int nt = 0; nt < 16; ++nt)
#pragma unroll
        for (int r = 0; r < 4; ++r) mx = fmaxf(mx, sc[nt][r]);
    mx = fmaxf(mx, __shfl_xor(mx, 16, 64));
    mx = fmaxf(mx, __shfl_xor(mx, 32, 64));
    float sm = 0.f;
#pragma unroll
    for (int nt = 0; nt < 16; ++nt)
#pragma unroll
        for (int r = 0; r < 4; ++r) {
            float e = __expf(sc[nt][r] - mx);
            sc[nt][r] = e;
            sm += e;
        }
    sm += __shfl_xor(sm, 16, 64);
    sm += __shfl_xor(sm, 32, 64);
    float inv = 1.f / sm;
#pragma unroll
    for (int nt = 0; nt < 16; ++nt)
#pragma unroll
        for (int r = 0; r < 4; ++r) sc[nt][r] *= inv;

    f32x4 oa[4];
#pragma unroll
    for (int dt = 0; dt < 4; ++dt) oa[dt] = zero;
    __builtin_amdgcn_s_setprio(1);
#pragma unroll
    for (int kt = 0; kt < 8; ++kt) {
        u32 A0 = cvtpk(sc[2 * kt][0], sc[2 * kt][1]);
        u32 A1 = cvtpk(sc[2 * kt][2], sc[2 * kt][3]);
        u32 B0 = cvtpk(sc[2 * kt + 1][0], sc[2 * kt + 1][1]);
        u32 B1 = cvtpk(sc[2 * kt + 1][2], sc[2 * kt + 1][3]);
        u32 a0s = bperm(s01, A0), b0s = bperm(s01, B0);
        u32 a1s = bperm(s01, A1), b1s = bperm(s01, B1);
        u32 a0t = bperm(s23, A0), b0t = bperm(s23, B0);
        u32 a1t = bperm(s23, A1), b1t = bperm(s23, B1);
        union { u32 u[4]; bf16x8 v; } pa;
        pa.u[0] = loA ? a0s : b0s;
        pa.u[1] = loA ? a1s : b1s;
        pa.u[2] = loA ? a0t : b0t;
        pa.u[3] = loA ? a1t : b1t;
#pragma unroll
        for (int dt = 0; dt < 4; ++dt) {
            bf16x8 bv = *(const bf16x8*)(Vl + (dt * 16 + q16) * 264 + kt * 32 + (lg << 3));
            oa[dt] = __builtin_amdgcn_mfma_f32_16x16x32_bf16(pa.v, bv, oa[dt], 0, 0, 0);
        }
    }
    __builtin_amdgcn_s_setprio(0);
#pragma unroll
    for (int dt = 0; dt < 4; ++dt)
#pragma unroll
        for (int r = 0; r < 4; ++r)
            ctx[(size_t)(b * LL + qrow_l + (lg << 2) + r) * 256 + hh * 64 + dt * 16 + q16] = f2bf(oa[dt][r]);
}

// ---------------- host launch ----------------

extern "C" void kernel_launch(void* const* d_in, const int* in_sizes, int n_in,
                              void* d_out, int out_size, void* d_ws, size_t ws_size,
                              hipStream_t stream) {
    (void)out_size; (void)ws_size; (void)n_in;
    const float* x        = (const float*)d_in[0];
    const int*   ei       = (const int*)d_in[1];
    const float* ea       = (const float*)d_in[2];
    const float* adj      = (const float*)d_in[3];
    const float* dis      = (const float*)d_in[4];
    int pb = (in_sizes[5] == 5120) ? 5 : 6;
    const float* g0_rel_w = (const float*)d_in[pb + 0];
    const float* g0_rel_b = (const float*)d_in[pb + 1];
    const float* g0_root_w= (const float*)d_in[pb + 2];
    const float* g_rel_w  = (const float*)d_in[pb + 3];
    const float* g_rel_b  = (const float*)d_in[pb + 4];
    const float* g_root_w = (const float*)d_in[pb + 5];
    const float* nm_g     = (const float*)d_in[pb + 6];
    const float* nm_b     = (const float*)d_in[pb + 7];
    const float* wq       = (const float*)d_in[pb + 8];
    const float* wk       = (const float*)d_in[pb + 9];
    const float* wv       = (const float*)d_in[pb + 10];
    const float* fc       = (const float*)d_in[pb + 11];
    const float* mha_g    = (const float*)d_in[pb + 12];
    const float* mha_b    = (const float*)d_in[pb + 13];
    const float* enc_g    = (const float*)d_in[pb + 14];
    const float* enc_b    = (const float*)d_in[pb + 15];
    const float* proj_w   = (const float*)d_in[pb + 16];
    const float* proj_b   = (const float*)d_in[pb + 17];
    const int* srcI = ei;
    const int* dstI = ei + EDGES;

    char* w = (char*)d_ws;
    float* Wf     = (float*)w; w += (size_t)33554432;   // W f32 scatter, then reused as matB (bf16)
    u16*   ctx    = (u16*)w;   w += (size_t)16777216;   // attn output [N,256]
    u16*   h      = (u16*)w;   w += (size_t)8388608;
    u16*   qP     = (u16*)w;   w += (size_t)16777216;   // packed Q [bh][256][64]
    u16*   kP     = (u16*)w;   w += (size_t)16777216;   // packed K [bh][256][64]
    u16*   Wb     = (u16*)w;   w += (size_t)16777216;   // W bf16 [128][256][256]
    u16*   bigT   = (u16*)w;   w += (size_t)16777216;   // hT (8.4MB) / vT (16.7MB), time-disjoint
    u16* wconvT0  = (u16*)w;   w += (size_t)32768;
    u16* wconvT   = (u16*)w;   w += (size_t)196608;
    u16* wqkvT    = (u16*)w;   w += (size_t)786432;
    u16* fcT      = (u16*)w;   w += (size_t)262144;
    u16* projT    = (u16*)w;   w += (size_t)32768;
    u16*   matB = (u16*)Wf;
    u16*   hT  = bigT;
    u16*   vT  = bigT;

    // --- prep (cast MUST precede build_matrix: matB aliases Wf) ---
    hipMemsetAsync(Wf, 0, 33554432, stream);
    scatter_w_k<<<2048, 256, 0, stream>>>(srcI, dstI, ea, Wf);
    cast_w_k<<<8192, 256, 0, stream>>>(Wf, Wb);
    build_matrix_k<<<32768, 256, 0, stream>>>(adj, dis, matB);
    prep_weights_k<<<2560, 256, 0, stream>>>(g0_rel_w, g0_root_w, g_rel_w, g_root_w,
                                             wq, wk, wv, fc, proj_w,
                                             wconvT0, wconvT, wqkvT, fcT, projT);
    transpose_x_k<<<2048, 256, 0, stream>>>(x, hT);

    for (int L = 0; L < 4; ++L) {
        if (L == 0)
            gemm_agg_conv<true><<<256, 256, 0, stream>>>(Wb, hT, x, h, wconvT0,
                                                         g0_rel_b, nm_g, nm_b);
        else
            gemm_agg_conv<false><<<256, 256, 0, stream>>>(Wb, hT, x, h, wconvT + (L - 1) * 32768,
                                                          g_rel_b + (L - 1) * 128,
                                                          nm_g + L * 128, nm_b + L * 128);
        gemm_qkv<<<dim3(256, 6), 256, 0, stream>>>(h, wqkvT + L * 98304, qP, kP, vT);
        attn_k<<<dim3(NB, 4, 2), 512, 0, stream>>>(qP, kP, vT, matB, ctx);
        gemm_fc_ln2<<<256, 256, 0, stream>>>(ctx, fcT + L * 32768,
                                             mha_g + L * 128, mha_b + L * 128,
                                             enc_g + L * 128, enc_b + L * 128, h, hT);
    }
    gemm_proj<<<256, 256, 0, stream>>>(h, projT, (float*)d_out, proj_b);
}